// Round 9
// baseline (145.811 us; speedup 1.0000x reference)
//
#include <hip/hip_runtime.h>
#include <hip/hip_bf16.h>

// Problem constants
#define B_  2
#define N_  2048
#define M_  2048
#define D_  512
#define H_  8
#define F_  2048
#define DH_ 64
#define ROWS 4096   // B_*N_ == B_*M_

#define SPLIT 2
#define KV_PER (M_ / SPLIT)   // 1024
#define NT (KV_PER / 64)      // 16 tiles of 64 keys
#define ATT_GRID (16 * 16 * SPLIT)   // n0(16) x bh(16) x sp

typedef __bf16 bf16x8 __attribute__((ext_vector_type(8)));
typedef __bf16 bf16x4v __attribute__((ext_vector_type(4)));
typedef float  f32x4  __attribute__((ext_vector_type(4)));
using bf16 = __hip_bfloat16;

// ---------------------------------------------------------------------------
// LayerNorm over x and y in one launch: rows 0..4095 -> x, 4096..8191 -> y.
// ---------------------------------------------------------------------------
__global__ __launch_bounds__(256) void ln12_kernel(
    const float* __restrict__ xi, const float* __restrict__ yi,
    const float* __restrict__ gam, const float* __restrict__ bet,
    bf16* __restrict__ xo, bf16* __restrict__ yo)
{
    int wave = threadIdx.x >> 6, lane = threadIdx.x & 63;
    int grow = blockIdx.x * 4 + wave;
    const float* in;
    bf16* out;
    int row;
    if (grow < ROWS) { in = xi; out = xo; row = grow; }
    else             { in = yi; out = yo; row = grow - ROWS; }
    const float* p = in + (size_t)row * D_ + lane * 8;
    float4 v0 = *(const float4*)p;
    float4 v1 = *(const float4*)(p + 4);
    float s  = v0.x + v0.y + v0.z + v0.w + v1.x + v1.y + v1.z + v1.w;
    float ss = v0.x*v0.x + v0.y*v0.y + v0.z*v0.z + v0.w*v0.w
             + v1.x*v1.x + v1.y*v1.y + v1.z*v1.z + v1.w*v1.w;
    for (int m = 1; m < 64; m <<= 1) {
        s  += __shfl_xor(s,  m, 64);
        ss += __shfl_xor(ss, m, 64);
    }
    float mu   = s * (1.f / D_);
    float var  = ss * (1.f / D_) - mu * mu;
    float rstd = rsqrtf(var + 1e-6f);
    int c = lane * 8;
    float4 g0 = *(const float4*)(gam + c), g1 = *(const float4*)(gam + c + 4);
    float4 b0 = *(const float4*)(bet + c), b1 = *(const float4*)(bet + c + 4);
    bf16* o = out + (size_t)row * D_ + c;
    o[0] = __float2bfloat16((v0.x - mu) * rstd * g0.x + b0.x);
    o[1] = __float2bfloat16((v0.y - mu) * rstd * g0.y + b0.y);
    o[2] = __float2bfloat16((v0.z - mu) * rstd * g0.z + b0.z);
    o[3] = __float2bfloat16((v0.w - mu) * rstd * g0.w + b0.w);
    o[4] = __float2bfloat16((v1.x - mu) * rstd * g1.x + b1.x);
    o[5] = __float2bfloat16((v1.y - mu) * rstd * g1.y + b1.y);
    o[6] = __float2bfloat16((v1.z - mu) * rstd * g1.z + b1.z);
    o[7] = __float2bfloat16((v1.w - mu) * rstd * g1.w + b1.w);
}

// Single-input LayerNorm (for x1 -> xn2)
__global__ __launch_bounds__(256) void ln_kernel(
    const float* __restrict__ in, const float* __restrict__ gam,
    const float* __restrict__ bet, bf16* __restrict__ out)
{
    int wave = threadIdx.x >> 6, lane = threadIdx.x & 63;
    int row  = blockIdx.x * 4 + wave;
    const float* p = in + (size_t)row * D_ + lane * 8;
    float4 v0 = *(const float4*)p;
    float4 v1 = *(const float4*)(p + 4);
    float s  = v0.x + v0.y + v0.z + v0.w + v1.x + v1.y + v1.z + v1.w;
    float ss = v0.x*v0.x + v0.y*v0.y + v0.z*v0.z + v0.w*v0.w
             + v1.x*v1.x + v1.y*v1.y + v1.z*v1.z + v1.w*v1.w;
    for (int m = 1; m < 64; m <<= 1) {
        s  += __shfl_xor(s,  m, 64);
        ss += __shfl_xor(ss, m, 64);
    }
    float mu   = s * (1.f / D_);
    float var  = ss * (1.f / D_) - mu * mu;
    float rstd = rsqrtf(var + 1e-6f);
    int c = lane * 8;
    float4 g0 = *(const float4*)(gam + c), g1 = *(const float4*)(gam + c + 4);
    float4 b0 = *(const float4*)(bet + c), b1 = *(const float4*)(bet + c + 4);
    bf16* o = out + (size_t)row * D_ + c;
    o[0] = __float2bfloat16((v0.x - mu) * rstd * g0.x + b0.x);
    o[1] = __float2bfloat16((v0.y - mu) * rstd * g0.y + b0.y);
    o[2] = __float2bfloat16((v0.z - mu) * rstd * g0.z + b0.z);
    o[3] = __float2bfloat16((v0.w - mu) * rstd * g0.w + b0.w);
    o[4] = __float2bfloat16((v1.x - mu) * rstd * g1.x + b1.x);
    o[5] = __float2bfloat16((v1.y - mu) * rstd * g1.y + b1.y);
    o[6] = __float2bfloat16((v1.z - mu) * rstd * g1.z + b1.z);
    o[7] = __float2bfloat16((v1.w - mu) * rstd * g1.w + b1.w);
}

// ---------------------------------------------------------------------------
// Weight transpose + cast: W[K,N] f32 -> Wt[N,K] bf16.  block (32,8)
// ---------------------------------------------------------------------------
__global__ void wtrans_kernel(const float* __restrict__ W, bf16* __restrict__ Wt,
                              int K, int N)
{
    __shared__ float t[32][33];
    int tx = threadIdx.x, ty = threadIdx.y;
    int n0 = blockIdx.x * 32, k0 = blockIdx.y * 32;
    for (int j = 0; j < 32; j += 8)
        t[ty + j][tx] = W[(size_t)(k0 + ty + j) * N + n0 + tx];
    __syncthreads();
    for (int j = 0; j < 32; j += 8)
        Wt[(size_t)(n0 + ty + j) * K + k0 + tx] = __float2bfloat16(t[tx][ty + j]);
}

// Batched square (512x512) weight transpose: z picks which of the 4 weights.
__global__ void wtrans4_kernel(const float* __restrict__ Wq, const float* __restrict__ Wk,
                               const float* __restrict__ Wv, const float* __restrict__ Wo,
                               bf16* __restrict__ Wqt, bf16* __restrict__ Wkt,
                               bf16* __restrict__ Wvt, bf16* __restrict__ Wot)
{
    int z = blockIdx.z;
    const float* W = z == 0 ? Wq : (z == 1 ? Wk : (z == 2 ? Wv : Wo));
    bf16* Wt       = z == 0 ? Wqt : (z == 1 ? Wkt : (z == 2 ? Wvt : Wot));
    __shared__ float t[32][33];
    int tx = threadIdx.x, ty = threadIdx.y;
    int n0 = blockIdx.x * 32, k0 = blockIdx.y * 32;
    for (int j = 0; j < 32; j += 8)
        t[ty + j][tx] = W[(size_t)(k0 + ty + j) * D_ + n0 + tx];
    __syncthreads();
    for (int j = 0; j < 32; j += 8)
        Wt[(size_t)(n0 + ty + j) * D_ + k0 + tx] = __float2bfloat16(t[tx][ty + j]);
}

// ---------------------------------------------------------------------------
// 64x64-tile GEMM. 4 waves (2x2, each 32x32), BK=64, reg-staged
// double-buffered LDS, XOR-swizzled for conflict-free ds_read_b128.
// VTRANS epilogue (for V projection): write per-head transposed layout.
// ---------------------------------------------------------------------------
template<bool RESID, bool ROWMASK, bool OUTBF, bool VTRANS>
__device__ __forceinline__ void gemm64_body(
    const bf16* __restrict__ A, const bf16* __restrict__ Bt,
    const float* __restrict__ bias, const float* __restrict__ resid,
    const float* __restrict__ rowmask,
    bf16* __restrict__ outb, float* __restrict__ outf,
    int Nn, int K)
{
    __shared__ __align__(16) char As[2][64 * 128];
    __shared__ __align__(16) char Bs[2][64 * 128];
    int t = threadIdx.x, lane = t & 63, wave = t >> 6;
    int wm = wave >> 1, wn = wave & 1;
    int r16 = lane & 15, g = lane >> 4;
    int m0 = blockIdx.x * 64, n0 = blockIdx.y * 64;

    const int sr0 = t >> 3, sr1 = sr0 + 32, sc = t & 7;
    const int wof0 = sr0 * 128 + ((sc ^ (sr0 & 7)) << 4);
    const int wof1 = sr1 * 128 + ((sc ^ (sr1 & 7)) << 4);
    const int rsw0 = ((g     ^ (r16 & 7)) << 4);   // ks=0 chunk
    const int rsw1 = (((4 + g) ^ (r16 & 7)) << 4); // ks=1 chunk

    uint4 a0, a1, b0, b1;
#define G64_LOAD(k0)                                                         \
    a0 = *(const uint4*)(A  + (size_t)(m0 + sr0) * K + (k0) + sc * 8);       \
    a1 = *(const uint4*)(A  + (size_t)(m0 + sr1) * K + (k0) + sc * 8);       \
    b0 = *(const uint4*)(Bt + (size_t)(n0 + sr0) * K + (k0) + sc * 8);       \
    b1 = *(const uint4*)(Bt + (size_t)(n0 + sr1) * K + (k0) + sc * 8);
#define G64_WRITE(buf)                                                       \
    *(uint4*)(As[buf] + wof0) = a0;  *(uint4*)(As[buf] + wof1) = a1;         \
    *(uint4*)(Bs[buf] + wof0) = b0;  *(uint4*)(Bs[buf] + wof1) = b1;

    f32x4 acc[2][2] = {};
    G64_LOAD(0)
    G64_WRITE(0)
    int cur = 0;
    const int nit = K >> 6;
    for (int it = 0; it < nit; ++it) {
        if (it + 1 < nit) { G64_LOAD((it + 1) << 6) }
        __syncthreads();
        bf16x8 af[2][2], bfr[2][2];
#pragma unroll
        for (int i = 0; i < 2; ++i) {
            af[i][0] = *(const bf16x8*)(As[cur] + (wm * 32 + i * 16 + r16) * 128 + rsw0);
            af[i][1] = *(const bf16x8*)(As[cur] + (wm * 32 + i * 16 + r16) * 128 + rsw1);
            bfr[i][0] = *(const bf16x8*)(Bs[cur] + (wn * 32 + i * 16 + r16) * 128 + rsw0);
            bfr[i][1] = *(const bf16x8*)(Bs[cur] + (wn * 32 + i * 16 + r16) * 128 + rsw1);
        }
        __builtin_amdgcn_s_setprio(1);
#pragma unroll
        for (int i = 0; i < 2; ++i)
#pragma unroll
            for (int j = 0; j < 2; ++j) {
                acc[i][j] = __builtin_amdgcn_mfma_f32_16x16x32_bf16(af[i][0], bfr[j][0], acc[i][j], 0, 0, 0);
                acc[i][j] = __builtin_amdgcn_mfma_f32_16x16x32_bf16(af[i][1], bfr[j][1], acc[i][j], 0, 0, 0);
            }
        __builtin_amdgcn_s_setprio(0);
        if (it + 1 < nit) { G64_WRITE(cur ^ 1) }
        cur ^= 1;
    }
#undef G64_LOAD
#undef G64_WRITE

#pragma unroll
    for (int i = 0; i < 2; ++i) {
        int rb = m0 + wm * 32 + i * 16 + g * 4;
#pragma unroll
        for (int j = 0; j < 2; ++j) {
            int cb = n0 + wn * 32 + j * 16 + r16;
            float bia = bias[cb];
            if (VTRANS) {
                // v[rr][cb] -> vt[(b*8 + cb>>6)*64 + (cb&63)][m], m = rr&2047
                bf16x4v w;
#pragma unroll
                for (int e = 0; e < 4; ++e) {
                    int rr = rb + e;
                    float val = acc[i][j][e] + bia;
                    if (ROWMASK) val *= rowmask[rr];
                    w[e] = (__bf16)val;
                }
                int bb = rb >> 11, m = rb & (M_ - 1);
                int bh = bb * H_ + (cb >> 6), d = cb & (DH_ - 1);
                *(bf16x4v*)(outb + ((size_t)bh * DH_ + d) * M_ + m) = w;
            } else {
#pragma unroll
                for (int e = 0; e < 4; ++e) {
                    int rr = rb + e;
                    float val = acc[i][j][e] + bia;
                    if (RESID)   val += resid[(size_t)rr * Nn + cb];
                    if (ROWMASK) val *= rowmask[rr];
                    if (OUTBF)   outb[(size_t)rr * Nn + cb] = __float2bfloat16(val);
                    else         outf[(size_t)rr * Nn + cb] = val;
                }
            }
        }
    }
}

template<bool RESID, bool OUTBF>
__global__ __launch_bounds__(256) void gemm64(
    const bf16* __restrict__ A, const bf16* __restrict__ Bt,
    const float* __restrict__ bias, const float* __restrict__ resid,
    bf16* __restrict__ outb, float* __restrict__ outf, int Nn, int K)
{
    gemm64_body<RESID, false, OUTBF, false>(A, Bt, bias, resid, nullptr, outb, outf, Nn, K);
}

// Batched Q/K/V projection: z selects Q, K, or V; V writes transposed.
__global__ __launch_bounds__(256) void gemm64_qkv(
    const bf16* __restrict__ xn, const bf16* __restrict__ yn,
    const bf16* __restrict__ Wqt, const bf16* __restrict__ Wkt, const bf16* __restrict__ Wvt,
    const float* __restrict__ bq, const float* __restrict__ bk, const float* __restrict__ bv,
    const float* __restrict__ mask_x, const float* __restrict__ mask_y,
    bf16* __restrict__ qb, bf16* __restrict__ kb, bf16* __restrict__ vtb)
{
    int z = blockIdx.z;
    if (z == 2) {
        gemm64_body<false, true, true, true>(yn, Wvt, bv, nullptr, mask_y, vtb, nullptr, D_, D_);
    } else {
        const bf16* A        = z == 0 ? xn : yn;
        const bf16* Bt       = z == 0 ? Wqt : Wkt;
        const float* bias    = z == 0 ? bq  : bk;
        const float* rowmask = z == 0 ? mask_x : mask_y;
        bf16* outb           = z == 0 ? qb  : kb;
        gemm64_body<false, true, true, false>(A, Bt, bias, nullptr, rowmask, outb, nullptr, D_, D_);
    }
}

// ---------------------------------------------------------------------------
// 128x128-tile GEMM (MLP1): 4 waves (2x2, each 64x64), BK=64, reg-staged
// double-buffered LDS, XOR-swizzled. GELU epilogue, bf16 out.
// ---------------------------------------------------------------------------
template<bool GELU>
__global__ __launch_bounds__(256, 2) void gemm128(
    const bf16* __restrict__ A, const bf16* __restrict__ Bt,
    const float* __restrict__ bias, bf16* __restrict__ outb,
    int Nn, int K)
{
    __shared__ __align__(16) char As[2][128 * 128];
    __shared__ __align__(16) char Bs[2][128 * 128];
    int t = threadIdx.x, lane = t & 63, wave = t >> 6;
    int wm = wave >> 1, wn = wave & 1;
    int r16 = lane & 15, g = lane >> 4;
    int m0 = blockIdx.x * 128, n0 = blockIdx.y * 128;

    const int sr = t >> 3, sc = t & 7;   // slot rows sr + 32*i, col sc
    const int swc = ((sc ^ (sr & 7)) << 4);
    const int rsw0 = ((g     ^ (r16 & 7)) << 4);
    const int rsw1 = (((4 + g) ^ (r16 & 7)) << 4);

    uint4 a[4], b[4];
#define G128_LOAD(k0)                                                          \
    _Pragma("unroll")                                                          \
    for (int i = 0; i < 4; ++i) {                                              \
        a[i] = *(const uint4*)(A  + (size_t)(m0 + sr + 32 * i) * K + (k0) + sc * 8); \
        b[i] = *(const uint4*)(Bt + (size_t)(n0 + sr + 32 * i) * K + (k0) + sc * 8); \
    }
#define G128_WRITE(buf)                                                        \
    _Pragma("unroll")                                                          \
    for (int i = 0; i < 4; ++i) {                                              \
        *(uint4*)(As[buf] + (sr + 32 * i) * 128 + swc) = a[i];                 \
        *(uint4*)(Bs[buf] + (sr + 32 * i) * 128 + swc) = b[i];                 \
    }

    f32x4 acc[4][4] = {};
    G128_LOAD(0)
    G128_WRITE(0)
    int cur = 0;
    const int nit = K >> 6;
    for (int it = 0; it < nit; ++it) {
        if (it + 1 < nit) { G128_LOAD((it + 1) << 6) }
        __syncthreads();
        bf16x8 af[4][2], bfr[4][2];
#pragma unroll
        for (int i = 0; i < 4; ++i) {
            af[i][0]  = *(const bf16x8*)(As[cur] + (wm * 64 + i * 16 + r16) * 128 + rsw0);
            af[i][1]  = *(const bf16x8*)(As[cur] + (wm * 64 + i * 16 + r16) * 128 + rsw1);
            bfr[i][0] = *(const bf16x8*)(Bs[cur] + (wn * 64 + i * 16 + r16) * 128 + rsw0);
            bfr[i][1] = *(const bf16x8*)(Bs[cur] + (wn * 64 + i * 16 + r16) * 128 + rsw1);
        }
        __builtin_amdgcn_s_setprio(1);
#pragma unroll
        for (int i = 0; i < 4; ++i)
#pragma unroll
            for (int j = 0; j < 4; ++j) {
                acc[i][j] = __builtin_amdgcn_mfma_f32_16x16x32_bf16(af[i][0], bfr[j][0], acc[i][j], 0, 0, 0);
                acc[i][j] = __builtin_amdgcn_mfma_f32_16x16x32_bf16(af[i][1], bfr[j][1], acc[i][j], 0, 0, 0);
            }
        __builtin_amdgcn_s_setprio(0);
        if (it + 1 < nit) { G128_WRITE(cur ^ 1) }
        cur ^= 1;
    }
#undef G128_LOAD
#undef G128_WRITE

#pragma unroll
    for (int i = 0; i < 4; ++i) {
        int rb = m0 + wm * 64 + i * 16 + g * 4;
#pragma unroll
        for (int j = 0; j < 4; ++j) {
            int cb = n0 + wn * 64 + j * 16 + r16;
            float bia = bias[cb];
#pragma unroll
            for (int e = 0; e < 4; ++e) {
                float val = acc[i][j][e] + bia;
                if (GELU) val = 0.5f * val * (1.f + erff(val * 0.70710678118654752f));
                outb[(size_t)(rb + e) * Nn + cb] = __float2bfloat16(val);
            }
        }
    }
}

// ---------------------------------------------------------------------------
// Flash attention (swapped S^T = K*Q), LDS-staged double-buffered K/V with
// XOR swizzle, reg-staged. 1D grid, XCD-chunked remap. 4 waves, 32 q-rows
// each. T13 defer-max. bf16 numerator + per-row (m,l) f32.
// ---------------------------------------------------------------------------
__global__ __launch_bounds__(256, 3) void attn_kernel(
    const bf16* __restrict__ q, const bf16* __restrict__ kk,
    const bf16* __restrict__ vt, bf16* __restrict__ num,
    float* __restrict__ ml)
{
    int bid = blockIdx.x;
    int wg  = (bid & 7) * (ATT_GRID / 8) + (bid >> 3);
    int n0  = (wg & 15) * 128;
    int bh  = (wg >> 4) & 15;
    int sp  = wg >> 8;
    int b = bh >> 3, h = bh & 7;
    int t = threadIdx.x, lane = t & 63, wave = t >> 6;
    int ql = lane & 15, gg = lane >> 4;

    __shared__ __align__(16) char KsB[2][64 * 128];
    __shared__ __align__(16) char VsB[2][64 * 128];
    __shared__ __align__(16) bf16 plds[4][16][72];

    bf16x8 qf0[2], qf1[2];
    {
        int qr0 = b * N_ + n0 + wave * 32 + ql;
        for (int ks = 0; ks < 2; ++ks) {
            bf16x8 qv = *(const bf16x8*)(q + (size_t)qr0 * D_ + h * DH_ + ks * 32 + gg * 8);
            for (int j = 0; j < 8; ++j) qv[j] = (__bf16)((float)qv[j] * 0.125f);
            qf0[ks] = qv;
            bf16x8 qw = *(const bf16x8*)(q + (size_t)(qr0 + 16) * D_ + h * DH_ + ks * 32 + gg * 8);
            for (int j = 0; j < 8; ++j) qw[j] = (__bf16)((float)qw[j] * 0.125f);
            qf1[ks] = qw;
        }
    }

    f32x4 cacc0[4] = {}, cacc1[4] = {};
    float m0r = -1e30f, l0r = 0.f, m1r = -1e30f, l1r = 0.f;

    const bf16* kbase = kk + (size_t)(b * M_ + sp * KV_PER) * D_ + h * DH_;
    const bf16* vtb   = vt + (size_t)bh * DH_ * M_ + sp * KV_PER;

    const int k0r = t >> 3,          kc0 = t & 7;
    const int k1r = (t >> 3) + 32;
    const int wofs0 = k0r * 128 + ((kc0 ^ (k0r & 7)) << 4);
    const int wofs1 = k1r * 128 + ((kc0 ^ (k1r & 7)) << 4);
    const int rsw0 = ((gg     ^ (ql & 7)) << 4);
    const int rsw1 = (((4 + gg) ^ (ql & 7)) << 4);

#define STAGE_LOAD(tt)                                                              \
    kw0 = *(const uint4*)(kbase + (size_t)((tt) * 64 + k0r) * D_ + kc0 * 8);        \
    kw1 = *(const uint4*)(kbase + (size_t)((tt) * 64 + k1r) * D_ + kc0 * 8);        \
    vw0 = *(const uint4*)(vtb + (size_t)k0r * M_ + (tt) * 64 + kc0 * 8);            \
    vw1 = *(const uint4*)(vtb + (size_t)k1r * M_ + (tt) * 64 + kc0 * 8);

#define STAGE_WRITE(buf)                                                            \
    *(uint4*)(KsB[buf] + wofs0) = kw0;                                              \
    *(uint4*)(KsB[buf] + wofs1) = kw1;                                              \
    *(uint4*)(VsB[buf] + wofs0) = vw0;                                              \
    *(uint4*)(VsB[buf] + wofs1) = vw1;

#define SOFTMAX_PV(S, MR, LR, CACC)                                                 \
    {                                                                               \
        float tmax = fmaxf(                                                         \
            fmaxf(fmaxf(fmaxf(S[0][0], S[0][1]), fmaxf(S[0][2], S[0][3])),          \
                  fmaxf(fmaxf(S[1][0], S[1][1]), fmaxf(S[1][2], S[1][3]))),         \
            fmaxf(fmaxf(fmaxf(S[2][0], S[2][1]), fmaxf(S[2][2], S[2][3])),          \
                  fmaxf(fmaxf(S[3][0], S[3][1]), fmaxf(S[3][2], S[3][3]))));        \
        tmax = fmaxf(tmax, __shfl_xor(tmax, 16, 64));                               \
        tmax = fmaxf(tmax, __shfl_xor(tmax, 32, 64));                               \
        if (__any(tmax - MR > 8.f)) {                                               \
            float mnew = fmaxf(MR, tmax);                                           \
            float scl  = __expf(MR - mnew);                                         \
            MR = mnew;                                                              \
            LR *= scl;                                                              \
            for (int df = 0; df < 4; ++df)                                          \
                for (int e = 0; e < 4; ++e) CACC[df][e] *= scl;                     \
        }                                                                           \
        float p[4][4]; float ps = 0.f;                                              \
        for (int nf = 0; nf < 4; ++nf)                                              \
            for (int e = 0; e < 4; ++e) { p[nf][e] = __expf(S[nf][e] - MR); ps += p[nf][e]; } \
        ps += __shfl_xor(ps, 16, 64);                                               \
        ps += __shfl_xor(ps, 32, 64);                                               \
        LR += ps;                                                                   \
        for (int nf = 0; nf < 4; ++nf) {                                            \
            bf16x4v w;                                                              \
            w[0] = (__bf16)p[nf][0]; w[1] = (__bf16)p[nf][1];                       \
            w[2] = (__bf16)p[nf][2]; w[3] = (__bf16)p[nf][3];                       \
            *(bf16x4v*)(&plds[wave][ql][nf * 16 + 4 * gg]) = w;                     \
        }                                                                           \
        __builtin_amdgcn_s_setprio(1);                                              \
        for (int ks = 0; ks < 2; ++ks) {                                            \
            bf16x8 pf = *(const bf16x8*)((const char*)&plds[wave][0][0]             \
                                         + ql * 144 + ks * 64 + gg * 16);           \
            for (int df = 0; df < 4; ++df)                                          \
                CACC[df] = __builtin_amdgcn_mfma_f32_16x16x32_bf16(                 \
                    vf[df * 2 + ks], pf, CACC[df], 0, 0, 0);                        \
        }                                                                           \
        __builtin_amdgcn_s_setprio(0);                                              \
    }

    uint4 kw0, kw1, vw0, vw1;
    STAGE_LOAD(0)
    STAGE_WRITE(0)
    int cur = 0;

    for (int tt = 0; tt < NT; ++tt) {
        if (tt + 1 < NT) { STAGE_LOAD(tt + 1) }
        __syncthreads();

        const char* Kb = KsB[cur];
        const char* Vb = VsB[cur];

        bf16x8 kf[8];
#pragma unroll
        for (int nf = 0; nf < 4; ++nf) {
            kf[nf * 2 + 0] = *(const bf16x8*)(Kb + (nf * 16 + ql) * 128 + rsw0);
            kf[nf * 2 + 1] = *(const bf16x8*)(Kb + (nf * 16 + ql) * 128 + rsw1);
        }

        f32x4 s0[4] = {}, s1[4] = {};
        __builtin_amdgcn_s_setprio(1);
#pragma unroll
        for (int nf = 0; nf < 4; ++nf) {
            s0[nf] = __builtin_amdgcn_mfma_f32_16x16x32_bf16(kf[nf * 2 + 0], qf0[0], s0[nf], 0, 0, 0);
            s0[nf] = __builtin_amdgcn_mfma_f32_16x16x32_bf16(kf[nf * 2 + 1], qf0[1], s0[nf], 0, 0, 0);
            s1[nf] = __builtin_amdgcn_mfma_f32_16x16x32_bf16(kf[nf * 2 + 0], qf1[0], s1[nf], 0, 0, 0);
            s1[nf] = __builtin_amdgcn_mfma_f32_16x16x32_bf16(kf[nf * 2 + 1], qf1[1], s1[nf], 0, 0, 0);
        }
        __builtin_amdgcn_s_setprio(0);

        bf16x8 vf[8];
#pragma unroll
        for (int df = 0; df < 4; ++df) {
            vf[df * 2 + 0] = *(const bf16x8*)(Vb + (df * 16 + ql) * 128 + rsw0);
            vf[df * 2 + 1] = *(const bf16x8*)(Vb + (df * 16 + ql) * 128 + rsw1);
        }

        SOFTMAX_PV(s0, m0r, l0r, cacc0)
        SOFTMAX_PV(s1, m1r, l1r, cacc1)

        if (tt + 1 < NT) { STAGE_WRITE(cur ^ 1) }
        cur ^= 1;
    }

    {
        int qr0 = b * N_ + n0 + wave * 32 + ql;
        bf16* nb0 = num + (size_t)sp * ROWS * D_ + (size_t)qr0 * D_ + h * DH_;
        bf16* nb1 = num + (size_t)sp * ROWS * D_ + (size_t)(qr0 + 16) * D_ + h * DH_;
#pragma unroll
        for (int df = 0; df < 4; ++df) {
            bf16x4v w0, w1;
#pragma unroll
            for (int e = 0; e < 4; ++e) {
                w0[e] = (__bf16)cacc0[df][e];
                w1[e] = (__bf16)cacc1[df][e];
            }
            *(bf16x4v*)(nb0 + df * 16 + 4 * gg) = w0;
            *(bf16x4v*)(nb1 + df * 16 + 4 * gg) = w1;
        }
        if (lane < 16) {
            size_t base = ((size_t)(sp * (B_ * H_) + bh) * N_ + (n0 + wave * 32 + ql)) * 2;
            ml[base] = m0r; ml[base + 1] = l0r;
            size_t base1 = ((size_t)(sp * (B_ * H_) + bh) * N_ + (n0 + wave * 32 + 16 + ql)) * 2;
            ml[base1] = m1r; ml[base1 + 1] = l1r;
        }
    }
#undef STAGE_LOAD
#undef STAGE_WRITE
#undef SOFTMAX_PV
}

// Combine the SPLIT partials (bf16 numerators) -> bf16 ctx
__global__ __launch_bounds__(256) void attn_combine(
    const bf16* __restrict__ num, const float* __restrict__ ml,
    bf16* __restrict__ ctx)
{
    int idx = blockIdx.x * 256 + threadIdx.x;
    int row = idx >> 7;
    int c4  = (idx & 127) << 2;
    int b = row >> 11, n = row & (N_ - 1);
    int h = c4 >> 6;
    int bh = (b << 3) + h;
    float mv[SPLIT], lv[SPLIT];
#pragma unroll
    for (int sp = 0; sp < SPLIT; ++sp) {
        const float* mp = ml + ((size_t)(sp * (B_ * H_) + bh) * N_ + n) * 2;
        mv[sp] = mp[0]; lv[sp] = mp[1];
    }
    float mx = mv[0];
#pragma unroll
    for (int sp = 1; sp < SPLIT; ++sp) mx = fmaxf(mx, mv[sp]);
    float den = 0.f;
    float wsc[SPLIT];
#pragma unroll
    for (int sp = 0; sp < SPLIT; ++sp) {
        wsc[sp] = __expf(mv[sp] - mx);
        den += wsc[sp] * lv[sp];
    }
    float inv = 1.f / den;
    float ax = 0.f, ay = 0.f, az = 0.f, aw = 0.f;
#pragma unroll
    for (int sp = 0; sp < SPLIT; ++sp) {
        bf16x4v v = *(const bf16x4v*)(num + (size_t)sp * ROWS * D_ + (size_t)row * D_ + c4);
        ax += wsc[sp] * (float)v[0]; ay += wsc[sp] * (float)v[1];
        az += wsc[sp] * (float)v[2]; aw += wsc[sp] * (float)v[3];
    }
    bf16* o = ctx + (size_t)row * D_ + c4;
    o[0] = __float2bfloat16(ax * inv);
    o[1] = __float2bfloat16(ay * inv);
    o[2] = __float2bfloat16(az * inv);
    o[3] = __float2bfloat16(aw * inv);
}

// ---------------------------------------------------------------------------
extern "C" void kernel_launch(void* const* d_in, const int* in_sizes, int n_in,
                              void* d_out, int out_size, void* d_ws, size_t ws_size,
                              hipStream_t stream)
{
    const float* x      = (const float*)d_in[0];
    const float* y      = (const float*)d_in[1];
    const float* mask_x = (const float*)d_in[2];
    const float* mask_y = (const float*)d_in[3];
    const float* Wq = (const float*)d_in[4];  const float* bq = (const float*)d_in[5];
    const float* Wk = (const float*)d_in[6];  const float* bk = (const float*)d_in[7];
    const float* Wv = (const float*)d_in[8];  const float* bv = (const float*)d_in[9];
    const float* Wo = (const float*)d_in[10]; const float* bo = (const float*)d_in[11];
    const float* W1 = (const float*)d_in[12]; const float* b1 = (const float*)d_in[13];
    const float* W2 = (const float*)d_in[14]; const float* b2 = (const float*)d_in[15];
    const float* ln1g = (const float*)d_in[16]; const float* ln1b = (const float*)d_in[17];
    const float* ln2g = (const float*)d_in[18]; const float* ln2b = (const float*)d_in[19];

    char* ws = (char*)d_ws;
    const size_t SZA = (size_t)ROWS * D_ * 2;     // 4 MiB bf16 activation
    bf16* xn   = (bf16*)ws;            ws += SZA;
    bf16* yn   = (bf16*)ws;            ws += SZA;
    bf16* qb   = (bf16*)ws;            ws += SZA;
    bf16* kb   = (bf16*)ws;            ws += SZA;
    bf16* vtb  = (bf16*)ws;            ws += SZA;
    bf16* ctxb = (bf16*)ws;            ws += SZA;
    bf16* xn2  = (bf16*)ws;            ws += SZA;
    bf16* hff  = (bf16*)ws;            ws += (size_t)ROWS * F_ * 2;
    float* x1  = (float*)ws;           ws += (size_t)ROWS * D_ * 4;
    bf16* Wqt = (bf16*)ws;             ws += (size_t)D_ * D_ * 2;
    bf16* Wkt = (bf16*)ws;             ws += (size_t)D_ * D_ * 2;
    bf16* Wvt = (bf16*)ws;             ws += (size_t)D_ * D_ * 2;
    bf16* Wot = (bf16*)ws;             ws += (size_t)D_ * D_ * 2;
    bf16* W1t = (bf16*)ws;             ws += (size_t)D_ * F_ * 2;
    bf16* W2t = (bf16*)ws;             ws += (size_t)F_ * D_ * 2;
    bf16* numb = (bf16*)ws;            ws += (size_t)SPLIT * ROWS * D_ * 2;
    float* mlb = (float*)ws;           ws += (size_t)SPLIT * B_ * H_ * N_ * 2 * 4;

    dim3 tb(32, 8);
    wtrans4_kernel<<<dim3(D_ / 32, D_ / 32, 4), tb, 0, stream>>>(
        Wq, Wk, Wv, Wo, Wqt, Wkt, Wvt, Wot);
    wtrans_kernel<<<dim3(F_ / 32, D_ / 32), tb, 0, stream>>>(W1, W1t, D_, F_);
    wtrans_kernel<<<dim3(D_ / 32, F_ / 32), tb, 0, stream>>>(W2, W2t, F_, D_);

    // LN(x) and LN(y) in one launch
    ln12_kernel<<<2 * ROWS / 4, 256, 0, stream>>>(x, y, ln1g, ln1b, xn, yn);

    // Q/K/V projections; V written directly in per-head transposed layout
    gemm64_qkv<<<dim3(ROWS / 64, D_ / 64, 3), 256, 0, stream>>>(
        xn, yn, Wqt, Wkt, Wvt, bq, bk, bv, mask_x, mask_y, qb, kb, vtb);

    attn_kernel<<<ATT_GRID, 256, 0, stream>>>(qb, kb, vtb, numb, mlb);
    attn_combine<<<(ROWS * D_ / 4) / 256, 256, 0, stream>>>(numb, mlb, ctxb);

    // out-proj + residual(x) -> x1 (f32)
    gemm64<true, false><<<dim3(ROWS / 64, D_ / 64), 256, 0, stream>>>(
        ctxb, Wot, bo, x, nullptr, x1, D_, D_);

    ln_kernel<<<ROWS / 4, 256, 0, stream>>>(x1, ln2g, ln2b, xn2);

    // MLP1 + GELU -> hff (bf16), 128x128 swizzled dbuf tiles (512 blocks)
    gemm128<true><<<dim3(ROWS / 128, F_ / 128), 256, 0, stream>>>(
        xn2, W1t, b1, hff, F_, D_);

    // MLP2 + residual(x1) -> d_out (f32)
    gemm64<true, false><<<dim3(ROWS / 64, D_ / 64), 256, 0, stream>>>(
        hff, W2t, b2, x1, nullptr, (float*)d_out, D_, F_);
}

// Round 10
// 123.530 us; speedup vs baseline: 1.1804x; 1.1804x over previous
//
#include <hip/hip_runtime.h>
#include <hip/hip_bf16.h>

// Problem constants
#define B_  2
#define N_  2048
#define M_  2048
#define D_  512
#define H_  8
#define F_  2048
#define DH_ 64
#define ROWS 4096   // B_*N_ == B_*M_

#define SPLIT 2
#define KV_PER (M_ / SPLIT)   // 1024
#define NT (KV_PER / 64)      // 16 tiles of 64 keys
#define ATT_GRID (16 * 16 * SPLIT)   // n0(16) x bh(16) x sp

typedef __bf16 bf16x8 __attribute__((ext_vector_type(8)));
typedef __bf16 bf16x4v __attribute__((ext_vector_type(4)));
typedef float  f32x4  __attribute__((ext_vector_type(4)));
using bf16 = __hip_bfloat16;

// ---------------------------------------------------------------------------
// LayerNorm over x and y in one launch: rows 0..4095 -> x, 4096..8191 -> y.
// ---------------------------------------------------------------------------
__global__ __launch_bounds__(256) void ln12_kernel(
    const float* __restrict__ xi, const float* __restrict__ yi,
    const float* __restrict__ gam, const float* __restrict__ bet,
    bf16* __restrict__ xo, bf16* __restrict__ yo)
{
    int wave = threadIdx.x >> 6, lane = threadIdx.x & 63;
    int grow = blockIdx.x * 4 + wave;
    const float* in;
    bf16* out;
    int row;
    if (grow < ROWS) { in = xi; out = xo; row = grow; }
    else             { in = yi; out = yo; row = grow - ROWS; }
    const float* p = in + (size_t)row * D_ + lane * 8;
    float4 v0 = *(const float4*)p;
    float4 v1 = *(const float4*)(p + 4);
    float s  = v0.x + v0.y + v0.z + v0.w + v1.x + v1.y + v1.z + v1.w;
    float ss = v0.x*v0.x + v0.y*v0.y + v0.z*v0.z + v0.w*v0.w
             + v1.x*v1.x + v1.y*v1.y + v1.z*v1.z + v1.w*v1.w;
    for (int m = 1; m < 64; m <<= 1) {
        s  += __shfl_xor(s,  m, 64);
        ss += __shfl_xor(ss, m, 64);
    }
    float mu   = s * (1.f / D_);
    float var  = ss * (1.f / D_) - mu * mu;
    float rstd = rsqrtf(var + 1e-6f);
    int c = lane * 8;
    float4 g0 = *(const float4*)(gam + c), g1 = *(const float4*)(gam + c + 4);
    float4 b0 = *(const float4*)(bet + c), b1 = *(const float4*)(bet + c + 4);
    bf16* o = out + (size_t)row * D_ + c;
    o[0] = __float2bfloat16((v0.x - mu) * rstd * g0.x + b0.x);
    o[1] = __float2bfloat16((v0.y - mu) * rstd * g0.y + b0.y);
    o[2] = __float2bfloat16((v0.z - mu) * rstd * g0.z + b0.z);
    o[3] = __float2bfloat16((v0.w - mu) * rstd * g0.w + b0.w);
    o[4] = __float2bfloat16((v1.x - mu) * rstd * g1.x + b1.x);
    o[5] = __float2bfloat16((v1.y - mu) * rstd * g1.y + b1.y);
    o[6] = __float2bfloat16((v1.z - mu) * rstd * g1.z + b1.z);
    o[7] = __float2bfloat16((v1.w - mu) * rstd * g1.w + b1.w);
}

// Single-input LayerNorm (for x1 -> xn2)
__global__ __launch_bounds__(256) void ln_kernel(
    const float* __restrict__ in, const float* __restrict__ gam,
    const float* __restrict__ bet, bf16* __restrict__ out)
{
    int wave = threadIdx.x >> 6, lane = threadIdx.x & 63;
    int row  = blockIdx.x * 4 + wave;
    const float* p = in + (size_t)row * D_ + lane * 8;
    float4 v0 = *(const float4*)p;
    float4 v1 = *(const float4*)(p + 4);
    float s  = v0.x + v0.y + v0.z + v0.w + v1.x + v1.y + v1.z + v1.w;
    float ss = v0.x*v0.x + v0.y*v0.y + v0.z*v0.z + v0.w*v0.w
             + v1.x*v1.x + v1.y*v1.y + v1.z*v1.z + v1.w*v1.w;
    for (int m = 1; m < 64; m <<= 1) {
        s  += __shfl_xor(s,  m, 64);
        ss += __shfl_xor(ss, m, 64);
    }
    float mu   = s * (1.f / D_);
    float var  = ss * (1.f / D_) - mu * mu;
    float rstd = rsqrtf(var + 1e-6f);
    int c = lane * 8;
    float4 g0 = *(const float4*)(gam + c), g1 = *(const float4*)(gam + c + 4);
    float4 b0 = *(const float4*)(bet + c), b1 = *(const float4*)(bet + c + 4);
    bf16* o = out + (size_t)row * D_ + c;
    o[0] = __float2bfloat16((v0.x - mu) * rstd * g0.x + b0.x);
    o[1] = __float2bfloat16((v0.y - mu) * rstd * g0.y + b0.y);
    o[2] = __float2bfloat16((v0.z - mu) * rstd * g0.z + b0.z);
    o[3] = __float2bfloat16((v0.w - mu) * rstd * g0.w + b0.w);
    o[4] = __float2bfloat16((v1.x - mu) * rstd * g1.x + b1.x);
    o[5] = __float2bfloat16((v1.y - mu) * rstd * g1.y + b1.y);
    o[6] = __float2bfloat16((v1.z - mu) * rstd * g1.z + b1.z);
    o[7] = __float2bfloat16((v1.w - mu) * rstd * g1.w + b1.w);
}

// ---------------------------------------------------------------------------
// Weight transpose + cast: W[K,N] f32 -> Wt[N,K] bf16.  block (32,8)
// ---------------------------------------------------------------------------
__global__ void wtrans_kernel(const float* __restrict__ W, bf16* __restrict__ Wt,
                              int K, int N)
{
    __shared__ float t[32][33];
    int tx = threadIdx.x, ty = threadIdx.y;
    int n0 = blockIdx.x * 32, k0 = blockIdx.y * 32;
    for (int j = 0; j < 32; j += 8)
        t[ty + j][tx] = W[(size_t)(k0 + ty + j) * N + n0 + tx];
    __syncthreads();
    for (int j = 0; j < 32; j += 8)
        Wt[(size_t)(n0 + ty + j) * K + k0 + tx] = __float2bfloat16(t[tx][ty + j]);
}

// Batched square (512x512) weight transpose: z picks which of the 4 weights.
__global__ void wtrans4_kernel(const float* __restrict__ Wq, const float* __restrict__ Wk,
                               const float* __restrict__ Wv, const float* __restrict__ Wo,
                               bf16* __restrict__ Wqt, bf16* __restrict__ Wkt,
                               bf16* __restrict__ Wvt, bf16* __restrict__ Wot)
{
    int z = blockIdx.z;
    const float* W = z == 0 ? Wq : (z == 1 ? Wk : (z == 2 ? Wv : Wo));
    bf16* Wt       = z == 0 ? Wqt : (z == 1 ? Wkt : (z == 2 ? Wvt : Wot));
    __shared__ float t[32][33];
    int tx = threadIdx.x, ty = threadIdx.y;
    int n0 = blockIdx.x * 32, k0 = blockIdx.y * 32;
    for (int j = 0; j < 32; j += 8)
        t[ty + j][tx] = W[(size_t)(k0 + ty + j) * D_ + n0 + tx];
    __syncthreads();
    for (int j = 0; j < 32; j += 8)
        Wt[(size_t)(n0 + ty + j) * D_ + k0 + tx] = __float2bfloat16(t[tx][ty + j]);
}

// ---------------------------------------------------------------------------
// Generic GEMM (128x128 tile, 4 waves, BK=32, padded LDS, high occupancy).
// Used for MLP1 (GELU epilogue). Proven ~25 µs class at full wave occupancy.
// ---------------------------------------------------------------------------
#define BM 128
#define BN 128
#define BK 32
#define LDK 40            // padded LDS row length in bf16 elems (80 B)

template<bool GELU, bool RESID, bool ROWMASK, bool OUTBF>
__global__ __launch_bounds__(256) void gemm_bt(
    const bf16* __restrict__ A, const bf16* __restrict__ Bt,
    const float* __restrict__ bias, const float* __restrict__ resid,
    const float* __restrict__ rowmask,
    bf16* __restrict__ outb, float* __restrict__ outf,
    int Mr, int Nn, int K)
{
    __shared__ bf16 As[BM * LDK];
    __shared__ bf16 Bs[BN * LDK];
    int t = threadIdx.x;
    int lane = t & 63, wave = t >> 6;
    int wm = wave >> 1, wn = wave & 1;
    int r16 = lane & 15, g = lane >> 4;
    int m0 = blockIdx.x * BM, n0 = blockIdx.y * BN;
    f32x4 acc[4][4] = {};
    for (int k0 = 0; k0 < K; k0 += BK) {
        __syncthreads();
        for (int it = 0; it < 2; ++it) {
            int c = it * 256 + t;
            int row = c >> 2, ko = (c & 3) * 8;
            uint4 dA = *(const uint4*)(A  + (size_t)(m0 + row) * K + k0 + ko);
            *(uint4*)((char*)As + row * (LDK * 2) + ko * 2) = dA;
            uint4 dB = *(const uint4*)(Bt + (size_t)(n0 + row) * K + k0 + ko);
            *(uint4*)((char*)Bs + row * (LDK * 2) + ko * 2) = dB;
        }
        __syncthreads();
        bf16x8 af[4], bfr[4];
        for (int i = 0; i < 4; ++i)
            af[i]  = *(const bf16x8*)((char*)As + (wm * 64 + i * 16 + r16) * (LDK * 2) + g * 16);
        for (int i = 0; i < 4; ++i)
            bfr[i] = *(const bf16x8*)((char*)Bs + (wn * 64 + i * 16 + r16) * (LDK * 2) + g * 16);
        for (int i = 0; i < 4; ++i)
            for (int j = 0; j < 4; ++j)
                acc[i][j] = __builtin_amdgcn_mfma_f32_16x16x32_bf16(af[i], bfr[j], acc[i][j], 0, 0, 0);
    }
    for (int i = 0; i < 4; ++i) {
        int rb = m0 + wm * 64 + i * 16 + g * 4;
        for (int j = 0; j < 4; ++j) {
            int cb = n0 + wn * 64 + j * 16 + r16;
            float bia = bias[cb];
            for (int e = 0; e < 4; ++e) {
                int rr = rb + e;
                float val = acc[i][j][e] + bia;
                if (GELU)    val = 0.5f * val * (1.f + erff(val * 0.70710678118654752f));
                if (RESID)   val += resid[(size_t)rr * Nn + cb];
                if (ROWMASK) val *= rowmask[rr];
                if (OUTBF)   outb[(size_t)rr * Nn + cb] = __float2bfloat16(val);
                else         outf[(size_t)rr * Nn + cb] = val;
            }
        }
    }
}

// ---------------------------------------------------------------------------
// 64x64-tile GEMM. 4 waves (2x2, each 32x32), BK=64, reg-staged
// double-buffered LDS, XOR-swizzled for conflict-free ds_read_b128.
// VTRANS epilogue (for V projection): write per-head transposed layout.
// ---------------------------------------------------------------------------
template<bool RESID, bool ROWMASK, bool OUTBF, bool VTRANS>
__device__ __forceinline__ void gemm64_body(
    const bf16* __restrict__ A, const bf16* __restrict__ Bt,
    const float* __restrict__ bias, const float* __restrict__ resid,
    const float* __restrict__ rowmask,
    bf16* __restrict__ outb, float* __restrict__ outf,
    int Nn, int K)
{
    __shared__ __align__(16) char As[2][64 * 128];
    __shared__ __align__(16) char Bs[2][64 * 128];
    int t = threadIdx.x, lane = t & 63, wave = t >> 6;
    int wm = wave >> 1, wn = wave & 1;
    int r16 = lane & 15, g = lane >> 4;
    int m0 = blockIdx.x * 64, n0 = blockIdx.y * 64;

    const int sr0 = t >> 3, sr1 = sr0 + 32, sc = t & 7;
    const int wof0 = sr0 * 128 + ((sc ^ (sr0 & 7)) << 4);
    const int wof1 = sr1 * 128 + ((sc ^ (sr1 & 7)) << 4);
    const int rsw0 = ((g     ^ (r16 & 7)) << 4);   // ks=0 chunk
    const int rsw1 = (((4 + g) ^ (r16 & 7)) << 4); // ks=1 chunk

    uint4 a0, a1, b0, b1;
#define G64_LOAD(k0)                                                         \
    a0 = *(const uint4*)(A  + (size_t)(m0 + sr0) * K + (k0) + sc * 8);       \
    a1 = *(const uint4*)(A  + (size_t)(m0 + sr1) * K + (k0) + sc * 8);       \
    b0 = *(const uint4*)(Bt + (size_t)(n0 + sr0) * K + (k0) + sc * 8);       \
    b1 = *(const uint4*)(Bt + (size_t)(n0 + sr1) * K + (k0) + sc * 8);
#define G64_WRITE(buf)                                                       \
    *(uint4*)(As[buf] + wof0) = a0;  *(uint4*)(As[buf] + wof1) = a1;         \
    *(uint4*)(Bs[buf] + wof0) = b0;  *(uint4*)(Bs[buf] + wof1) = b1;

    f32x4 acc[2][2] = {};
    G64_LOAD(0)
    G64_WRITE(0)
    int cur = 0;
    const int nit = K >> 6;
    for (int it = 0; it < nit; ++it) {
        if (it + 1 < nit) { G64_LOAD((it + 1) << 6) }
        __syncthreads();
        bf16x8 af[2][2], bfr[2][2];
#pragma unroll
        for (int i = 0; i < 2; ++i) {
            af[i][0] = *(const bf16x8*)(As[cur] + (wm * 32 + i * 16 + r16) * 128 + rsw0);
            af[i][1] = *(const bf16x8*)(As[cur] + (wm * 32 + i * 16 + r16) * 128 + rsw1);
            bfr[i][0] = *(const bf16x8*)(Bs[cur] + (wn * 32 + i * 16 + r16) * 128 + rsw0);
            bfr[i][1] = *(const bf16x8*)(Bs[cur] + (wn * 32 + i * 16 + r16) * 128 + rsw1);
        }
        __builtin_amdgcn_s_setprio(1);
#pragma unroll
        for (int i = 0; i < 2; ++i)
#pragma unroll
            for (int j = 0; j < 2; ++j) {
                acc[i][j] = __builtin_amdgcn_mfma_f32_16x16x32_bf16(af[i][0], bfr[j][0], acc[i][j], 0, 0, 0);
                acc[i][j] = __builtin_amdgcn_mfma_f32_16x16x32_bf16(af[i][1], bfr[j][1], acc[i][j], 0, 0, 0);
            }
        __builtin_amdgcn_s_setprio(0);
        if (it + 1 < nit) { G64_WRITE(cur ^ 1) }
        cur ^= 1;
    }
#undef G64_LOAD
#undef G64_WRITE

#pragma unroll
    for (int i = 0; i < 2; ++i) {
        int rb = m0 + wm * 32 + i * 16 + g * 4;
#pragma unroll
        for (int j = 0; j < 2; ++j) {
            int cb = n0 + wn * 32 + j * 16 + r16;
            float bia = bias[cb];
            if (VTRANS) {
                bf16x4v w;
#pragma unroll
                for (int e = 0; e < 4; ++e) {
                    int rr = rb + e;
                    float val = acc[i][j][e] + bia;
                    if (ROWMASK) val *= rowmask[rr];
                    w[e] = (__bf16)val;
                }
                int bb = rb >> 11, m = rb & (M_ - 1);
                int bh = bb * H_ + (cb >> 6), d = cb & (DH_ - 1);
                *(bf16x4v*)(outb + ((size_t)bh * DH_ + d) * M_ + m) = w;
            } else {
#pragma unroll
                for (int e = 0; e < 4; ++e) {
                    int rr = rb + e;
                    float val = acc[i][j][e] + bia;
                    if (RESID)   val += resid[(size_t)rr * Nn + cb];
                    if (ROWMASK) val *= rowmask[rr];
                    if (OUTBF)   outb[(size_t)rr * Nn + cb] = __float2bfloat16(val);
                    else         outf[(size_t)rr * Nn + cb] = val;
                }
            }
        }
    }
}

template<bool RESID, bool OUTBF>
__global__ __launch_bounds__(256) void gemm64(
    const bf16* __restrict__ A, const bf16* __restrict__ Bt,
    const float* __restrict__ bias, const float* __restrict__ resid,
    bf16* __restrict__ outb, float* __restrict__ outf, int Nn, int K)
{
    gemm64_body<RESID, false, OUTBF, false>(A, Bt, bias, resid, nullptr, outb, outf, Nn, K);
}

// Batched Q/K/V projection: z selects Q, K, or V; V writes transposed.
__global__ __launch_bounds__(256) void gemm64_qkv(
    const bf16* __restrict__ xn, const bf16* __restrict__ yn,
    const bf16* __restrict__ Wqt, const bf16* __restrict__ Wkt, const bf16* __restrict__ Wvt,
    const float* __restrict__ bq, const float* __restrict__ bk, const float* __restrict__ bv,
    const float* __restrict__ mask_x, const float* __restrict__ mask_y,
    bf16* __restrict__ qb, bf16* __restrict__ kb, bf16* __restrict__ vtb)
{
    int z = blockIdx.z;
    if (z == 2) {
        gemm64_body<false, true, true, true>(yn, Wvt, bv, nullptr, mask_y, vtb, nullptr, D_, D_);
    } else {
        const bf16* A        = z == 0 ? xn : yn;
        const bf16* Bt       = z == 0 ? Wqt : Wkt;
        const float* bias    = z == 0 ? bq  : bk;
        const float* rowmask = z == 0 ? mask_x : mask_y;
        bf16* outb           = z == 0 ? qb  : kb;
        gemm64_body<false, true, true, false>(A, Bt, bias, nullptr, rowmask, outb, nullptr, D_, D_);
    }
}

// ---------------------------------------------------------------------------
// Flash attention (swapped S^T = K*Q), LDS-staged double-buffered K/V with
// XOR swizzle, reg-staged. 1D grid, XCD-chunked remap. 4 waves, 32 q-rows
// each. T13 defer-max. bf16 numerator + per-row (m,l) f32.
// ---------------------------------------------------------------------------
__global__ __launch_bounds__(256, 3) void attn_kernel(
    const bf16* __restrict__ q, const bf16* __restrict__ kk,
    const bf16* __restrict__ vt, bf16* __restrict__ num,
    float* __restrict__ ml)
{
    int bid = blockIdx.x;
    int wg  = (bid & 7) * (ATT_GRID / 8) + (bid >> 3);
    int n0  = (wg & 15) * 128;
    int bh  = (wg >> 4) & 15;
    int sp  = wg >> 8;
    int b = bh >> 3, h = bh & 7;
    int t = threadIdx.x, lane = t & 63, wave = t >> 6;
    int ql = lane & 15, gg = lane >> 4;

    __shared__ __align__(16) char KsB[2][64 * 128];
    __shared__ __align__(16) char VsB[2][64 * 128];
    __shared__ __align__(16) bf16 plds[4][16][72];

    bf16x8 qf0[2], qf1[2];
    {
        int qr0 = b * N_ + n0 + wave * 32 + ql;
        for (int ks = 0; ks < 2; ++ks) {
            bf16x8 qv = *(const bf16x8*)(q + (size_t)qr0 * D_ + h * DH_ + ks * 32 + gg * 8);
            for (int j = 0; j < 8; ++j) qv[j] = (__bf16)((float)qv[j] * 0.125f);
            qf0[ks] = qv;
            bf16x8 qw = *(const bf16x8*)(q + (size_t)(qr0 + 16) * D_ + h * DH_ + ks * 32 + gg * 8);
            for (int j = 0; j < 8; ++j) qw[j] = (__bf16)((float)qw[j] * 0.125f);
            qf1[ks] = qw;
        }
    }

    f32x4 cacc0[4] = {}, cacc1[4] = {};
    float m0r = -1e30f, l0r = 0.f, m1r = -1e30f, l1r = 0.f;

    const bf16* kbase = kk + (size_t)(b * M_ + sp * KV_PER) * D_ + h * DH_;
    const bf16* vtb   = vt + (size_t)bh * DH_ * M_ + sp * KV_PER;

    const int k0r = t >> 3,          kc0 = t & 7;
    const int k1r = (t >> 3) + 32;
    const int wofs0 = k0r * 128 + ((kc0 ^ (k0r & 7)) << 4);
    const int wofs1 = k1r * 128 + ((kc0 ^ (k1r & 7)) << 4);
    const int rsw0 = ((gg     ^ (ql & 7)) << 4);
    const int rsw1 = (((4 + gg) ^ (ql & 7)) << 4);

#define STAGE_LOAD(tt)                                                              \
    kw0 = *(const uint4*)(kbase + (size_t)((tt) * 64 + k0r) * D_ + kc0 * 8);        \
    kw1 = *(const uint4*)(kbase + (size_t)((tt) * 64 + k1r) * D_ + kc0 * 8);        \
    vw0 = *(const uint4*)(vtb + (size_t)k0r * M_ + (tt) * 64 + kc0 * 8);            \
    vw1 = *(const uint4*)(vtb + (size_t)k1r * M_ + (tt) * 64 + kc0 * 8);

#define STAGE_WRITE(buf)                                                            \
    *(uint4*)(KsB[buf] + wofs0) = kw0;                                              \
    *(uint4*)(KsB[buf] + wofs1) = kw1;                                              \
    *(uint4*)(VsB[buf] + wofs0) = vw0;                                              \
    *(uint4*)(VsB[buf] + wofs1) = vw1;

#define SOFTMAX_PV(S, MR, LR, CACC)                                                 \
    {                                                                               \
        float tmax = fmaxf(                                                         \
            fmaxf(fmaxf(fmaxf(S[0][0], S[0][1]), fmaxf(S[0][2], S[0][3])),          \
                  fmaxf(fmaxf(S[1][0], S[1][1]), fmaxf(S[1][2], S[1][3]))),         \
            fmaxf(fmaxf(fmaxf(S[2][0], S[2][1]), fmaxf(S[2][2], S[2][3])),          \
                  fmaxf(fmaxf(S[3][0], S[3][1]), fmaxf(S[3][2], S[3][3]))));        \
        tmax = fmaxf(tmax, __shfl_xor(tmax, 16, 64));                               \
        tmax = fmaxf(tmax, __shfl_xor(tmax, 32, 64));                               \
        if (__any(tmax - MR > 8.f)) {                                               \
            float mnew = fmaxf(MR, tmax);                                           \
            float scl  = __expf(MR - mnew);                                         \
            MR = mnew;                                                              \
            LR *= scl;                                                              \
            for (int df = 0; df < 4; ++df)                                          \
                for (int e = 0; e < 4; ++e) CACC[df][e] *= scl;                     \
        }                                                                           \
        float p[4][4]; float ps = 0.f;                                              \
        for (int nf = 0; nf < 4; ++nf)                                              \
            for (int e = 0; e < 4; ++e) { p[nf][e] = __expf(S[nf][e] - MR); ps += p[nf][e]; } \
        ps += __shfl_xor(ps, 16, 64);                                               \
        ps += __shfl_xor(ps, 32, 64);                                               \
        LR += ps;                                                                   \
        for (int nf = 0; nf < 4; ++nf) {                                            \
            bf16x4v w;                                                              \
            w[0] = (__bf16)p[nf][0]; w[1] = (__bf16)p[nf][1];                       \
            w[2] = (__bf16)p[nf][2]; w[3] = (__bf16)p[nf][3];                       \
            *(bf16x4v*)(&plds[wave][ql][nf * 16 + 4 * gg]) = w;                     \
        }                                                                           \
        __builtin_amdgcn_s_setprio(1);                                              \
        for (int ks = 0; ks < 2; ++ks) {                                            \
            bf16x8 pf = *(const bf16x8*)((const char*)&plds[wave][0][0]             \
                                         + ql * 144 + ks * 64 + gg * 16);           \
            for (int df = 0; df < 4; ++df)                                          \
                CACC[df] = __builtin_amdgcn_mfma_f32_16x16x32_bf16(                 \
                    vf[df * 2 + ks], pf, CACC[df], 0, 0, 0);                        \
        }                                                                           \
        __builtin_amdgcn_s_setprio(0);                                              \
    }

    uint4 kw0, kw1, vw0, vw1;
    STAGE_LOAD(0)
    STAGE_WRITE(0)
    int cur = 0;

    for (int tt = 0; tt < NT; ++tt) {
        if (tt + 1 < NT) { STAGE_LOAD(tt + 1) }
        __syncthreads();

        const char* Kb = KsB[cur];
        const char* Vb = VsB[cur];

        bf16x8 kf[8];
#pragma unroll
        for (int nf = 0; nf < 4; ++nf) {
            kf[nf * 2 + 0] = *(const bf16x8*)(Kb + (nf * 16 + ql) * 128 + rsw0);
            kf[nf * 2 + 1] = *(const bf16x8*)(Kb + (nf * 16 + ql) * 128 + rsw1);
        }

        f32x4 s0[4] = {}, s1[4] = {};
        __builtin_amdgcn_s_setprio(1);
#pragma unroll
        for (int nf = 0; nf < 4; ++nf) {
            s0[nf] = __builtin_amdgcn_mfma_f32_16x16x32_bf16(kf[nf * 2 + 0], qf0[0], s0[nf], 0, 0, 0);
            s0[nf] = __builtin_amdgcn_mfma_f32_16x16x32_bf16(kf[nf * 2 + 1], qf0[1], s0[nf], 0, 0, 0);
            s1[nf] = __builtin_amdgcn_mfma_f32_16x16x32_bf16(kf[nf * 2 + 0], qf1[0], s1[nf], 0, 0, 0);
            s1[nf] = __builtin_amdgcn_mfma_f32_16x16x32_bf16(kf[nf * 2 + 1], qf1[1], s1[nf], 0, 0, 0);
        }
        __builtin_amdgcn_s_setprio(0);

        bf16x8 vf[8];
#pragma unroll
        for (int df = 0; df < 4; ++df) {
            vf[df * 2 + 0] = *(const bf16x8*)(Vb + (df * 16 + ql) * 128 + rsw0);
            vf[df * 2 + 1] = *(const bf16x8*)(Vb + (df * 16 + ql) * 128 + rsw1);
        }

        SOFTMAX_PV(s0, m0r, l0r, cacc0)
        SOFTMAX_PV(s1, m1r, l1r, cacc1)

        if (tt + 1 < NT) { STAGE_WRITE(cur ^ 1) }
        cur ^= 1;
    }

    {
        int qr0 = b * N_ + n0 + wave * 32 + ql;
        bf16* nb0 = num + (size_t)sp * ROWS * D_ + (size_t)qr0 * D_ + h * DH_;
        bf16* nb1 = num + (size_t)sp * ROWS * D_ + (size_t)(qr0 + 16) * D_ + h * DH_;
#pragma unroll
        for (int df = 0; df < 4; ++df) {
            bf16x4v w0, w1;
#pragma unroll
            for (int e = 0; e < 4; ++e) {
                w0[e] = (__bf16)cacc0[df][e];
                w1[e] = (__bf16)cacc1[df][e];
            }
            *(bf16x4v*)(nb0 + df * 16 + 4 * gg) = w0;
            *(bf16x4v*)(nb1 + df * 16 + 4 * gg) = w1;
        }
        if (lane < 16) {
            size_t base = ((size_t)(sp * (B_ * H_) + bh) * N_ + (n0 + wave * 32 + ql)) * 2;
            ml[base] = m0r; ml[base + 1] = l0r;
            size_t base1 = ((size_t)(sp * (B_ * H_) + bh) * N_ + (n0 + wave * 32 + 16 + ql)) * 2;
            ml[base1] = m1r; ml[base1 + 1] = l1r;
        }
    }
#undef STAGE_LOAD
#undef STAGE_WRITE
#undef SOFTMAX_PV
}

// Combine the SPLIT partials (bf16 numerators) -> bf16 ctx
__global__ __launch_bounds__(256) void attn_combine(
    const bf16* __restrict__ num, const float* __restrict__ ml,
    bf16* __restrict__ ctx)
{
    int idx = blockIdx.x * 256 + threadIdx.x;
    int row = idx >> 7;
    int c4  = (idx & 127) << 2;
    int b = row >> 11, n = row & (N_ - 1);
    int h = c4 >> 6;
    int bh = (b << 3) + h;
    float mv[SPLIT], lv[SPLIT];
#pragma unroll
    for (int sp = 0; sp < SPLIT; ++sp) {
        const float* mp = ml + ((size_t)(sp * (B_ * H_) + bh) * N_ + n) * 2;
        mv[sp] = mp[0]; lv[sp] = mp[1];
    }
    float mx = mv[0];
#pragma unroll
    for (int sp = 1; sp < SPLIT; ++sp) mx = fmaxf(mx, mv[sp]);
    float den = 0.f;
    float wsc[SPLIT];
#pragma unroll
    for (int sp = 0; sp < SPLIT; ++sp) {
        wsc[sp] = __expf(mv[sp] - mx);
        den += wsc[sp] * lv[sp];
    }
    float inv = 1.f / den;
    float ax = 0.f, ay = 0.f, az = 0.f, aw = 0.f;
#pragma unroll
    for (int sp = 0; sp < SPLIT; ++sp) {
        bf16x4v v = *(const bf16x4v*)(num + (size_t)sp * ROWS * D_ + (size_t)row * D_ + c4);
        ax += wsc[sp] * (float)v[0]; ay += wsc[sp] * (float)v[1];
        az += wsc[sp] * (float)v[2]; aw += wsc[sp] * (float)v[3];
    }
    bf16* o = ctx + (size_t)row * D_ + c4;
    o[0] = __float2bfloat16(ax * inv);
    o[1] = __float2bfloat16(ay * inv);
    o[2] = __float2bfloat16(az * inv);
    o[3] = __float2bfloat16(aw * inv);
}

// ---------------------------------------------------------------------------
extern "C" void kernel_launch(void* const* d_in, const int* in_sizes, int n_in,
                              void* d_out, int out_size, void* d_ws, size_t ws_size,
                              hipStream_t stream)
{
    const float* x      = (const float*)d_in[0];
    const float* y      = (const float*)d_in[1];
    const float* mask_x = (const float*)d_in[2];
    const float* mask_y = (const float*)d_in[3];
    const float* Wq = (const float*)d_in[4];  const float* bq = (const float*)d_in[5];
    const float* Wk = (const float*)d_in[6];  const float* bk = (const float*)d_in[7];
    const float* Wv = (const float*)d_in[8];  const float* bv = (const float*)d_in[9];
    const float* Wo = (const float*)d_in[10]; const float* bo = (const float*)d_in[11];
    const float* W1 = (const float*)d_in[12]; const float* b1 = (const float*)d_in[13];
    const float* W2 = (const float*)d_in[14]; const float* b2 = (const float*)d_in[15];
    const float* ln1g = (const float*)d_in[16]; const float* ln1b = (const float*)d_in[17];
    const float* ln2g = (const float*)d_in[18]; const float* ln2b = (const float*)d_in[19];

    char* ws = (char*)d_ws;
    const size_t SZA = (size_t)ROWS * D_ * 2;     // 4 MiB bf16 activation
    bf16* xn   = (bf16*)ws;            ws += SZA;
    bf16* yn   = (bf16*)ws;            ws += SZA;
    bf16* qb   = (bf16*)ws;            ws += SZA;
    bf16* kb   = (bf16*)ws;            ws += SZA;
    bf16* vtb  = (bf16*)ws;            ws += SZA;
    bf16* ctxb = (bf16*)ws;            ws += SZA;
    bf16* xn2  = (bf16*)ws;            ws += SZA;
    bf16* hff  = (bf16*)ws;            ws += (size_t)ROWS * F_ * 2;
    float* x1  = (float*)ws;           ws += (size_t)ROWS * D_ * 4;
    bf16* Wqt = (bf16*)ws;             ws += (size_t)D_ * D_ * 2;
    bf16* Wkt = (bf16*)ws;             ws += (size_t)D_ * D_ * 2;
    bf16* Wvt = (bf16*)ws;             ws += (size_t)D_ * D_ * 2;
    bf16* Wot = (bf16*)ws;             ws += (size_t)D_ * D_ * 2;
    bf16* W1t = (bf16*)ws;             ws += (size_t)D_ * F_ * 2;
    bf16* W2t = (bf16*)ws;             ws += (size_t)F_ * D_ * 2;
    bf16* numb = (bf16*)ws;            ws += (size_t)SPLIT * ROWS * D_ * 2;
    float* mlb = (float*)ws;           ws += (size_t)SPLIT * B_ * H_ * N_ * 2 * 4;

    dim3 tb(32, 8);
    wtrans4_kernel<<<dim3(D_ / 32, D_ / 32, 4), tb, 0, stream>>>(
        Wq, Wk, Wv, Wo, Wqt, Wkt, Wvt, Wot);
    wtrans_kernel<<<dim3(F_ / 32, D_ / 32), tb, 0, stream>>>(W1, W1t, D_, F_);
    wtrans_kernel<<<dim3(D_ / 32, F_ / 32), tb, 0, stream>>>(W2, W2t, F_, D_);

    // LN(x) and LN(y) in one launch
    ln12_kernel<<<2 * ROWS / 4, 256, 0, stream>>>(x, y, ln1g, ln1b, xn, yn);

    // Q/K/V projections; V written directly in per-head transposed layout
    gemm64_qkv<<<dim3(ROWS / 64, D_ / 64, 3), 256, 0, stream>>>(
        xn, yn, Wqt, Wkt, Wvt, bq, bk, bv, mask_x, mask_y, qb, kb, vtb);

    attn_kernel<<<ATT_GRID, 256, 0, stream>>>(qb, kb, vtb, numb, mlb);
    attn_combine<<<(ROWS * D_ / 4) / 256, 256, 0, stream>>>(numb, mlb, ctxb);

    // out-proj + residual(x) -> x1 (f32)
    gemm64<true, false><<<dim3(ROWS / 64, D_ / 64), 256, 0, stream>>>(
        ctxb, Wot, bo, x, nullptr, x1, D_, D_);

    ln_kernel<<<ROWS / 4, 256, 0, stream>>>(x1, ln2g, ln2b, xn2);

    // MLP1 + GELU -> hff (bf16), proven high-occupancy 128x128/BK=32 kernel
    gemm_bt<true, false, false, true><<<dim3(ROWS / BM, F_ / BN), 256, 0, stream>>>(
        xn2, W1t, b1, nullptr, nullptr, hff, nullptr, ROWS, F_, D_);

    // MLP2 + residual(x1) -> d_out (f32)
    gemm64<true, false><<<dim3(ROWS / 64, D_ / 64), 256, 0, stream>>>(
        hff, W2t, b2, x1, nullptr, (float*)d_out, D_, F_);
}

// Round 11
// 121.509 us; speedup vs baseline: 1.2000x; 1.0166x over previous
//
#include <hip/hip_runtime.h>
#include <hip/hip_bf16.h>

// Problem constants
#define B_  2
#define N_  2048
#define M_  2048
#define D_  512
#define H_  8
#define F_  2048
#define DH_ 64
#define ROWS 4096   // B_*N_ == B_*M_

#define SPLIT 2
#define KV_PER (M_ / SPLIT)   // 1024
#define NT (KV_PER / 64)      // 16 tiles of 64 keys
#define ATT_GRID (16 * 16 * SPLIT)   // n0(16) x bh(16) x sp

typedef __bf16 bf16x8 __attribute__((ext_vector_type(8)));
typedef __bf16 bf16x4v __attribute__((ext_vector_type(4)));
typedef float  f32x4  __attribute__((ext_vector_type(4)));
using bf16 = __hip_bfloat16;

// ---------------------------------------------------------------------------
// LayerNorm over x and y (f32 in) in one launch.
// ---------------------------------------------------------------------------
__global__ __launch_bounds__(256) void ln12_kernel(
    const float* __restrict__ xi, const float* __restrict__ yi,
    const float* __restrict__ gam, const float* __restrict__ bet,
    bf16* __restrict__ xo, bf16* __restrict__ yo)
{
    int wave = threadIdx.x >> 6, lane = threadIdx.x & 63;
    int grow = blockIdx.x * 4 + wave;
    const float* in;
    bf16* out;
    int row;
    if (grow < ROWS) { in = xi; out = xo; row = grow; }
    else             { in = yi; out = yo; row = grow - ROWS; }
    const float* p = in + (size_t)row * D_ + lane * 8;
    float4 v0 = *(const float4*)p;
    float4 v1 = *(const float4*)(p + 4);
    float s  = v0.x + v0.y + v0.z + v0.w + v1.x + v1.y + v1.z + v1.w;
    float ss = v0.x*v0.x + v0.y*v0.y + v0.z*v0.z + v0.w*v0.w
             + v1.x*v1.x + v1.y*v1.y + v1.z*v1.z + v1.w*v1.w;
    for (int m = 1; m < 64; m <<= 1) {
        s  += __shfl_xor(s,  m, 64);
        ss += __shfl_xor(ss, m, 64);
    }
    float mu   = s * (1.f / D_);
    float var  = ss * (1.f / D_) - mu * mu;
    float rstd = rsqrtf(var + 1e-6f);
    int c = lane * 8;
    float4 g0 = *(const float4*)(gam + c), g1 = *(const float4*)(gam + c + 4);
    float4 b0 = *(const float4*)(bet + c), b1 = *(const float4*)(bet + c + 4);
    bf16* o = out + (size_t)row * D_ + c;
    o[0] = __float2bfloat16((v0.x - mu) * rstd * g0.x + b0.x);
    o[1] = __float2bfloat16((v0.y - mu) * rstd * g0.y + b0.y);
    o[2] = __float2bfloat16((v0.z - mu) * rstd * g0.z + b0.z);
    o[3] = __float2bfloat16((v0.w - mu) * rstd * g0.w + b0.w);
    o[4] = __float2bfloat16((v1.x - mu) * rstd * g1.x + b1.x);
    o[5] = __float2bfloat16((v1.y - mu) * rstd * g1.y + b1.y);
    o[6] = __float2bfloat16((v1.z - mu) * rstd * g1.z + b1.z);
    o[7] = __float2bfloat16((v1.w - mu) * rstd * g1.w + b1.w);
}

// LayerNorm, bf16 input (for x1 -> xn2)
__global__ __launch_bounds__(256) void lnb_kernel(
    const bf16* __restrict__ in, const float* __restrict__ gam,
    const float* __restrict__ bet, bf16* __restrict__ out)
{
    int wave = threadIdx.x >> 6, lane = threadIdx.x & 63;
    int row  = blockIdx.x * 4 + wave;
    bf16x8 v = *(const bf16x8*)(in + (size_t)row * D_ + lane * 8);
    float f[8];
    float s = 0.f, ss = 0.f;
#pragma unroll
    for (int j = 0; j < 8; ++j) {
        f[j] = (float)v[j];
        s += f[j]; ss += f[j] * f[j];
    }
    for (int m = 1; m < 64; m <<= 1) {
        s  += __shfl_xor(s,  m, 64);
        ss += __shfl_xor(ss, m, 64);
    }
    float mu   = s * (1.f / D_);
    float var  = ss * (1.f / D_) - mu * mu;
    float rstd = rsqrtf(var + 1e-6f);
    int c = lane * 8;
    float4 g0 = *(const float4*)(gam + c), g1 = *(const float4*)(gam + c + 4);
    float4 b0 = *(const float4*)(bet + c), b1 = *(const float4*)(bet + c + 4);
    bf16* o = out + (size_t)row * D_ + c;
    o[0] = __float2bfloat16((f[0] - mu) * rstd * g0.x + b0.x);
    o[1] = __float2bfloat16((f[1] - mu) * rstd * g0.y + b0.y);
    o[2] = __float2bfloat16((f[2] - mu) * rstd * g0.z + b0.z);
    o[3] = __float2bfloat16((f[3] - mu) * rstd * g0.w + b0.w);
    o[4] = __float2bfloat16((f[4] - mu) * rstd * g1.x + b1.x);
    o[5] = __float2bfloat16((f[5] - mu) * rstd * g1.y + b1.y);
    o[6] = __float2bfloat16((f[6] - mu) * rstd * g1.z + b1.z);
    o[7] = __float2bfloat16((f[7] - mu) * rstd * g1.w + b1.w);
}

// ---------------------------------------------------------------------------
// Weight transpose + cast: W[K,N] f32 -> Wt[N,K] bf16.  block (32,8)
// ---------------------------------------------------------------------------
__global__ void wtrans_kernel(const float* __restrict__ W, bf16* __restrict__ Wt,
                              int K, int N)
{
    __shared__ float t[32][33];
    int tx = threadIdx.x, ty = threadIdx.y;
    int n0 = blockIdx.x * 32, k0 = blockIdx.y * 32;
    for (int j = 0; j < 32; j += 8)
        t[ty + j][tx] = W[(size_t)(k0 + ty + j) * N + n0 + tx];
    __syncthreads();
    for (int j = 0; j < 32; j += 8)
        Wt[(size_t)(n0 + ty + j) * K + k0 + tx] = __float2bfloat16(t[tx][ty + j]);
}

// Batched square (512x512) weight transpose: z picks which of the 4 weights.
__global__ void wtrans4_kernel(const float* __restrict__ Wq, const float* __restrict__ Wk,
                               const float* __restrict__ Wv, const float* __restrict__ Wo,
                               bf16* __restrict__ Wqt, bf16* __restrict__ Wkt,
                               bf16* __restrict__ Wvt, bf16* __restrict__ Wot)
{
    int z = blockIdx.z;
    const float* W = z == 0 ? Wq : (z == 1 ? Wk : (z == 2 ? Wv : Wo));
    bf16* Wt       = z == 0 ? Wqt : (z == 1 ? Wkt : (z == 2 ? Wvt : Wot));
    __shared__ float t[32][33];
    int tx = threadIdx.x, ty = threadIdx.y;
    int n0 = blockIdx.x * 32, k0 = blockIdx.y * 32;
    for (int j = 0; j < 32; j += 8)
        t[ty + j][tx] = W[(size_t)(k0 + ty + j) * D_ + n0 + tx];
    __syncthreads();
    for (int j = 0; j < 32; j += 8)
        Wt[(size_t)(n0 + ty + j) * D_ + k0 + tx] = __float2bfloat16(t[tx][ty + j]);
}

// ---------------------------------------------------------------------------
// MLP1 GEMM, m97 structure: 128x128 tile, BK=32, global_load_lds width=16
// into LINEAR LDS (wave-uniform dest base + lane*16), single-buffered.
// GELU epilogue, bf16 out.
// ---------------------------------------------------------------------------
__global__ __launch_bounds__(256) void gemm_glds_gelu(
    const bf16* __restrict__ A, const bf16* __restrict__ Bt,
    const float* __restrict__ bias, bf16* __restrict__ outb,
    int Nn, int K)
{
    __shared__ __align__(16) bf16 As[128 * 32];   // [row][32 k] 64B rows
    __shared__ __align__(16) bf16 Bs[128 * 32];
    int t = threadIdx.x, lane = t & 63, wave = t >> 6;
    int wm = wave >> 1, wn = wave & 1;
    int r16 = lane & 15, g = lane >> 4;
    int m0 = blockIdx.x * 128, n0 = blockIdx.y * 128;

    const int srow = wave * 32;          // this wave's 32-row slice
    const int lrow = lane >> 2;          // 0..15 within a 16-row instr
    const int lcol = (lane & 3) * 8;     // bf16 elems (16B chunks)

    f32x4 acc[4][4] = {};
    for (int k0 = 0; k0 < K; k0 += 32) {
        __syncthreads();   // previous iter's reads done before overwrite
#pragma unroll
        for (int j = 0; j < 2; ++j) {
            const bf16* gpA = A + (size_t)(m0 + srow + j * 16 + lrow) * K + k0 + lcol;
            __builtin_amdgcn_global_load_lds(
                (const __attribute__((address_space(1))) void*)gpA,
                (__attribute__((address_space(3))) void*)(As + (srow + j * 16) * 32),
                16, 0, 0);
            const bf16* gpB = Bt + (size_t)(n0 + srow + j * 16 + lrow) * K + k0 + lcol;
            __builtin_amdgcn_global_load_lds(
                (const __attribute__((address_space(1))) void*)gpB,
                (__attribute__((address_space(3))) void*)(Bs + (srow + j * 16) * 32),
                16, 0, 0);
        }
        __syncthreads();   // vmcnt(0) drain + all writes visible
        bf16x8 af[4], bfr[4];
#pragma unroll
        for (int i = 0; i < 4; ++i) {
            af[i]  = *(const bf16x8*)((const char*)As + (wm * 64 + i * 16 + r16) * 64 + g * 16);
            bfr[i] = *(const bf16x8*)((const char*)Bs + (wn * 64 + i * 16 + r16) * 64 + g * 16);
        }
        __builtin_amdgcn_s_setprio(1);
#pragma unroll
        for (int i = 0; i < 4; ++i)
#pragma unroll
            for (int j = 0; j < 4; ++j)
                acc[i][j] = __builtin_amdgcn_mfma_f32_16x16x32_bf16(af[i], bfr[j], acc[i][j], 0, 0, 0);
        __builtin_amdgcn_s_setprio(0);
    }

#pragma unroll
    for (int i = 0; i < 4; ++i) {
        int rb = m0 + wm * 64 + i * 16 + g * 4;
#pragma unroll
        for (int j = 0; j < 4; ++j) {
            int cb = n0 + wn * 64 + j * 16 + r16;
            float bia = bias[cb];
#pragma unroll
            for (int e = 0; e < 4; ++e) {
                float val = acc[i][j][e] + bia;
                val = 0.5f * val * (1.f + erff(val * 0.70710678118654752f));
                outb[(size_t)(rb + e) * Nn + cb] = __float2bfloat16(val);
            }
        }
    }
}

// ---------------------------------------------------------------------------
// 64x64-tile GEMM. 4 waves (2x2, each 32x32), BK=64, reg-staged
// double-buffered LDS, XOR-swizzled. VTRANS epilogue for V projection.
// RESIDBF: residual read as bf16.
// ---------------------------------------------------------------------------
template<bool RESID, bool RESIDBF, bool ROWMASK, bool OUTBF, bool VTRANS>
__device__ __forceinline__ void gemm64_body(
    const bf16* __restrict__ A, const bf16* __restrict__ Bt,
    const float* __restrict__ bias, const float* __restrict__ resid,
    const bf16* __restrict__ residb, const float* __restrict__ rowmask,
    bf16* __restrict__ outb, float* __restrict__ outf,
    int Nn, int K)
{
    __shared__ __align__(16) char As[2][64 * 128];
    __shared__ __align__(16) char Bs[2][64 * 128];
    int t = threadIdx.x, lane = t & 63, wave = t >> 6;
    int wm = wave >> 1, wn = wave & 1;
    int r16 = lane & 15, g = lane >> 4;
    int m0 = blockIdx.x * 64, n0 = blockIdx.y * 64;

    const int sr0 = t >> 3, sr1 = sr0 + 32, sc = t & 7;
    const int wof0 = sr0 * 128 + ((sc ^ (sr0 & 7)) << 4);
    const int wof1 = sr1 * 128 + ((sc ^ (sr1 & 7)) << 4);
    const int rsw0 = ((g     ^ (r16 & 7)) << 4);
    const int rsw1 = (((4 + g) ^ (r16 & 7)) << 4);

    uint4 a0, a1, b0, b1;
#define G64_LOAD(k0)                                                         \
    a0 = *(const uint4*)(A  + (size_t)(m0 + sr0) * K + (k0) + sc * 8);       \
    a1 = *(const uint4*)(A  + (size_t)(m0 + sr1) * K + (k0) + sc * 8);       \
    b0 = *(const uint4*)(Bt + (size_t)(n0 + sr0) * K + (k0) + sc * 8);       \
    b1 = *(const uint4*)(Bt + (size_t)(n0 + sr1) * K + (k0) + sc * 8);
#define G64_WRITE(buf)                                                       \
    *(uint4*)(As[buf] + wof0) = a0;  *(uint4*)(As[buf] + wof1) = a1;         \
    *(uint4*)(Bs[buf] + wof0) = b0;  *(uint4*)(Bs[buf] + wof1) = b1;

    f32x4 acc[2][2] = {};
    G64_LOAD(0)
    G64_WRITE(0)
    int cur = 0;
    const int nit = K >> 6;
    for (int it = 0; it < nit; ++it) {
        if (it + 1 < nit) { G64_LOAD((it + 1) << 6) }
        __syncthreads();
        bf16x8 af[2][2], bfr[2][2];
#pragma unroll
        for (int i = 0; i < 2; ++i) {
            af[i][0] = *(const bf16x8*)(As[cur] + (wm * 32 + i * 16 + r16) * 128 + rsw0);
            af[i][1] = *(const bf16x8*)(As[cur] + (wm * 32 + i * 16 + r16) * 128 + rsw1);
            bfr[i][0] = *(const bf16x8*)(Bs[cur] + (wn * 32 + i * 16 + r16) * 128 + rsw0);
            bfr[i][1] = *(const bf16x8*)(Bs[cur] + (wn * 32 + i * 16 + r16) * 128 + rsw1);
        }
        __builtin_amdgcn_s_setprio(1);
#pragma unroll
        for (int i = 0; i < 2; ++i)
#pragma unroll
            for (int j = 0; j < 2; ++j) {
                acc[i][j] = __builtin_amdgcn_mfma_f32_16x16x32_bf16(af[i][0], bfr[j][0], acc[i][j], 0, 0, 0);
                acc[i][j] = __builtin_amdgcn_mfma_f32_16x16x32_bf16(af[i][1], bfr[j][1], acc[i][j], 0, 0, 0);
            }
        __builtin_amdgcn_s_setprio(0);
        if (it + 1 < nit) { G64_WRITE(cur ^ 1) }
        cur ^= 1;
    }
#undef G64_LOAD
#undef G64_WRITE

#pragma unroll
    for (int i = 0; i < 2; ++i) {
        int rb = m0 + wm * 32 + i * 16 + g * 4;
#pragma unroll
        for (int j = 0; j < 2; ++j) {
            int cb = n0 + wn * 32 + j * 16 + r16;
            float bia = bias[cb];
            if (VTRANS) {
                bf16x4v w;
#pragma unroll
                for (int e = 0; e < 4; ++e) {
                    int rr = rb + e;
                    float val = acc[i][j][e] + bia;
                    if (ROWMASK) val *= rowmask[rr];
                    w[e] = (__bf16)val;
                }
                int bb = rb >> 11, m = rb & (M_ - 1);
                int bh = bb * H_ + (cb >> 6), d = cb & (DH_ - 1);
                *(bf16x4v*)(outb + ((size_t)bh * DH_ + d) * M_ + m) = w;
            } else {
#pragma unroll
                for (int e = 0; e < 4; ++e) {
                    int rr = rb + e;
                    float val = acc[i][j][e] + bia;
                    if (RESID) {
                        if (RESIDBF) val += (float)residb[(size_t)rr * Nn + cb];
                        else         val += resid[(size_t)rr * Nn + cb];
                    }
                    if (ROWMASK) val *= rowmask[rr];
                    if (OUTBF)   outb[(size_t)rr * Nn + cb] = __float2bfloat16(val);
                    else         outf[(size_t)rr * Nn + cb] = val;
                }
            }
        }
    }
}

// Wo projection: resid = x (f32), out = x1 bf16
__global__ __launch_bounds__(256) void gemm64_wo(
    const bf16* __restrict__ A, const bf16* __restrict__ Bt,
    const float* __restrict__ bias, const float* __restrict__ resid,
    bf16* __restrict__ outb, int Nn, int K)
{
    gemm64_body<true, false, false, true, false>(A, Bt, bias, resid, nullptr, nullptr,
                                                 outb, nullptr, Nn, K);
}

// MLP2: resid = x1 (bf16), out = d_out f32
__global__ __launch_bounds__(256) void gemm64_mlp2(
    const bf16* __restrict__ A, const bf16* __restrict__ Bt,
    const float* __restrict__ bias, const bf16* __restrict__ residb,
    float* __restrict__ outf, int Nn, int K)
{
    gemm64_body<true, true, false, false, false>(A, Bt, bias, nullptr, residb, nullptr,
                                                 nullptr, outf, Nn, K);
}

// Batched Q/K/V projection: z selects Q, K, or V; V writes transposed.
__global__ __launch_bounds__(256) void gemm64_qkv(
    const bf16* __restrict__ xn, const bf16* __restrict__ yn,
    const bf16* __restrict__ Wqt, const bf16* __restrict__ Wkt, const bf16* __restrict__ Wvt,
    const float* __restrict__ bq, const float* __restrict__ bk, const float* __restrict__ bv,
    const float* __restrict__ mask_x, const float* __restrict__ mask_y,
    bf16* __restrict__ qb, bf16* __restrict__ kb, bf16* __restrict__ vtb)
{
    int z = blockIdx.z;
    if (z == 2) {
        gemm64_body<false, false, true, true, true>(yn, Wvt, bv, nullptr, nullptr, mask_y,
                                                    vtb, nullptr, D_, D_);
    } else {
        const bf16* A        = z == 0 ? xn : yn;
        const bf16* Bt       = z == 0 ? Wqt : Wkt;
        const float* bias    = z == 0 ? bq  : bk;
        const float* rowmask = z == 0 ? mask_x : mask_y;
        bf16* outb           = z == 0 ? qb  : kb;
        gemm64_body<false, false, true, true, false>(A, Bt, bias, nullptr, nullptr, rowmask,
                                                     outb, nullptr, D_, D_);
    }
}

// ---------------------------------------------------------------------------
// Flash attention (swapped S^T = K*Q), LDS-staged double-buffered K/V with
// XOR swizzle, reg-staged. 1D grid, XCD-chunked remap. 4 waves, 32 q-rows
// each. T13 defer-max. bf16 numerator + per-row (m,l) f32.
// ---------------------------------------------------------------------------
__global__ __launch_bounds__(256, 3) void attn_kernel(
    const bf16* __restrict__ q, const bf16* __restrict__ kk,
    const bf16* __restrict__ vt, bf16* __restrict__ num,
    float* __restrict__ ml)
{
    int bid = blockIdx.x;
    int wg  = (bid & 7) * (ATT_GRID / 8) + (bid >> 3);
    int n0  = (wg & 15) * 128;
    int bh  = (wg >> 4) & 15;
    int sp  = wg >> 8;
    int b = bh >> 3, h = bh & 7;
    int t = threadIdx.x, lane = t & 63, wave = t >> 6;
    int ql = lane & 15, gg = lane >> 4;

    __shared__ __align__(16) char KsB[2][64 * 128];
    __shared__ __align__(16) char VsB[2][64 * 128];
    __shared__ __align__(16) bf16 plds[4][16][72];

    bf16x8 qf0[2], qf1[2];
    {
        int qr0 = b * N_ + n0 + wave * 32 + ql;
        for (int ks = 0; ks < 2; ++ks) {
            bf16x8 qv = *(const bf16x8*)(q + (size_t)qr0 * D_ + h * DH_ + ks * 32 + gg * 8);
            for (int j = 0; j < 8; ++j) qv[j] = (__bf16)((float)qv[j] * 0.125f);
            qf0[ks] = qv;
            bf16x8 qw = *(const bf16x8*)(q + (size_t)(qr0 + 16) * D_ + h * DH_ + ks * 32 + gg * 8);
            for (int j = 0; j < 8; ++j) qw[j] = (__bf16)((float)qw[j] * 0.125f);
            qf1[ks] = qw;
        }
    }

    f32x4 cacc0[4] = {}, cacc1[4] = {};
    float m0r = -1e30f, l0r = 0.f, m1r = -1e30f, l1r = 0.f;

    const bf16* kbase = kk + (size_t)(b * M_ + sp * KV_PER) * D_ + h * DH_;
    const bf16* vtb   = vt + (size_t)bh * DH_ * M_ + sp * KV_PER;

    const int k0r = t >> 3,          kc0 = t & 7;
    const int k1r = (t >> 3) + 32;
    const int wofs0 = k0r * 128 + ((kc0 ^ (k0r & 7)) << 4);
    const int wofs1 = k1r * 128 + ((kc0 ^ (k1r & 7)) << 4);
    const int rsw0 = ((gg     ^ (ql & 7)) << 4);
    const int rsw1 = (((4 + gg) ^ (ql & 7)) << 4);

#define STAGE_LOAD(tt)                                                              \
    kw0 = *(const uint4*)(kbase + (size_t)((tt) * 64 + k0r) * D_ + kc0 * 8);        \
    kw1 = *(const uint4*)(kbase + (size_t)((tt) * 64 + k1r) * D_ + kc0 * 8);        \
    vw0 = *(const uint4*)(vtb + (size_t)k0r * M_ + (tt) * 64 + kc0 * 8);            \
    vw1 = *(const uint4*)(vtb + (size_t)k1r * M_ + (tt) * 64 + kc0 * 8);

#define STAGE_WRITE(buf)                                                            \
    *(uint4*)(KsB[buf] + wofs0) = kw0;                                              \
    *(uint4*)(KsB[buf] + wofs1) = kw1;                                              \
    *(uint4*)(VsB[buf] + wofs0) = vw0;                                              \
    *(uint4*)(VsB[buf] + wofs1) = vw1;

#define SOFTMAX_PV(S, MR, LR, CACC)                                                 \
    {                                                                               \
        float tmax = fmaxf(                                                         \
            fmaxf(fmaxf(fmaxf(S[0][0], S[0][1]), fmaxf(S[0][2], S[0][3])),          \
                  fmaxf(fmaxf(S[1][0], S[1][1]), fmaxf(S[1][2], S[1][3]))),         \
            fmaxf(fmaxf(fmaxf(S[2][0], S[2][1]), fmaxf(S[2][2], S[2][3])),          \
                  fmaxf(fmaxf(S[3][0], S[3][1]), fmaxf(S[3][2], S[3][3]))));        \
        tmax = fmaxf(tmax, __shfl_xor(tmax, 16, 64));                               \
        tmax = fmaxf(tmax, __shfl_xor(tmax, 32, 64));                               \
        if (__any(tmax - MR > 8.f)) {                                               \
            float mnew = fmaxf(MR, tmax);                                           \
            float scl  = __expf(MR - mnew);                                         \
            MR = mnew;                                                              \
            LR *= scl;                                                              \
            for (int df = 0; df < 4; ++df)                                          \
                for (int e = 0; e < 4; ++e) CACC[df][e] *= scl;                     \
        }                                                                           \
        float p[4][4]; float ps = 0.f;                                              \
        for (int nf = 0; nf < 4; ++nf)                                              \
            for (int e = 0; e < 4; ++e) { p[nf][e] = __expf(S[nf][e] - MR); ps += p[nf][e]; } \
        ps += __shfl_xor(ps, 16, 64);                                               \
        ps += __shfl_xor(ps, 32, 64);                                               \
        LR += ps;                                                                   \
        for (int nf = 0; nf < 4; ++nf) {                                            \
            bf16x4v w;                                                              \
            w[0] = (__bf16)p[nf][0]; w[1] = (__bf16)p[nf][1];                       \
            w[2] = (__bf16)p[nf][2]; w[3] = (__bf16)p[nf][3];                       \
            *(bf16x4v*)(&plds[wave][ql][nf * 16 + 4 * gg]) = w;                     \
        }                                                                           \
        __builtin_amdgcn_s_setprio(1);                                              \
        for (int ks = 0; ks < 2; ++ks) {                                            \
            bf16x8 pf = *(const bf16x8*)((const char*)&plds[wave][0][0]             \
                                         + ql * 144 + ks * 64 + gg * 16);           \
            for (int df = 0; df < 4; ++df)                                          \
                CACC[df] = __builtin_amdgcn_mfma_f32_16x16x32_bf16(                 \
                    vf[df * 2 + ks], pf, CACC[df], 0, 0, 0);                        \
        }                                                                           \
        __builtin_amdgcn_s_setprio(0);                                              \
    }

    uint4 kw0, kw1, vw0, vw1;
    STAGE_LOAD(0)
    STAGE_WRITE(0)
    int cur = 0;

    for (int tt = 0; tt < NT; ++tt) {
        if (tt + 1 < NT) { STAGE_LOAD(tt + 1) }
        __syncthreads();

        const char* Kb = KsB[cur];
        const char* Vb = VsB[cur];

        bf16x8 kf[8];
#pragma unroll
        for (int nf = 0; nf < 4; ++nf) {
            kf[nf * 2 + 0] = *(const bf16x8*)(Kb + (nf * 16 + ql) * 128 + rsw0);
            kf[nf * 2 + 1] = *(const bf16x8*)(Kb + (nf * 16 + ql) * 128 + rsw1);
        }

        f32x4 s0[4] = {}, s1[4] = {};
        __builtin_amdgcn_s_setprio(1);
#pragma unroll
        for (int nf = 0; nf < 4; ++nf) {
            s0[nf] = __builtin_amdgcn_mfma_f32_16x16x32_bf16(kf[nf * 2 + 0], qf0[0], s0[nf], 0, 0, 0);
            s0[nf] = __builtin_amdgcn_mfma_f32_16x16x32_bf16(kf[nf * 2 + 1], qf0[1], s0[nf], 0, 0, 0);
            s1[nf] = __builtin_amdgcn_mfma_f32_16x16x32_bf16(kf[nf * 2 + 0], qf1[0], s1[nf], 0, 0, 0);
            s1[nf] = __builtin_amdgcn_mfma_f32_16x16x32_bf16(kf[nf * 2 + 1], qf1[1], s1[nf], 0, 0, 0);
        }
        __builtin_amdgcn_s_setprio(0);

        bf16x8 vf[8];
#pragma unroll
        for (int df = 0; df < 4; ++df) {
            vf[df * 2 + 0] = *(const bf16x8*)(Vb + (df * 16 + ql) * 128 + rsw0);
            vf[df * 2 + 1] = *(const bf16x8*)(Vb + (df * 16 + ql) * 128 + rsw1);
        }

        SOFTMAX_PV(s0, m0r, l0r, cacc0)
        SOFTMAX_PV(s1, m1r, l1r, cacc1)

        if (tt + 1 < NT) { STAGE_WRITE(cur ^ 1) }
        cur ^= 1;
    }

    {
        int qr0 = b * N_ + n0 + wave * 32 + ql;
        bf16* nb0 = num + (size_t)sp * ROWS * D_ + (size_t)qr0 * D_ + h * DH_;
        bf16* nb1 = num + (size_t)sp * ROWS * D_ + (size_t)(qr0 + 16) * D_ + h * DH_;
#pragma unroll
        for (int df = 0; df < 4; ++df) {
            bf16x4v w0, w1;
#pragma unroll
            for (int e = 0; e < 4; ++e) {
                w0[e] = (__bf16)cacc0[df][e];
                w1[e] = (__bf16)cacc1[df][e];
            }
            *(bf16x4v*)(nb0 + df * 16 + 4 * gg) = w0;
            *(bf16x4v*)(nb1 + df * 16 + 4 * gg) = w1;
        }
        if (lane < 16) {
            size_t base = ((size_t)(sp * (B_ * H_) + bh) * N_ + (n0 + wave * 32 + ql)) * 2;
            ml[base] = m0r; ml[base + 1] = l0r;
            size_t base1 = ((size_t)(sp * (B_ * H_) + bh) * N_ + (n0 + wave * 32 + 16 + ql)) * 2;
            ml[base1] = m1r; ml[base1 + 1] = l1r;
        }
    }
#undef STAGE_LOAD
#undef STAGE_WRITE
#undef SOFTMAX_PV
}

// Combine the SPLIT partials (bf16 numerators) -> bf16 ctx
__global__ __launch_bounds__(256) void attn_combine(
    const bf16* __restrict__ num, const float* __restrict__ ml,
    bf16* __restrict__ ctx)
{
    int idx = blockIdx.x * 256 + threadIdx.x;
    int row = idx >> 7;
    int c4  = (idx & 127) << 2;
    int b = row >> 11, n = row & (N_ - 1);
    int h = c4 >> 6;
    int bh = (b << 3) + h;
    float mv[SPLIT], lv[SPLIT];
#pragma unroll
    for (int sp = 0; sp < SPLIT; ++sp) {
        const float* mp = ml + ((size_t)(sp * (B_ * H_) + bh) * N_ + n) * 2;
        mv[sp] = mp[0]; lv[sp] = mp[1];
    }
    float mx = mv[0];
#pragma unroll
    for (int sp = 1; sp < SPLIT; ++sp) mx = fmaxf(mx, mv[sp]);
    float den = 0.f;
    float wsc[SPLIT];
#pragma unroll
    for (int sp = 0; sp < SPLIT; ++sp) {
        wsc[sp] = __expf(mv[sp] - mx);
        den += wsc[sp] * lv[sp];
    }
    float inv = 1.f / den;
    float ax = 0.f, ay = 0.f, az = 0.f, aw = 0.f;
#pragma unroll
    for (int sp = 0; sp < SPLIT; ++sp) {
        bf16x4v v = *(const bf16x4v*)(num + (size_t)sp * ROWS * D_ + (size_t)row * D_ + c4);
        ax += wsc[sp] * (float)v[0]; ay += wsc[sp] * (float)v[1];
        az += wsc[sp] * (float)v[2]; aw += wsc[sp] * (float)v[3];
    }
    bf16* o = ctx + (size_t)row * D_ + c4;
    o[0] = __float2bfloat16(ax * inv);
    o[1] = __float2bfloat16(ay * inv);
    o[2] = __float2bfloat16(az * inv);
    o[3] = __float2bfloat16(aw * inv);
}

// ---------------------------------------------------------------------------
extern "C" void kernel_launch(void* const* d_in, const int* in_sizes, int n_in,
                              void* d_out, int out_size, void* d_ws, size_t ws_size,
                              hipStream_t stream)
{
    const float* x      = (const float*)d_in[0];
    const float* y      = (const float*)d_in[1];
    const float* mask_x = (const float*)d_in[2];
    const float* mask_y = (const float*)d_in[3];
    const float* Wq = (const float*)d_in[4];  const float* bq = (const float*)d_in[5];
    const float* Wk = (const float*)d_in[6];  const float* bk = (const float*)d_in[7];
    const float* Wv = (const float*)d_in[8];  const float* bv = (const float*)d_in[9];
    const float* Wo = (const float*)d_in[10]; const float* bo = (const float*)d_in[11];
    const float* W1 = (const float*)d_in[12]; const float* b1 = (const float*)d_in[13];
    const float* W2 = (const float*)d_in[14]; const float* b2 = (const float*)d_in[15];
    const float* ln1g = (const float*)d_in[16]; const float* ln1b = (const float*)d_in[17];
    const float* ln2g = (const float*)d_in[18]; const float* ln2b = (const float*)d_in[19];

    char* ws = (char*)d_ws;
    const size_t SZA = (size_t)ROWS * D_ * 2;     // 4 MiB bf16 activation
    bf16* xn   = (bf16*)ws;            ws += SZA;
    bf16* yn   = (bf16*)ws;            ws += SZA;
    bf16* qb   = (bf16*)ws;            ws += SZA;
    bf16* kb   = (bf16*)ws;            ws += SZA;
    bf16* vtb  = (bf16*)ws;            ws += SZA;
    bf16* ctxb = (bf16*)ws;            ws += SZA;
    bf16* xn2  = (bf16*)ws;            ws += SZA;
    bf16* x1b  = (bf16*)ws;            ws += SZA;
    bf16* hff  = (bf16*)ws;            ws += (size_t)ROWS * F_ * 2;
    bf16* Wqt = (bf16*)ws;             ws += (size_t)D_ * D_ * 2;
    bf16* Wkt = (bf16*)ws;             ws += (size_t)D_ * D_ * 2;
    bf16* Wvt = (bf16*)ws;             ws += (size_t)D_ * D_ * 2;
    bf16* Wot = (bf16*)ws;             ws += (size_t)D_ * D_ * 2;
    bf16* W1t = (bf16*)ws;             ws += (size_t)D_ * F_ * 2;
    bf16* W2t = (bf16*)ws;             ws += (size_t)F_ * D_ * 2;
    bf16* numb = (bf16*)ws;            ws += (size_t)SPLIT * ROWS * D_ * 2;
    float* mlb = (float*)ws;           ws += (size_t)SPLIT * B_ * H_ * N_ * 2 * 4;

    dim3 tb(32, 8);
    wtrans4_kernel<<<dim3(D_ / 32, D_ / 32, 4), tb, 0, stream>>>(
        Wq, Wk, Wv, Wo, Wqt, Wkt, Wvt, Wot);
    wtrans_kernel<<<dim3(F_ / 32, D_ / 32), tb, 0, stream>>>(W1, W1t, D_, F_);
    wtrans_kernel<<<dim3(D_ / 32, F_ / 32), tb, 0, stream>>>(W2, W2t, F_, D_);

    // LN(x) and LN(y) in one launch
    ln12_kernel<<<2 * ROWS / 4, 256, 0, stream>>>(x, y, ln1g, ln1b, xn, yn);

    // Q/K/V projections; V written directly in per-head transposed layout
    gemm64_qkv<<<dim3(ROWS / 64, D_ / 64, 3), 256, 0, stream>>>(
        xn, yn, Wqt, Wkt, Wvt, bq, bk, bv, mask_x, mask_y, qb, kb, vtb);

    attn_kernel<<<ATT_GRID, 256, 0, stream>>>(qb, kb, vtb, numb, mlb);
    attn_combine<<<(ROWS * D_ / 4) / 256, 256, 0, stream>>>(numb, mlb, ctxb);

    // out-proj + residual(x f32) -> x1 (bf16)
    gemm64_wo<<<dim3(ROWS / 64, D_ / 64), 256, 0, stream>>>(
        ctxb, Wot, bo, x, x1b, D_, D_);

    // ln2 on bf16 x1
    lnb_kernel<<<ROWS / 4, 256, 0, stream>>>(x1b, ln2g, ln2b, xn2);

    // MLP1 + GELU -> hff (bf16), m97-structure glds kernel (512 blocks)
    gemm_glds_gelu<<<dim3(ROWS / 128, F_ / 128), 256, 0, stream>>>(
        xn2, W1t, b1, hff, F_, D_);

    // MLP2 + residual(x1 bf16) -> d_out (f32)
    gemm64_mlp2<<<dim3(ROWS / 64, D_ / 64), 256, 0, stream>>>(
        hff, W2t, b2, x1b, (float*)d_out, D_, F_);
}

// Round 12
// 119.929 us; speedup vs baseline: 1.2158x; 1.0132x over previous
//
#include <hip/hip_runtime.h>
#include <hip/hip_bf16.h>

// Problem constants
#define B_  2
#define N_  2048
#define M_  2048
#define D_  512
#define H_  8
#define F_  2048
#define DH_ 64
#define ROWS 4096   // B_*N_ == B_*M_

#define SPLIT 2
#define KV_PER (M_ / SPLIT)   // 1024
#define NT (KV_PER / 64)      // 16 tiles of 64 keys
#define ATT_GRID (16 * 16 * SPLIT)   // n0(16) x bh(16) x sp

#define QSCALE (0.125f * 1.44269504088896f)   // 1/sqrt(dh) * log2(e): exp2 domain

typedef __bf16 bf16x8 __attribute__((ext_vector_type(8)));
typedef __bf16 bf16x4v __attribute__((ext_vector_type(4)));
typedef float  f32x4  __attribute__((ext_vector_type(4)));
using bf16 = __hip_bfloat16;

// ---------------------------------------------------------------------------
// Fused prep: blocks 0..3071 = weight transposes (f32->bf16, W[K,N]->Wt[N,K]);
// blocks 3072..5119 = LayerNorm of x and y.
// ---------------------------------------------------------------------------
__global__ __launch_bounds__(256) void prep_kernel(
    const float* __restrict__ Wq, const float* __restrict__ Wk,
    const float* __restrict__ Wv, const float* __restrict__ Wo,
    const float* __restrict__ W1, const float* __restrict__ W2,
    bf16* __restrict__ Wqt, bf16* __restrict__ Wkt,
    bf16* __restrict__ Wvt, bf16* __restrict__ Wot,
    bf16* __restrict__ W1t, bf16* __restrict__ W2t,
    const float* __restrict__ x, const float* __restrict__ y,
    const float* __restrict__ ln1g, const float* __restrict__ ln1b,
    bf16* __restrict__ xn, bf16* __restrict__ yn)
{
    __shared__ float tle[32][33];
    int id = blockIdx.x;
    if (id < 3072) {
        const float* W; bf16* Wt; int K, N, n0, k0;
        if (id < 1024) {
            int z = id >> 8, xy = id & 255;
            W  = z == 0 ? Wq  : (z == 1 ? Wk  : (z == 2 ? Wv  : Wo));
            Wt = z == 0 ? Wqt : (z == 1 ? Wkt : (z == 2 ? Wvt : Wot));
            K = D_; N = D_;
            n0 = (xy & 15) * 32; k0 = (xy >> 4) * 32;
        } else if (id < 2048) {
            int local = id - 1024;
            W = W1; Wt = W1t; K = D_; N = F_;
            n0 = (local & 63) * 32; k0 = (local >> 6) * 32;
        } else {
            int local = id - 2048;
            W = W2; Wt = W2t; K = F_; N = D_;
            n0 = (local & 15) * 32; k0 = (local >> 4) * 32;
        }
        int tx = threadIdx.x & 31, ty = threadIdx.x >> 5;
        for (int j = 0; j < 32; j += 8)
            tle[ty + j][tx] = W[(size_t)(k0 + ty + j) * N + n0 + tx];
        __syncthreads();
        for (int j = 0; j < 32; j += 8)
            Wt[(size_t)(n0 + ty + j) * K + k0 + tx] = __float2bfloat16(tle[tx][ty + j]);
    } else {
        int wave = threadIdx.x >> 6, lane = threadIdx.x & 63;
        int grow = (id - 3072) * 4 + wave;
        const float* in;
        bf16* out;
        int row;
        if (grow < ROWS) { in = x; out = xn; row = grow; }
        else             { in = y; out = yn; row = grow - ROWS; }
        const float* p = in + (size_t)row * D_ + lane * 8;
        float4 v0 = *(const float4*)p;
        float4 v1 = *(const float4*)(p + 4);
        float s  = v0.x + v0.y + v0.z + v0.w + v1.x + v1.y + v1.z + v1.w;
        float ss = v0.x*v0.x + v0.y*v0.y + v0.z*v0.z + v0.w*v0.w
                 + v1.x*v1.x + v1.y*v1.y + v1.z*v1.z + v1.w*v1.w;
        for (int m = 1; m < 64; m <<= 1) {
            s  += __shfl_xor(s,  m, 64);
            ss += __shfl_xor(ss, m, 64);
        }
        float mu   = s * (1.f / D_);
        float var  = ss * (1.f / D_) - mu * mu;
        float rstd = rsqrtf(var + 1e-6f);
        int c = lane * 8;
        float4 g0 = *(const float4*)(ln1g + c), g1 = *(const float4*)(ln1g + c + 4);
        float4 b0 = *(const float4*)(ln1b + c), b1 = *(const float4*)(ln1b + c + 4);
        bf16* o = out + (size_t)row * D_ + c;
        o[0] = __float2bfloat16((v0.x - mu) * rstd * g0.x + b0.x);
        o[1] = __float2bfloat16((v0.y - mu) * rstd * g0.y + b0.y);
        o[2] = __float2bfloat16((v0.z - mu) * rstd * g0.z + b0.z);
        o[3] = __float2bfloat16((v0.w - mu) * rstd * g0.w + b0.w);
        o[4] = __float2bfloat16((v1.x - mu) * rstd * g1.x + b1.x);
        o[5] = __float2bfloat16((v1.y - mu) * rstd * g1.y + b1.y);
        o[6] = __float2bfloat16((v1.z - mu) * rstd * g1.z + b1.z);
        o[7] = __float2bfloat16((v1.w - mu) * rstd * g1.w + b1.w);
    }
}

// LayerNorm, bf16 input (for x1 -> xn2)
__global__ __launch_bounds__(256) void lnb_kernel(
    const bf16* __restrict__ in, const float* __restrict__ gam,
    const float* __restrict__ bet, bf16* __restrict__ out)
{
    int wave = threadIdx.x >> 6, lane = threadIdx.x & 63;
    int row  = blockIdx.x * 4 + wave;
    bf16x8 v = *(const bf16x8*)(in + (size_t)row * D_ + lane * 8);
    float f[8];
    float s = 0.f, ss = 0.f;
#pragma unroll
    for (int j = 0; j < 8; ++j) {
        f[j] = (float)v[j];
        s += f[j]; ss += f[j] * f[j];
    }
    for (int m = 1; m < 64; m <<= 1) {
        s  += __shfl_xor(s,  m, 64);
        ss += __shfl_xor(ss, m, 64);
    }
    float mu   = s * (1.f / D_);
    float var  = ss * (1.f / D_) - mu * mu;
    float rstd = rsqrtf(var + 1e-6f);
    int c = lane * 8;
    float4 g0 = *(const float4*)(gam + c), g1 = *(const float4*)(gam + c + 4);
    float4 b0 = *(const float4*)(bet + c), b1 = *(const float4*)(bet + c + 4);
    bf16* o = out + (size_t)row * D_ + c;
    o[0] = __float2bfloat16((f[0] - mu) * rstd * g0.x + b0.x);
    o[1] = __float2bfloat16((f[1] - mu) * rstd * g0.y + b0.y);
    o[2] = __float2bfloat16((f[2] - mu) * rstd * g0.z + b0.z);
    o[3] = __float2bfloat16((f[3] - mu) * rstd * g0.w + b0.w);
    o[4] = __float2bfloat16((f[4] - mu) * rstd * g1.x + b1.x);
    o[5] = __float2bfloat16((f[5] - mu) * rstd * g1.y + b1.y);
    o[6] = __float2bfloat16((f[6] - mu) * rstd * g1.z + b1.z);
    o[7] = __float2bfloat16((f[7] - mu) * rstd * g1.w + b1.w);
}

// ---------------------------------------------------------------------------
// MLP1 GEMM, m97 structure: 128x128 tile, BK=32, global_load_lds width=16
// into LINEAR LDS, single-buffered. GELU epilogue, bf16 out.
// ---------------------------------------------------------------------------
__global__ __launch_bounds__(256) void gemm_glds_gelu(
    const bf16* __restrict__ A, const bf16* __restrict__ Bt,
    const float* __restrict__ bias, bf16* __restrict__ outb,
    int Nn, int K)
{
    __shared__ __align__(16) bf16 As[128 * 32];   // [row][32 k] 64B rows
    __shared__ __align__(16) bf16 Bs[128 * 32];
    int t = threadIdx.x, lane = t & 63, wave = t >> 6;
    int wm = wave >> 1, wn = wave & 1;
    int r16 = lane & 15, g = lane >> 4;
    int m0 = blockIdx.x * 128, n0 = blockIdx.y * 128;

    const int srow = wave * 32;
    const int lrow = lane >> 2;
    const int lcol = (lane & 3) * 8;

    f32x4 acc[4][4] = {};
    for (int k0 = 0; k0 < K; k0 += 32) {
        __syncthreads();
#pragma unroll
        for (int j = 0; j < 2; ++j) {
            const bf16* gpA = A + (size_t)(m0 + srow + j * 16 + lrow) * K + k0 + lcol;
            __builtin_amdgcn_global_load_lds(
                (const __attribute__((address_space(1))) void*)gpA,
                (__attribute__((address_space(3))) void*)(As + (srow + j * 16) * 32),
                16, 0, 0);
            const bf16* gpB = Bt + (size_t)(n0 + srow + j * 16 + lrow) * K + k0 + lcol;
            __builtin_amdgcn_global_load_lds(
                (const __attribute__((address_space(1))) void*)gpB,
                (__attribute__((address_space(3))) void*)(Bs + (srow + j * 16) * 32),
                16, 0, 0);
        }
        __syncthreads();
        bf16x8 af[4], bfr[4];
#pragma unroll
        for (int i = 0; i < 4; ++i) {
            af[i]  = *(const bf16x8*)((const char*)As + (wm * 64 + i * 16 + r16) * 64 + g * 16);
            bfr[i] = *(const bf16x8*)((const char*)Bs + (wn * 64 + i * 16 + r16) * 64 + g * 16);
        }
        __builtin_amdgcn_s_setprio(1);
#pragma unroll
        for (int i = 0; i < 4; ++i)
#pragma unroll
            for (int j = 0; j < 4; ++j)
                acc[i][j] = __builtin_amdgcn_mfma_f32_16x16x32_bf16(af[i], bfr[j], acc[i][j], 0, 0, 0);
        __builtin_amdgcn_s_setprio(0);
    }

#pragma unroll
    for (int i = 0; i < 4; ++i) {
        int rb = m0 + wm * 64 + i * 16 + g * 4;
#pragma unroll
        for (int j = 0; j < 4; ++j) {
            int cb = n0 + wn * 64 + j * 16 + r16;
            float bia = bias[cb];
#pragma unroll
            for (int e = 0; e < 4; ++e) {
                float val = acc[i][j][e] + bia;
                val = 0.5f * val * (1.f + erff(val * 0.70710678118654752f));
                outb[(size_t)(rb + e) * Nn + cb] = __float2bfloat16(val);
            }
        }
    }
}

// ---------------------------------------------------------------------------
// 64x64-tile GEMM. 4 waves (2x2, each 32x32), BK=64, reg-staged
// double-buffered LDS, XOR-swizzled. VTRANS epilogue for V projection.
// ---------------------------------------------------------------------------
template<bool RESID, bool RESIDBF, bool ROWMASK, bool OUTBF, bool VTRANS>
__device__ __forceinline__ void gemm64_body(
    const bf16* __restrict__ A, const bf16* __restrict__ Bt,
    const float* __restrict__ bias, const float* __restrict__ resid,
    const bf16* __restrict__ residb, const float* __restrict__ rowmask,
    bf16* __restrict__ outb, float* __restrict__ outf,
    int Nn, int K)
{
    __shared__ __align__(16) char As[2][64 * 128];
    __shared__ __align__(16) char Bs[2][64 * 128];
    int t = threadIdx.x, lane = t & 63, wave = t >> 6;
    int wm = wave >> 1, wn = wave & 1;
    int r16 = lane & 15, g = lane >> 4;
    int m0 = blockIdx.x * 64, n0 = blockIdx.y * 64;

    const int sr0 = t >> 3, sr1 = sr0 + 32, sc = t & 7;
    const int wof0 = sr0 * 128 + ((sc ^ (sr0 & 7)) << 4);
    const int wof1 = sr1 * 128 + ((sc ^ (sr1 & 7)) << 4);
    const int rsw0 = ((g     ^ (r16 & 7)) << 4);
    const int rsw1 = (((4 + g) ^ (r16 & 7)) << 4);

    uint4 a0, a1, b0, b1;
#define G64_LOAD(k0)                                                         \
    a0 = *(const uint4*)(A  + (size_t)(m0 + sr0) * K + (k0) + sc * 8);       \
    a1 = *(const uint4*)(A  + (size_t)(m0 + sr1) * K + (k0) + sc * 8);       \
    b0 = *(const uint4*)(Bt + (size_t)(n0 + sr0) * K + (k0) + sc * 8);       \
    b1 = *(const uint4*)(Bt + (size_t)(n0 + sr1) * K + (k0) + sc * 8);
#define G64_WRITE(buf)                                                       \
    *(uint4*)(As[buf] + wof0) = a0;  *(uint4*)(As[buf] + wof1) = a1;         \
    *(uint4*)(Bs[buf] + wof0) = b0;  *(uint4*)(Bs[buf] + wof1) = b1;

    f32x4 acc[2][2] = {};
    G64_LOAD(0)
    G64_WRITE(0)
    int cur = 0;
    const int nit = K >> 6;
    for (int it = 0; it < nit; ++it) {
        if (it + 1 < nit) { G64_LOAD((it + 1) << 6) }
        __syncthreads();
        bf16x8 af[2][2], bfr[2][2];
#pragma unroll
        for (int i = 0; i < 2; ++i) {
            af[i][0] = *(const bf16x8*)(As[cur] + (wm * 32 + i * 16 + r16) * 128 + rsw0);
            af[i][1] = *(const bf16x8*)(As[cur] + (wm * 32 + i * 16 + r16) * 128 + rsw1);
            bfr[i][0] = *(const bf16x8*)(Bs[cur] + (wn * 32 + i * 16 + r16) * 128 + rsw0);
            bfr[i][1] = *(const bf16x8*)(Bs[cur] + (wn * 32 + i * 16 + r16) * 128 + rsw1);
        }
        __builtin_amdgcn_s_setprio(1);
#pragma unroll
        for (int i = 0; i < 2; ++i)
#pragma unroll
            for (int j = 0; j < 2; ++j) {
                acc[i][j] = __builtin_amdgcn_mfma_f32_16x16x32_bf16(af[i][0], bfr[j][0], acc[i][j], 0, 0, 0);
                acc[i][j] = __builtin_amdgcn_mfma_f32_16x16x32_bf16(af[i][1], bfr[j][1], acc[i][j], 0, 0, 0);
            }
        __builtin_amdgcn_s_setprio(0);
        if (it + 1 < nit) { G64_WRITE(cur ^ 1) }
        cur ^= 1;
    }
#undef G64_LOAD
#undef G64_WRITE

#pragma unroll
    for (int i = 0; i < 2; ++i) {
        int rb = m0 + wm * 32 + i * 16 + g * 4;
#pragma unroll
        for (int j = 0; j < 2; ++j) {
            int cb = n0 + wn * 32 + j * 16 + r16;
            float bia = bias[cb];
            if (VTRANS) {
                bf16x4v w;
#pragma unroll
                for (int e = 0; e < 4; ++e) {
                    int rr = rb + e;
                    float val = acc[i][j][e] + bia;
                    if (ROWMASK) val *= rowmask[rr];
                    w[e] = (__bf16)val;
                }
                int bb = rb >> 11, m = rb & (M_ - 1);
                int bh = bb * H_ + (cb >> 6), d = cb & (DH_ - 1);
                *(bf16x4v*)(outb + ((size_t)bh * DH_ + d) * M_ + m) = w;
            } else {
#pragma unroll
                for (int e = 0; e < 4; ++e) {
                    int rr = rb + e;
                    float val = acc[i][j][e] + bia;
                    if (RESID) {
                        if (RESIDBF) val += (float)residb[(size_t)rr * Nn + cb];
                        else         val += resid[(size_t)rr * Nn + cb];
                    }
                    if (ROWMASK) val *= rowmask[rr];
                    if (OUTBF)   outb[(size_t)rr * Nn + cb] = __float2bfloat16(val);
                    else         outf[(size_t)rr * Nn + cb] = val;
                }
            }
        }
    }
}

// Wo projection: resid = x (f32), out = x1 bf16
__global__ __launch_bounds__(256) void gemm64_wo(
    const bf16* __restrict__ A, const bf16* __restrict__ Bt,
    const float* __restrict__ bias, const float* __restrict__ resid,
    bf16* __restrict__ outb, int Nn, int K)
{
    gemm64_body<true, false, false, true, false>(A, Bt, bias, resid, nullptr, nullptr,
                                                 outb, nullptr, Nn, K);
}

// MLP2: resid = x1 (bf16), out = d_out f32
__global__ __launch_bounds__(256) void gemm64_mlp2(
    const bf16* __restrict__ A, const bf16* __restrict__ Bt,
    const float* __restrict__ bias, const bf16* __restrict__ residb,
    float* __restrict__ outf, int Nn, int K)
{
    gemm64_body<true, true, false, false, false>(A, Bt, bias, nullptr, residb, nullptr,
                                                 nullptr, outf, Nn, K);
}

// Batched Q/K/V projection: z selects Q, K, or V; V writes transposed.
__global__ __launch_bounds__(256) void gemm64_qkv(
    const bf16* __restrict__ xn, const bf16* __restrict__ yn,
    const bf16* __restrict__ Wqt, const bf16* __restrict__ Wkt, const bf16* __restrict__ Wvt,
    const float* __restrict__ bq, const float* __restrict__ bk, const float* __restrict__ bv,
    const float* __restrict__ mask_x, const float* __restrict__ mask_y,
    bf16* __restrict__ qb, bf16* __restrict__ kb, bf16* __restrict__ vtb)
{
    int z = blockIdx.z;
    if (z == 2) {
        gemm64_body<false, false, true, true, true>(yn, Wvt, bv, nullptr, nullptr, mask_y,
                                                    vtb, nullptr, D_, D_);
    } else {
        const bf16* A        = z == 0 ? xn : yn;
        const bf16* Bt       = z == 0 ? Wqt : Wkt;
        const float* bias    = z == 0 ? bq  : bk;
        const float* rowmask = z == 0 ? mask_x : mask_y;
        bf16* outb           = z == 0 ? qb  : kb;
        gemm64_body<false, false, true, true, false>(A, Bt, bias, nullptr, nullptr, rowmask,
                                                     outb, nullptr, D_, D_);
    }
}

// ---------------------------------------------------------------------------
// Flash attention (swapped S^T = K*Q), LDS-staged double-buffered K/V with
// XOR swizzle, reg-staged. 1D grid, XCD-chunked remap. 4 waves, 32 q-rows
// each. exp2-domain softmax (log2e folded into Q scale), T13 defer-max.
// bf16 numerator + per-row (m,l) f32 (m in log2 domain).
// ---------------------------------------------------------------------------
__global__ __launch_bounds__(256, 3) void attn_kernel(
    const bf16* __restrict__ q, const bf16* __restrict__ kk,
    const bf16* __restrict__ vt, bf16* __restrict__ num,
    float* __restrict__ ml)
{
    int bid = blockIdx.x;
    int wg  = (bid & 7) * (ATT_GRID / 8) + (bid >> 3);
    int n0  = (wg & 15) * 128;
    int bh  = (wg >> 4) & 15;
    int sp  = wg >> 8;
    int b = bh >> 3, h = bh & 7;
    int t = threadIdx.x, lane = t & 63, wave = t >> 6;
    int ql = lane & 15, gg = lane >> 4;

    __shared__ __align__(16) char KsB[2][64 * 128];
    __shared__ __align__(16) char VsB[2][64 * 128];
    __shared__ __align__(16) bf16 plds[4][16][72];

    bf16x8 qf0[2], qf1[2];
    {
        int qr0 = b * N_ + n0 + wave * 32 + ql;
        for (int ks = 0; ks < 2; ++ks) {
            bf16x8 qv = *(const bf16x8*)(q + (size_t)qr0 * D_ + h * DH_ + ks * 32 + gg * 8);
            for (int j = 0; j < 8; ++j) qv[j] = (__bf16)((float)qv[j] * QSCALE);
            qf0[ks] = qv;
            bf16x8 qw = *(const bf16x8*)(q + (size_t)(qr0 + 16) * D_ + h * DH_ + ks * 32 + gg * 8);
            for (int j = 0; j < 8; ++j) qw[j] = (__bf16)((float)qw[j] * QSCALE);
            qf1[ks] = qw;
        }
    }

    f32x4 cacc0[4] = {}, cacc1[4] = {};
    float m0r = -1e30f, l0r = 0.f, m1r = -1e30f, l1r = 0.f;

    const bf16* kbase = kk + (size_t)(b * M_ + sp * KV_PER) * D_ + h * DH_;
    const bf16* vtb   = vt + (size_t)bh * DH_ * M_ + sp * KV_PER;

    const int k0r = t >> 3,          kc0 = t & 7;
    const int k1r = (t >> 3) + 32;
    const int wofs0 = k0r * 128 + ((kc0 ^ (k0r & 7)) << 4);
    const int wofs1 = k1r * 128 + ((kc0 ^ (k1r & 7)) << 4);
    const int rsw0 = ((gg     ^ (ql & 7)) << 4);
    const int rsw1 = (((4 + gg) ^ (ql & 7)) << 4);

#define STAGE_LOAD(tt)                                                              \
    kw0 = *(const uint4*)(kbase + (size_t)((tt) * 64 + k0r) * D_ + kc0 * 8);        \
    kw1 = *(const uint4*)(kbase + (size_t)((tt) * 64 + k1r) * D_ + kc0 * 8);        \
    vw0 = *(const uint4*)(vtb + (size_t)k0r * M_ + (tt) * 64 + kc0 * 8);            \
    vw1 = *(const uint4*)(vtb + (size_t)k1r * M_ + (tt) * 64 + kc0 * 8);

#define STAGE_WRITE(buf)                                                            \
    *(uint4*)(KsB[buf] + wofs0) = kw0;                                              \
    *(uint4*)(KsB[buf] + wofs1) = kw1;                                              \
    *(uint4*)(VsB[buf] + wofs0) = vw0;                                              \
    *(uint4*)(VsB[buf] + wofs1) = vw1;

#define SOFTMAX_PV(S, MR, LR, CACC)                                                 \
    {                                                                               \
        float tmax = fmaxf(                                                         \
            fmaxf(fmaxf(fmaxf(S[0][0], S[0][1]), fmaxf(S[0][2], S[0][3])),          \
                  fmaxf(fmaxf(S[1][0], S[1][1]), fmaxf(S[1][2], S[1][3]))),         \
            fmaxf(fmaxf(fmaxf(S[2][0], S[2][1]), fmaxf(S[2][2], S[2][3])),          \
                  fmaxf(fmaxf(S[3][0], S[3][1]), fmaxf(S[3][2], S[3][3]))));        \
        tmax = fmaxf(tmax, __shfl_xor(tmax, 16, 64));                               \
        tmax = fmaxf(tmax, __shfl_xor(tmax, 32, 64));                               \
        if (__any(tmax - MR > 11.f)) {      /* defer-max, THR=11 bits */            \
            float mnew = fmaxf(MR, tmax);                                           \
            float scl  = exp2f(MR - mnew);                                          \
            MR = mnew;                                                              \
            LR *= scl;                                                              \
            for (int df = 0; df < 4; ++df)                                          \
                for (int e = 0; e < 4; ++e) CACC[df][e] *= scl;                     \
        }                                                                           \
        float p[4][4]; float ps = 0.f;                                              \
        for (int nf = 0; nf < 4; ++nf)                                              \
            for (int e = 0; e < 4; ++e) { p[nf][e] = exp2f(S[nf][e] - MR); ps += p[nf][e]; } \
        ps += __shfl_xor(ps, 16, 64);                                               \
        ps += __shfl_xor(ps, 32, 64);                                               \
        LR += ps;                                                                   \
        for (int nf = 0; nf < 4; ++nf) {                                            \
            bf16x4v w;                                                              \
            w[0] = (__bf16)p[nf][0]; w[1] = (__bf16)p[nf][1];                       \
            w[2] = (__bf16)p[nf][2]; w[3] = (__bf16)p[nf][3];                       \
            *(bf16x4v*)(&plds[wave][ql][nf * 16 + 4 * gg]) = w;                     \
        }                                                                           \
        __builtin_amdgcn_s_setprio(1);                                              \
        for (int ks = 0; ks < 2; ++ks) {                                            \
            bf16x8 pf = *(const bf16x8*)((const char*)&plds[wave][0][0]             \
                                         + ql * 144 + ks * 64 + gg * 16);           \
            for (int df = 0; df < 4; ++df)                                          \
                CACC[df] = __builtin_amdgcn_mfma_f32_16x16x32_bf16(                 \
                    vf[df * 2 + ks], pf, CACC[df], 0, 0, 0);                        \
        }                                                                           \
        __builtin_amdgcn_s_setprio(0);                                              \
    }

    uint4 kw0, kw1, vw0, vw1;
    STAGE_LOAD(0)
    STAGE_WRITE(0)
    int cur = 0;

    for (int tt = 0; tt < NT; ++tt) {
        if (tt + 1 < NT) { STAGE_LOAD(tt + 1) }
        __syncthreads();

        const char* Kb = KsB[cur];
        const char* Vb = VsB[cur];

        bf16x8 kf[8];
#pragma unroll
        for (int nf = 0; nf < 4; ++nf) {
            kf[nf * 2 + 0] = *(const bf16x8*)(Kb + (nf * 16 + ql) * 128 + rsw0);
            kf[nf * 2 + 1] = *(const bf16x8*)(Kb + (nf * 16 + ql) * 128 + rsw1);
        }

        f32x4 s0[4] = {}, s1[4] = {};
        __builtin_amdgcn_s_setprio(1);
#pragma unroll
        for (int nf = 0; nf < 4; ++nf) {
            s0[nf] = __builtin_amdgcn_mfma_f32_16x16x32_bf16(kf[nf * 2 + 0], qf0[0], s0[nf], 0, 0, 0);
            s0[nf] = __builtin_amdgcn_mfma_f32_16x16x32_bf16(kf[nf * 2 + 1], qf0[1], s0[nf], 0, 0, 0);
            s1[nf] = __builtin_amdgcn_mfma_f32_16x16x32_bf16(kf[nf * 2 + 0], qf1[0], s1[nf], 0, 0, 0);
            s1[nf] = __builtin_amdgcn_mfma_f32_16x16x32_bf16(kf[nf * 2 + 1], qf1[1], s1[nf], 0, 0, 0);
        }
        __builtin_amdgcn_s_setprio(0);

        bf16x8 vf[8];
#pragma unroll
        for (int df = 0; df < 4; ++df) {
            vf[df * 2 + 0] = *(const bf16x8*)(Vb + (df * 16 + ql) * 128 + rsw0);
            vf[df * 2 + 1] = *(const bf16x8*)(Vb + (df * 16 + ql) * 128 + rsw1);
        }

        SOFTMAX_PV(s0, m0r, l0r, cacc0)
        SOFTMAX_PV(s1, m1r, l1r, cacc1)

        if (tt + 1 < NT) { STAGE_WRITE(cur ^ 1) }
        cur ^= 1;
    }

    {
        int qr0 = b * N_ + n0 + wave * 32 + ql;
        bf16* nb0 = num + (size_t)sp * ROWS * D_ + (size_t)qr0 * D_ + h * DH_;
        bf16* nb1 = num + (size_t)sp * ROWS * D_ + (size_t)(qr0 + 16) * D_ + h * DH_;
#pragma unroll
        for (int df = 0; df < 4; ++df) {
            bf16x4v w0, w1;
#pragma unroll
            for (int e = 0; e < 4; ++e) {
                w0[e] = (__bf16)cacc0[df][e];
                w1[e] = (__bf16)cacc1[df][e];
            }
            *(bf16x4v*)(nb0 + df * 16 + 4 * gg) = w0;
            *(bf16x4v*)(nb1 + df * 16 + 4 * gg) = w1;
        }
        if (lane < 16) {
            size_t base = ((size_t)(sp * (B_ * H_) + bh) * N_ + (n0 + wave * 32 + ql)) * 2;
            ml[base] = m0r; ml[base + 1] = l0r;
            size_t base1 = ((size_t)(sp * (B_ * H_) + bh) * N_ + (n0 + wave * 32 + 16 + ql)) * 2;
            ml[base1] = m1r; ml[base1 + 1] = l1r;
        }
    }
#undef STAGE_LOAD
#undef STAGE_WRITE
#undef SOFTMAX_PV
}

// Combine the SPLIT partials (bf16 numerators, m in log2 domain) -> bf16 ctx
__global__ __launch_bounds__(256) void attn_combine(
    const bf16* __restrict__ num, const float* __restrict__ ml,
    bf16* __restrict__ ctx)
{
    int idx = blockIdx.x * 256 + threadIdx.x;
    int row = idx >> 7;
    int c4  = (idx & 127) << 2;
    int b = row >> 11, n = row & (N_ - 1);
    int h = c4 >> 6;
    int bh = (b << 3) + h;
    float mv[SPLIT], lv[SPLIT];
#pragma unroll
    for (int sp = 0; sp < SPLIT; ++sp) {
        const float* mp = ml + ((size_t)(sp * (B_ * H_) + bh) * N_ + n) * 2;
        mv[sp] = mp[0]; lv[sp] = mp[1];
    }
    float mx = mv[0];
#pragma unroll
    for (int sp = 1; sp < SPLIT; ++sp) mx = fmaxf(mx, mv[sp]);
    float den = 0.f;
    float wsc[SPLIT];
#pragma unroll
    for (int sp = 0; sp < SPLIT; ++sp) {
        wsc[sp] = exp2f(mv[sp] - mx);
        den += wsc[sp] * lv[sp];
    }
    float inv = 1.f / den;
    float ax = 0.f, ay = 0.f, az = 0.f, aw = 0.f;
#pragma unroll
    for (int sp = 0; sp < SPLIT; ++sp) {
        bf16x4v v = *(const bf16x4v*)(num + (size_t)sp * ROWS * D_ + (size_t)row * D_ + c4);
        ax += wsc[sp] * (float)v[0]; ay += wsc[sp] * (float)v[1];
        az += wsc[sp] * (float)v[2]; aw += wsc[sp] * (float)v[3];
    }
    bf16* o = ctx + (size_t)row * D_ + c4;
    o[0] = __float2bfloat16(ax * inv);
    o[1] = __float2bfloat16(ay * inv);
    o[2] = __float2bfloat16(az * inv);
    o[3] = __float2bfloat16(aw * inv);
}

// ---------------------------------------------------------------------------
extern "C" void kernel_launch(void* const* d_in, const int* in_sizes, int n_in,
                              void* d_out, int out_size, void* d_ws, size_t ws_size,
                              hipStream_t stream)
{
    const float* x      = (const float*)d_in[0];
    const float* y      = (const float*)d_in[1];
    const float* mask_x = (const float*)d_in[2];
    const float* mask_y = (const float*)d_in[3];
    const float* Wq = (const float*)d_in[4];  const float* bq = (const float*)d_in[5];
    const float* Wk = (const float*)d_in[6];  const float* bk = (const float*)d_in[7];
    const float* Wv = (const float*)d_in[8];  const float* bv = (const float*)d_in[9];
    const float* Wo = (const float*)d_in[10]; const float* bo = (const float*)d_in[11];
    const float* W1 = (const float*)d_in[12]; const float* b1 = (const float*)d_in[13];
    const float* W2 = (const float*)d_in[14]; const float* b2 = (const float*)d_in[15];
    const float* ln1g = (const float*)d_in[16]; const float* ln1b = (const float*)d_in[17];
    const float* ln2g = (const float*)d_in[18]; const float* ln2b = (const float*)d_in[19];

    char* ws = (char*)d_ws;
    const size_t SZA = (size_t)ROWS * D_ * 2;     // 4 MiB bf16 activation
    bf16* xn   = (bf16*)ws;            ws += SZA;
    bf16* yn   = (bf16*)ws;            ws += SZA;
    bf16* qb   = (bf16*)ws;            ws += SZA;
    bf16* kb   = (bf16*)ws;            ws += SZA;
    bf16* vtb  = (bf16*)ws;            ws += SZA;
    bf16* ctxb = (bf16*)ws;            ws += SZA;
    bf16* xn2  = (bf16*)ws;            ws += SZA;
    bf16* x1b  = (bf16*)ws;            ws += SZA;
    bf16* hff  = (bf16*)ws;            ws += (size_t)ROWS * F_ * 2;
    bf16* Wqt = (bf16*)ws;             ws += (size_t)D_ * D_ * 2;
    bf16* Wkt = (bf16*)ws;             ws += (size_t)D_ * D_ * 2;
    bf16* Wvt = (bf16*)ws;             ws += (size_t)D_ * D_ * 2;
    bf16* Wot = (bf16*)ws;             ws += (size_t)D_ * D_ * 2;
    bf16* W1t = (bf16*)ws;             ws += (size_t)D_ * F_ * 2;
    bf16* W2t = (bf16*)ws;             ws += (size_t)F_ * D_ * 2;
    bf16* numb = (bf16*)ws;            ws += (size_t)SPLIT * ROWS * D_ * 2;
    float* mlb = (float*)ws;           ws += (size_t)SPLIT * B_ * H_ * N_ * 2 * 4;

    // One fused prep launch: all 6 weight transposes + LN(x) + LN(y)
    prep_kernel<<<5120, 256, 0, stream>>>(
        Wq, Wk, Wv, Wo, W1, W2, Wqt, Wkt, Wvt, Wot, W1t, W2t,
        x, y, ln1g, ln1b, xn, yn);

    // Q/K/V projections; V written directly in per-head transposed layout
    gemm64_qkv<<<dim3(ROWS / 64, D_ / 64, 3), 256, 0, stream>>>(
        xn, yn, Wqt, Wkt, Wvt, bq, bk, bv, mask_x, mask_y, qb, kb, vtb);

    attn_kernel<<<ATT_GRID, 256, 0, stream>>>(qb, kb, vtb, numb, mlb);
    attn_combine<<<(ROWS * D_ / 4) / 256, 256, 0, stream>>>(numb, mlb, ctxb);

    // out-proj + residual(x f32) -> x1 (bf16)
    gemm64_wo<<<dim3(ROWS / 64, D_ / 64), 256, 0, stream>>>(
        ctxb, Wot, bo, x, x1b, D_, D_);

    // ln2 on bf16 x1
    lnb_kernel<<<ROWS / 4, 256, 0, stream>>>(x1b, ln2g, ln2b, xn2);

    // MLP1 + GELU -> hff (bf16), glds kernel (512 blocks)
    gemm_glds_gelu<<<dim3(ROWS / 128, F_ / 128), 256, 0, stream>>>(
        xn2, W1t, b1, hff, F_, D_);

    // MLP2 + residual(x1 bf16) -> d_out (f32)
    gemm64_mlp2<<<dim3(ROWS / 64, D_ / 64), 256, 0, stream>>>(
        hff, W2t, b2, x1b, (float*)d_out, D_, F_);
}

// Round 13
// 114.968 us; speedup vs baseline: 1.2683x; 1.0431x over previous
//
#include <hip/hip_runtime.h>
#include <hip/hip_bf16.h>

// Problem constants
#define B_  2
#define N_  2048
#define M_  2048
#define D_  512
#define H_  8
#define F_  2048
#define DH_ 64
#define ROWS 4096   // B_*N_ == B_*M_

#define SPLIT 4
#define KV_PER (M_ / SPLIT)   // 512
#define NT (KV_PER / 64)      // 8 tiles of 64 keys
#define ATT_GRID (16 * 16 * SPLIT)   // n0(16) x bh(16) x sp = 1024

typedef __bf16 bf16x8 __attribute__((ext_vector_type(8)));
typedef __bf16 bf16x4v __attribute__((ext_vector_type(4)));
typedef float  f32x4  __attribute__((ext_vector_type(4)));
using bf16 = __hip_bfloat16;

// ---------------------------------------------------------------------------
// Fused prep: blocks 0..3071 = weight transposes (f32->bf16, W[K,N]->Wt[N,K]);
// blocks 3072..5119 = LayerNorm of x and y.
// ---------------------------------------------------------------------------
__global__ __launch_bounds__(256) void prep_kernel(
    const float* __restrict__ Wq, const float* __restrict__ Wk,
    const float* __restrict__ Wv, const float* __restrict__ Wo,
    const float* __restrict__ W1, const float* __restrict__ W2,
    bf16* __restrict__ Wqt, bf16* __restrict__ Wkt,
    bf16* __restrict__ Wvt, bf16* __restrict__ Wot,
    bf16* __restrict__ W1t, bf16* __restrict__ W2t,
    const float* __restrict__ x, const float* __restrict__ y,
    const float* __restrict__ ln1g, const float* __restrict__ ln1b,
    bf16* __restrict__ xn, bf16* __restrict__ yn)
{
    __shared__ float tle[32][33];
    int id = blockIdx.x;
    if (id < 3072) {
        const float* W; bf16* Wt; int K, N, n0, k0;
        if (id < 1024) {
            int z = id >> 8, xy = id & 255;
            W  = z == 0 ? Wq  : (z == 1 ? Wk  : (z == 2 ? Wv  : Wo));
            Wt = z == 0 ? Wqt : (z == 1 ? Wkt : (z == 2 ? Wvt : Wot));
            K = D_; N = D_;
            n0 = (xy & 15) * 32; k0 = (xy >> 4) * 32;
        } else if (id < 2048) {
            int local = id - 1024;
            W = W1; Wt = W1t; K = D_; N = F_;
            n0 = (local & 63) * 32; k0 = (local >> 6) * 32;
        } else {
            int local = id - 2048;
            W = W2; Wt = W2t; K = F_; N = D_;
            n0 = (local & 15) * 32; k0 = (local >> 4) * 32;
        }
        int tx = threadIdx.x & 31, ty = threadIdx.x >> 5;
        for (int j = 0; j < 32; j += 8)
            tle[ty + j][tx] = W[(size_t)(k0 + ty + j) * N + n0 + tx];
        __syncthreads();
        for (int j = 0; j < 32; j += 8)
            Wt[(size_t)(n0 + ty + j) * K + k0 + tx] = __float2bfloat16(tle[tx][ty + j]);
    } else {
        int wave = threadIdx.x >> 6, lane = threadIdx.x & 63;
        int grow = (id - 3072) * 4 + wave;
        const float* in;
        bf16* out;
        int row;
        if (grow < ROWS) { in = x; out = xn; row = grow; }
        else             { in = y; out = yn; row = grow - ROWS; }
        const float* p = in + (size_t)row * D_ + lane * 8;
        float4 v0 = *(const float4*)p;
        float4 v1 = *(const float4*)(p + 4);
        float s  = v0.x + v0.y + v0.z + v0.w + v1.x + v1.y + v1.z + v1.w;
        float ss = v0.x*v0.x + v0.y*v0.y + v0.z*v0.z + v0.w*v0.w
                 + v1.x*v1.x + v1.y*v1.y + v1.z*v1.z + v1.w*v1.w;
        for (int m = 1; m < 64; m <<= 1) {
            s  += __shfl_xor(s,  m, 64);
            ss += __shfl_xor(ss, m, 64);
        }
        float mu   = s * (1.f / D_);
        float var  = ss * (1.f / D_) - mu * mu;
        float rstd = rsqrtf(var + 1e-6f);
        int c = lane * 8;
        float4 g0 = *(const float4*)(ln1g + c), g1 = *(const float4*)(ln1g + c + 4);
        float4 b0 = *(const float4*)(ln1b + c), b1 = *(const float4*)(ln1b + c + 4);
        bf16* o = out + (size_t)row * D_ + c;
        o[0] = __float2bfloat16((v0.x - mu) * rstd * g0.x + b0.x);
        o[1] = __float2bfloat16((v0.y - mu) * rstd * g0.y + b0.y);
        o[2] = __float2bfloat16((v0.z - mu) * rstd * g0.z + b0.z);
        o[3] = __float2bfloat16((v0.w - mu) * rstd * g0.w + b0.w);
        o[4] = __float2bfloat16((v1.x - mu) * rstd * g1.x + b1.x);
        o[5] = __float2bfloat16((v1.y - mu) * rstd * g1.y + b1.y);
        o[6] = __float2bfloat16((v1.z - mu) * rstd * g1.z + b1.z);
        o[7] = __float2bfloat16((v1.w - mu) * rstd * g1.w + b1.w);
    }
}

// LayerNorm, bf16 input (for x1 -> xn2)
__global__ __launch_bounds__(256) void lnb_kernel(
    const bf16* __restrict__ in, const float* __restrict__ gam,
    const float* __restrict__ bet, bf16* __restrict__ out)
{
    int wave = threadIdx.x >> 6, lane = threadIdx.x & 63;
    int row  = blockIdx.x * 4 + wave;
    bf16x8 v = *(const bf16x8*)(in + (size_t)row * D_ + lane * 8);
    float f[8];
    float s = 0.f, ss = 0.f;
#pragma unroll
    for (int j = 0; j < 8; ++j) {
        f[j] = (float)v[j];
        s += f[j]; ss += f[j] * f[j];
    }
    for (int m = 1; m < 64; m <<= 1) {
        s  += __shfl_xor(s,  m, 64);
        ss += __shfl_xor(ss, m, 64);
    }
    float mu   = s * (1.f / D_);
    float var  = ss * (1.f / D_) - mu * mu;
    float rstd = rsqrtf(var + 1e-6f);
    int c = lane * 8;
    float4 g0 = *(const float4*)(gam + c), g1 = *(const float4*)(gam + c + 4);
    float4 b0 = *(const float4*)(bet + c), b1 = *(const float4*)(bet + c + 4);
    bf16* o = out + (size_t)row * D_ + c;
    o[0] = __float2bfloat16((f[0] - mu) * rstd * g0.x + b0.x);
    o[1] = __float2bfloat16((f[1] - mu) * rstd * g0.y + b0.y);
    o[2] = __float2bfloat16((f[2] - mu) * rstd * g0.z + b0.z);
    o[3] = __float2bfloat16((f[3] - mu) * rstd * g0.w + b0.w);
    o[4] = __float2bfloat16((f[4] - mu) * rstd * g1.x + b1.x);
    o[5] = __float2bfloat16((f[5] - mu) * rstd * g1.y + b1.y);
    o[6] = __float2bfloat16((f[6] - mu) * rstd * g1.z + b1.z);
    o[7] = __float2bfloat16((f[7] - mu) * rstd * g1.w + b1.w);
}

// ---------------------------------------------------------------------------
// MLP1 GEMM, m97 structure: 128x128 tile, BK=32, global_load_lds width=16
// into LINEAR LDS, single-buffered. GELU epilogue, bf16 out.
// ---------------------------------------------------------------------------
__global__ __launch_bounds__(256) void gemm_glds_gelu(
    const bf16* __restrict__ A, const bf16* __restrict__ Bt,
    const float* __restrict__ bias, bf16* __restrict__ outb,
    int Nn, int K)
{
    __shared__ __align__(16) bf16 As[128 * 32];   // [row][32 k] 64B rows
    __shared__ __align__(16) bf16 Bs[128 * 32];
    int t = threadIdx.x, lane = t & 63, wave = t >> 6;
    int wm = wave >> 1, wn = wave & 1;
    int r16 = lane & 15, g = lane >> 4;
    int m0 = blockIdx.x * 128, n0 = blockIdx.y * 128;

    const int srow = wave * 32;
    const int lrow = lane >> 2;
    const int lcol = (lane & 3) * 8;

    f32x4 acc[4][4] = {};
    for (int k0 = 0; k0 < K; k0 += 32) {
        __syncthreads();
#pragma unroll
        for (int j = 0; j < 2; ++j) {
            const bf16* gpA = A + (size_t)(m0 + srow + j * 16 + lrow) * K + k0 + lcol;
            __builtin_amdgcn_global_load_lds(
                (const __attribute__((address_space(1))) void*)gpA,
                (__attribute__((address_space(3))) void*)(As + (srow + j * 16) * 32),
                16, 0, 0);
            const bf16* gpB = Bt + (size_t)(n0 + srow + j * 16 + lrow) * K + k0 + lcol;
            __builtin_amdgcn_global_load_lds(
                (const __attribute__((address_space(1))) void*)gpB,
                (__attribute__((address_space(3))) void*)(Bs + (srow + j * 16) * 32),
                16, 0, 0);
        }
        __syncthreads();
        bf16x8 af[4], bfr[4];
#pragma unroll
        for (int i = 0; i < 4; ++i) {
            af[i]  = *(const bf16x8*)((const char*)As + (wm * 64 + i * 16 + r16) * 64 + g * 16);
            bfr[i] = *(const bf16x8*)((const char*)Bs + (wn * 64 + i * 16 + r16) * 64 + g * 16);
        }
        __builtin_amdgcn_s_setprio(1);
#pragma unroll
        for (int i = 0; i < 4; ++i)
#pragma unroll
            for (int j = 0; j < 4; ++j)
                acc[i][j] = __builtin_amdgcn_mfma_f32_16x16x32_bf16(af[i], bfr[j], acc[i][j], 0, 0, 0);
        __builtin_amdgcn_s_setprio(0);
    }

#pragma unroll
    for (int i = 0; i < 4; ++i) {
        int rb = m0 + wm * 64 + i * 16 + g * 4;
#pragma unroll
        for (int j = 0; j < 4; ++j) {
            int cb = n0 + wn * 64 + j * 16 + r16;
            float bia = bias[cb];
#pragma unroll
            for (int e = 0; e < 4; ++e) {
                float val = acc[i][j][e] + bia;
                val = 0.5f * val * (1.f + erff(val * 0.70710678118654752f));
                outb[(size_t)(rb + e) * Nn + cb] = __float2bfloat16(val);
            }
        }
    }
}

// ---------------------------------------------------------------------------
// 64x64-tile GEMM. 4 waves (2x2, each 32x32), BK=64, reg-staged
// double-buffered LDS, XOR-swizzled. VTRANS epilogue for V projection.
// ---------------------------------------------------------------------------
template<bool RESID, bool RESIDBF, bool ROWMASK, bool OUTBF, bool VTRANS>
__device__ __forceinline__ void gemm64_body(
    const bf16* __restrict__ A, const bf16* __restrict__ Bt,
    const float* __restrict__ bias, const float* __restrict__ resid,
    const bf16* __restrict__ residb, const float* __restrict__ rowmask,
    bf16* __restrict__ outb, float* __restrict__ outf,
    int Nn, int K)
{
    __shared__ __align__(16) char As[2][64 * 128];
    __shared__ __align__(16) char Bs[2][64 * 128];
    int t = threadIdx.x, lane = t & 63, wave = t >> 6;
    int wm = wave >> 1, wn = wave & 1;
    int r16 = lane & 15, g = lane >> 4;
    int m0 = blockIdx.x * 64, n0 = blockIdx.y * 64;

    const int sr0 = t >> 3, sr1 = sr0 + 32, sc = t & 7;
    const int wof0 = sr0 * 128 + ((sc ^ (sr0 & 7)) << 4);
    const int wof1 = sr1 * 128 + ((sc ^ (sr1 & 7)) << 4);
    const int rsw0 = ((g     ^ (r16 & 7)) << 4);
    const int rsw1 = (((4 + g) ^ (r16 & 7)) << 4);

    uint4 a0, a1, b0, b1;
#define G64_LOAD(k0)                                                         \
    a0 = *(const uint4*)(A  + (size_t)(m0 + sr0) * K + (k0) + sc * 8);       \
    a1 = *(const uint4*)(A  + (size_t)(m0 + sr1) * K + (k0) + sc * 8);       \
    b0 = *(const uint4*)(Bt + (size_t)(n0 + sr0) * K + (k0) + sc * 8);       \
    b1 = *(const uint4*)(Bt + (size_t)(n0 + sr1) * K + (k0) + sc * 8);
#define G64_WRITE(buf)                                                       \
    *(uint4*)(As[buf] + wof0) = a0;  *(uint4*)(As[buf] + wof1) = a1;         \
    *(uint4*)(Bs[buf] + wof0) = b0;  *(uint4*)(Bs[buf] + wof1) = b1;

    f32x4 acc[2][2] = {};
    G64_LOAD(0)
    G64_WRITE(0)
    int cur = 0;
    const int nit = K >> 6;
    for (int it = 0; it < nit; ++it) {
        if (it + 1 < nit) { G64_LOAD((it + 1) << 6) }
        __syncthreads();
        bf16x8 af[2][2], bfr[2][2];
#pragma unroll
        for (int i = 0; i < 2; ++i) {
            af[i][0] = *(const bf16x8*)(As[cur] + (wm * 32 + i * 16 + r16) * 128 + rsw0);
            af[i][1] = *(const bf16x8*)(As[cur] + (wm * 32 + i * 16 + r16) * 128 + rsw1);
            bfr[i][0] = *(const bf16x8*)(Bs[cur] + (wn * 32 + i * 16 + r16) * 128 + rsw0);
            bfr[i][1] = *(const bf16x8*)(Bs[cur] + (wn * 32 + i * 16 + r16) * 128 + rsw1);
        }
        __builtin_amdgcn_s_setprio(1);
#pragma unroll
        for (int i = 0; i < 2; ++i)
#pragma unroll
            for (int j = 0; j < 2; ++j) {
                acc[i][j] = __builtin_amdgcn_mfma_f32_16x16x32_bf16(af[i][0], bfr[j][0], acc[i][j], 0, 0, 0);
                acc[i][j] = __builtin_amdgcn_mfma_f32_16x16x32_bf16(af[i][1], bfr[j][1], acc[i][j], 0, 0, 0);
            }
        __builtin_amdgcn_s_setprio(0);
        if (it + 1 < nit) { G64_WRITE(cur ^ 1) }
        cur ^= 1;
    }
#undef G64_LOAD
#undef G64_WRITE

#pragma unroll
    for (int i = 0; i < 2; ++i) {
        int rb = m0 + wm * 32 + i * 16 + g * 4;
#pragma unroll
        for (int j = 0; j < 2; ++j) {
            int cb = n0 + wn * 32 + j * 16 + r16;
            float bia = bias[cb];
            if (VTRANS) {
                bf16x4v w;
#pragma unroll
                for (int e = 0; e < 4; ++e) {
                    int rr = rb + e;
                    float val = acc[i][j][e] + bia;
                    if (ROWMASK) val *= rowmask[rr];
                    w[e] = (__bf16)val;
                }
                int bb = rb >> 11, m = rb & (M_ - 1);
                int bh = bb * H_ + (cb >> 6), d = cb & (DH_ - 1);
                *(bf16x4v*)(outb + ((size_t)bh * DH_ + d) * M_ + m) = w;
            } else {
#pragma unroll
                for (int e = 0; e < 4; ++e) {
                    int rr = rb + e;
                    float val = acc[i][j][e] + bia;
                    if (RESID) {
                        if (RESIDBF) val += (float)residb[(size_t)rr * Nn + cb];
                        else         val += resid[(size_t)rr * Nn + cb];
                    }
                    if (ROWMASK) val *= rowmask[rr];
                    if (OUTBF)   outb[(size_t)rr * Nn + cb] = __float2bfloat16(val);
                    else         outf[(size_t)rr * Nn + cb] = val;
                }
            }
        }
    }
}

// Wo projection: resid = x (f32), out = x1 bf16
__global__ __launch_bounds__(256) void gemm64_wo(
    const bf16* __restrict__ A, const bf16* __restrict__ Bt,
    const float* __restrict__ bias, const float* __restrict__ resid,
    bf16* __restrict__ outb, int Nn, int K)
{
    gemm64_body<true, false, false, true, false>(A, Bt, bias, resid, nullptr, nullptr,
                                                 outb, nullptr, Nn, K);
}

// MLP2: resid = x1 (bf16), out = d_out f32
__global__ __launch_bounds__(256) void gemm64_mlp2(
    const bf16* __restrict__ A, const bf16* __restrict__ Bt,
    const float* __restrict__ bias, const bf16* __restrict__ residb,
    float* __restrict__ outf, int Nn, int K)
{
    gemm64_body<true, true, false, false, false>(A, Bt, bias, nullptr, residb, nullptr,
                                                 nullptr, outf, Nn, K);
}

// Batched Q/K/V projection: z selects Q, K, or V; V writes transposed.
__global__ __launch_bounds__(256) void gemm64_qkv(
    const bf16* __restrict__ xn, const bf16* __restrict__ yn,
    const bf16* __restrict__ Wqt, const bf16* __restrict__ Wkt, const bf16* __restrict__ Wvt,
    const float* __restrict__ bq, const float* __restrict__ bk, const float* __restrict__ bv,
    const float* __restrict__ mask_x, const float* __restrict__ mask_y,
    bf16* __restrict__ qb, bf16* __restrict__ kb, bf16* __restrict__ vtb)
{
    int z = blockIdx.z;
    if (z == 2) {
        gemm64_body<false, false, true, true, true>(yn, Wvt, bv, nullptr, nullptr, mask_y,
                                                    vtb, nullptr, D_, D_);
    } else {
        const bf16* A        = z == 0 ? xn : yn;
        const bf16* Bt       = z == 0 ? Wqt : Wkt;
        const float* bias    = z == 0 ? bq  : bk;
        const float* rowmask = z == 0 ? mask_x : mask_y;
        bf16* outb           = z == 0 ? qb  : kb;
        gemm64_body<false, false, true, true, false>(A, Bt, bias, nullptr, nullptr, rowmask,
                                                     outb, nullptr, D_, D_);
    }
}

// ---------------------------------------------------------------------------
// Flash attention (swapped S^T = K*Q), LDS-staged double-buffered K/V with
// XOR swizzle, reg-staged. 1D grid, XCD-chunked remap. 4 waves, 32 q-rows
// each. __expf softmax (fast native), T13 defer-max THR=8.
// bf16 numerator + per-row (m,l) f32.
// ---------------------------------------------------------------------------
__global__ __launch_bounds__(256, 3) void attn_kernel(
    const bf16* __restrict__ q, const bf16* __restrict__ kk,
    const bf16* __restrict__ vt, bf16* __restrict__ num,
    float* __restrict__ ml)
{
    int bid = blockIdx.x;
    int wg  = (bid & 7) * (ATT_GRID / 8) + (bid >> 3);
    int n0  = (wg & 15) * 128;
    int bh  = (wg >> 4) & 15;
    int sp  = wg >> 8;
    int b = bh >> 3, h = bh & 7;
    int t = threadIdx.x, lane = t & 63, wave = t >> 6;
    int ql = lane & 15, gg = lane >> 4;

    __shared__ __align__(16) char KsB[2][64 * 128];
    __shared__ __align__(16) char VsB[2][64 * 128];
    __shared__ __align__(16) bf16 plds[4][16][72];

    bf16x8 qf0[2], qf1[2];
    {
        int qr0 = b * N_ + n0 + wave * 32 + ql;
        for (int ks = 0; ks < 2; ++ks) {
            bf16x8 qv = *(const bf16x8*)(q + (size_t)qr0 * D_ + h * DH_ + ks * 32 + gg * 8);
            for (int j = 0; j < 8; ++j) qv[j] = (__bf16)((float)qv[j] * 0.125f);
            qf0[ks] = qv;
            bf16x8 qw = *(const bf16x8*)(q + (size_t)(qr0 + 16) * D_ + h * DH_ + ks * 32 + gg * 8);
            for (int j = 0; j < 8; ++j) qw[j] = (__bf16)((float)qw[j] * 0.125f);
            qf1[ks] = qw;
        }
    }

    f32x4 cacc0[4] = {}, cacc1[4] = {};
    float m0r = -1e30f, l0r = 0.f, m1r = -1e30f, l1r = 0.f;

    const bf16* kbase = kk + (size_t)(b * M_ + sp * KV_PER) * D_ + h * DH_;
    const bf16* vtb   = vt + (size_t)bh * DH_ * M_ + sp * KV_PER;

    const int k0r = t >> 3,          kc0 = t & 7;
    const int k1r = (t >> 3) + 32;
    const int wofs0 = k0r * 128 + ((kc0 ^ (k0r & 7)) << 4);
    const int wofs1 = k1r * 128 + ((kc0 ^ (k1r & 7)) << 4);
    const int rsw0 = ((gg     ^ (ql & 7)) << 4);
    const int rsw1 = (((4 + gg) ^ (ql & 7)) << 4);

#define STAGE_LOAD(tt)                                                              \
    kw0 = *(const uint4*)(kbase + (size_t)((tt) * 64 + k0r) * D_ + kc0 * 8);        \
    kw1 = *(const uint4*)(kbase + (size_t)((tt) * 64 + k1r) * D_ + kc0 * 8);        \
    vw0 = *(const uint4*)(vtb + (size_t)k0r * M_ + (tt) * 64 + kc0 * 8);            \
    vw1 = *(const uint4*)(vtb + (size_t)k1r * M_ + (tt) * 64 + kc0 * 8);

#define STAGE_WRITE(buf)                                                            \
    *(uint4*)(KsB[buf] + wofs0) = kw0;                                              \
    *(uint4*)(KsB[buf] + wofs1) = kw1;                                              \
    *(uint4*)(VsB[buf] + wofs0) = vw0;                                              \
    *(uint4*)(VsB[buf] + wofs1) = vw1;

#define SOFTMAX_PV(S, MR, LR, CACC)                                                 \
    {                                                                               \
        float tmax = fmaxf(                                                         \
            fmaxf(fmaxf(fmaxf(S[0][0], S[0][1]), fmaxf(S[0][2], S[0][3])),          \
                  fmaxf(fmaxf(S[1][0], S[1][1]), fmaxf(S[1][2], S[1][3]))),         \
            fmaxf(fmaxf(fmaxf(S[2][0], S[2][1]), fmaxf(S[2][2], S[2][3])),          \
                  fmaxf(fmaxf(S[3][0], S[3][1]), fmaxf(S[3][2], S[3][3]))));        \
        tmax = fmaxf(tmax, __shfl_xor(tmax, 16, 64));                               \
        tmax = fmaxf(tmax, __shfl_xor(tmax, 32, 64));                               \
        if (__any(tmax - MR > 8.f)) {                                               \
            float mnew = fmaxf(MR, tmax);                                           \
            float scl  = __expf(MR - mnew);                                         \
            MR = mnew;                                                              \
            LR *= scl;                                                              \
            for (int df = 0; df < 4; ++df)                                          \
                for (int e = 0; e < 4; ++e) CACC[df][e] *= scl;                     \
        }                                                                           \
        float p[4][4]; float ps = 0.f;                                              \
        for (int nf = 0; nf < 4; ++nf)                                              \
            for (int e = 0; e < 4; ++e) { p[nf][e] = __expf(S[nf][e] - MR); ps += p[nf][e]; } \
        ps += __shfl_xor(ps, 16, 64);                                               \
        ps += __shfl_xor(ps, 32, 64);                                               \
        LR += ps;                                                                   \
        for (int nf = 0; nf < 4; ++nf) {                                            \
            bf16x4v w;                                                              \
            w[0] = (__bf16)p[nf][0]; w[1] = (__bf16)p[nf][1];                       \
            w[2] = (__bf16)p[nf][2]; w[3] = (__bf16)p[nf][3];                       \
            *(bf16x4v*)(&plds[wave][ql][nf * 16 + 4 * gg]) = w;                     \
        }                                                                           \
        __builtin_amdgcn_s_setprio(1);                                              \
        for (int ks = 0; ks < 2; ++ks) {                                            \
            bf16x8 pf = *(const bf16x8*)((const char*)&plds[wave][0][0]             \
                                         + ql * 144 + ks * 64 + gg * 16);           \
            for (int df = 0; df < 4; ++df)                                          \
                CACC[df] = __builtin_amdgcn_mfma_f32_16x16x32_bf16(                 \
                    vf[df * 2 + ks], pf, CACC[df], 0, 0, 0);                        \
        }                                                                           \
        __builtin_amdgcn_s_setprio(0);                                              \
    }

    uint4 kw0, kw1, vw0, vw1;
    STAGE_LOAD(0)
    STAGE_WRITE(0)
    int cur = 0;

    for (int tt = 0; tt < NT; ++tt) {
        if (tt + 1 < NT) { STAGE_LOAD(tt + 1) }
        __syncthreads();

        const char* Kb = KsB[cur];
        const char* Vb = VsB[cur];

        bf16x8 kf[8];
#pragma unroll
        for (int nf = 0; nf < 4; ++nf) {
            kf[nf * 2 + 0] = *(const bf16x8*)(Kb + (nf * 16 + ql) * 128 + rsw0);
            kf[nf * 2 + 1] = *(const bf16x8*)(Kb + (nf * 16 + ql) * 128 + rsw1);
        }

        f32x4 s0[4] = {}, s1[4] = {};
        __builtin_amdgcn_s_setprio(1);
#pragma unroll
        for (int nf = 0; nf < 4; ++nf) {
            s0[nf] = __builtin_amdgcn_mfma_f32_16x16x32_bf16(kf[nf * 2 + 0], qf0[0], s0[nf], 0, 0, 0);
            s0[nf] = __builtin_amdgcn_mfma_f32_16x16x32_bf16(kf[nf * 2 + 1], qf0[1], s0[nf], 0, 0, 0);
            s1[nf] = __builtin_amdgcn_mfma_f32_16x16x32_bf16(kf[nf * 2 + 0], qf1[0], s1[nf], 0, 0, 0);
            s1[nf] = __builtin_amdgcn_mfma_f32_16x16x32_bf16(kf[nf * 2 + 1], qf1[1], s1[nf], 0, 0, 0);
        }
        __builtin_amdgcn_s_setprio(0);

        bf16x8 vf[8];
#pragma unroll
        for (int df = 0; df < 4; ++df) {
            vf[df * 2 + 0] = *(const bf16x8*)(Vb + (df * 16 + ql) * 128 + rsw0);
            vf[df * 2 + 1] = *(const bf16x8*)(Vb + (df * 16 + ql) * 128 + rsw1);
        }

        SOFTMAX_PV(s0, m0r, l0r, cacc0)
        SOFTMAX_PV(s1, m1r, l1r, cacc1)

        if (tt + 1 < NT) { STAGE_WRITE(cur ^ 1) }
        cur ^= 1;
    }

    {
        int qr0 = b * N_ + n0 + wave * 32 + ql;
        bf16* nb0 = num + (size_t)sp * ROWS * D_ + (size_t)qr0 * D_ + h * DH_;
        bf16* nb1 = num + (size_t)sp * ROWS * D_ + (size_t)(qr0 + 16) * D_ + h * DH_;
#pragma unroll
        for (int df = 0; df < 4; ++df) {
            bf16x4v w0, w1;
#pragma unroll
            for (int e = 0; e < 4; ++e) {
                w0[e] = (__bf16)cacc0[df][e];
                w1[e] = (__bf16)cacc1[df][e];
            }
            *(bf16x4v*)(nb0 + df * 16 + 4 * gg) = w0;
            *(bf16x4v*)(nb1 + df * 16 + 4 * gg) = w1;
        }
        if (lane < 16) {
            size_t base = ((size_t)(sp * (B_ * H_) + bh) * N_ + (n0 + wave * 32 + ql)) * 2;
            ml[base] = m0r; ml[base + 1] = l0r;
            size_t base1 = ((size_t)(sp * (B_ * H_) + bh) * N_ + (n0 + wave * 32 + 16 + ql)) * 2;
            ml[base1] = m1r; ml[base1 + 1] = l1r;
        }
    }
#undef STAGE_LOAD
#undef STAGE_WRITE
#undef SOFTMAX_PV
}

// Combine the SPLIT partials (bf16 numerators) -> bf16 ctx
__global__ __launch_bounds__(256) void attn_combine(
    const bf16* __restrict__ num, const float* __restrict__ ml,
    bf16* __restrict__ ctx)
{
    int idx = blockIdx.x * 256 + threadIdx.x;
    int row = idx >> 7;
    int c4  = (idx & 127) << 2;
    int b = row >> 11, n = row & (N_ - 1);
    int h = c4 >> 6;
    int bh = (b << 3) + h;
    float mv[SPLIT], lv[SPLIT];
#pragma unroll
    for (int sp = 0; sp < SPLIT; ++sp) {
        const float* mp = ml + ((size_t)(sp * (B_ * H_) + bh) * N_ + n) * 2;
        mv[sp] = mp[0]; lv[sp] = mp[1];
    }
    float mx = mv[0];
#pragma unroll
    for (int sp = 1; sp < SPLIT; ++sp) mx = fmaxf(mx, mv[sp]);
    float den = 0.f;
    float wsc[SPLIT];
#pragma unroll
    for (int sp = 0; sp < SPLIT; ++sp) {
        wsc[sp] = __expf(mv[sp] - mx);
        den += wsc[sp] * lv[sp];
    }
    float inv = 1.f / den;
    float ax = 0.f, ay = 0.f, az = 0.f, aw = 0.f;
#pragma unroll
    for (int sp = 0; sp < SPLIT; ++sp) {
        bf16x4v v = *(const bf16x4v*)(num + (size_t)sp * ROWS * D_ + (size_t)row * D_ + c4);
        ax += wsc[sp] * (float)v[0]; ay += wsc[sp] * (float)v[1];
        az += wsc[sp] * (float)v[2]; aw += wsc[sp] * (float)v[3];
    }
    bf16* o = ctx + (size_t)row * D_ + c4;
    o[0] = __float2bfloat16(ax * inv);
    o[1] = __float2bfloat16(ay * inv);
    o[2] = __float2bfloat16(az * inv);
    o[3] = __float2bfloat16(aw * inv);
}

// ---------------------------------------------------------------------------
extern "C" void kernel_launch(void* const* d_in, const int* in_sizes, int n_in,
                              void* d_out, int out_size, void* d_ws, size_t ws_size,
                              hipStream_t stream)
{
    const float* x      = (const float*)d_in[0];
    const float* y      = (const float*)d_in[1];
    const float* mask_x = (const float*)d_in[2];
    const float* mask_y = (const float*)d_in[3];
    const float* Wq = (const float*)d_in[4];  const float* bq = (const float*)d_in[5];
    const float* Wk = (const float*)d_in[6];  const float* bk = (const float*)d_in[7];
    const float* Wv = (const float*)d_in[8];  const float* bv = (const float*)d_in[9];
    const float* Wo = (const float*)d_in[10]; const float* bo = (const float*)d_in[11];
    const float* W1 = (const float*)d_in[12]; const float* b1 = (const float*)d_in[13];
    const float* W2 = (const float*)d_in[14]; const float* b2 = (const float*)d_in[15];
    const float* ln1g = (const float*)d_in[16]; const float* ln1b = (const float*)d_in[17];
    const float* ln2g = (const float*)d_in[18]; const float* ln2b = (const float*)d_in[19];

    char* ws = (char*)d_ws;
    const size_t SZA = (size_t)ROWS * D_ * 2;     // 4 MiB bf16 activation
    bf16* xn   = (bf16*)ws;            ws += SZA;
    bf16* yn   = (bf16*)ws;            ws += SZA;
    bf16* qb   = (bf16*)ws;            ws += SZA;
    bf16* kb   = (bf16*)ws;            ws += SZA;
    bf16* vtb  = (bf16*)ws;            ws += SZA;
    bf16* ctxb = (bf16*)ws;            ws += SZA;
    bf16* xn2  = (bf16*)ws;            ws += SZA;
    bf16* x1b  = (bf16*)ws;            ws += SZA;
    bf16* hff  = (bf16*)ws;            ws += (size_t)ROWS * F_ * 2;
    bf16* Wqt = (bf16*)ws;             ws += (size_t)D_ * D_ * 2;
    bf16* Wkt = (bf16*)ws;             ws += (size_t)D_ * D_ * 2;
    bf16* Wvt = (bf16*)ws;             ws += (size_t)D_ * D_ * 2;
    bf16* Wot = (bf16*)ws;             ws += (size_t)D_ * D_ * 2;
    bf16* W1t = (bf16*)ws;             ws += (size_t)D_ * F_ * 2;
    bf16* W2t = (bf16*)ws;             ws += (size_t)F_ * D_ * 2;
    bf16* numb = (bf16*)ws;            ws += (size_t)SPLIT * ROWS * D_ * 2;
    float* mlb = (float*)ws;           ws += (size_t)SPLIT * B_ * H_ * N_ * 2 * 4;

    // One fused prep launch: all 6 weight transposes + LN(x) + LN(y)
    prep_kernel<<<5120, 256, 0, stream>>>(
        Wq, Wk, Wv, Wo, W1, W2, Wqt, Wkt, Wvt, Wot, W1t, W2t,
        x, y, ln1g, ln1b, xn, yn);

    // Q/K/V projections; V written directly in per-head transposed layout
    gemm64_qkv<<<dim3(ROWS / 64, D_ / 64, 3), 256, 0, stream>>>(
        xn, yn, Wqt, Wkt, Wvt, bq, bk, bv, mask_x, mask_y, qb, kb, vtb);

    attn_kernel<<<ATT_GRID, 256, 0, stream>>>(qb, kb, vtb, numb, mlb);
    attn_combine<<<(ROWS * D_ / 4) / 256, 256, 0, stream>>>(numb, mlb, ctxb);

    // out-proj + residual(x f32) -> x1 (bf16)
    gemm64_wo<<<dim3(ROWS / 64, D_ / 64), 256, 0, stream>>>(
        ctxb, Wot, bo, x, x1b, D_, D_);

    // ln2 on bf16 x1
    lnb_kernel<<<ROWS / 4, 256, 0, stream>>>(x1b, ln2g, ln2b, xn2);

    // MLP1 + GELU -> hff (bf16), glds kernel (512 blocks)
    gemm_glds_gelu<<<dim3(ROWS / 128, F_ / 128), 256, 0, stream>>>(
        xn2, W1t, b1, hff, F_, D_);

    // MLP2 + residual(x1 bf16) -> d_out (f32)
    gemm64_mlp2<<<dim3(ROWS / 64, D_ / 64), 256, 0, stream>>>(
        hff, W2t, b2, x1b, (float*)d_out, D_, F_);
}

// Round 14
// 111.725 us; speedup vs baseline: 1.3051x; 1.0290x over previous
//
#include <hip/hip_runtime.h>
#include <hip/hip_bf16.h>

// Problem constants
#define B_  2
#define N_  2048
#define M_  2048
#define D_  512
#define H_  8
#define F_  2048
#define DH_ 64
#define ROWS 4096   // B_*N_ == B_*M_

#define SPLIT 4
#define KV_PER (M_ / SPLIT)   // 512
#define NT (KV_PER / 64)      // 8 tiles of 64 keys
#define ATT_GRID (16 * 16 * SPLIT)   // n0(16) x bh(16) x sp = 1024

typedef __bf16 bf16x8 __attribute__((ext_vector_type(8)));
typedef __bf16 bf16x4v __attribute__((ext_vector_type(4)));
typedef float  f32x4  __attribute__((ext_vector_type(4)));
using bf16 = __hip_bfloat16;

// ---------------------------------------------------------------------------
// Fused prep: blocks 0..3071 = weight transposes (f32->bf16, W[K,N]->Wt[N,K]);
// blocks 3072..5119 = LayerNorm of x and y.
// ---------------------------------------------------------------------------
__global__ __launch_bounds__(256) void prep_kernel(
    const float* __restrict__ Wq, const float* __restrict__ Wk,
    const float* __restrict__ Wv, const float* __restrict__ Wo,
    const float* __restrict__ W1, const float* __restrict__ W2,
    bf16* __restrict__ Wqt, bf16* __restrict__ Wkt,
    bf16* __restrict__ Wvt, bf16* __restrict__ Wot,
    bf16* __restrict__ W1t, bf16* __restrict__ W2t,
    const float* __restrict__ x, const float* __restrict__ y,
    const float* __restrict__ ln1g, const float* __restrict__ ln1b,
    bf16* __restrict__ xn, bf16* __restrict__ yn)
{
    __shared__ float tle[32][33];
    int id = blockIdx.x;
    if (id < 3072) {
        const float* W; bf16* Wt; int K, N, n0, k0;
        if (id < 1024) {
            int z = id >> 8, xy = id & 255;
            W  = z == 0 ? Wq  : (z == 1 ? Wk  : (z == 2 ? Wv  : Wo));
            Wt = z == 0 ? Wqt : (z == 1 ? Wkt : (z == 2 ? Wvt : Wot));
            K = D_; N = D_;
            n0 = (xy & 15) * 32; k0 = (xy >> 4) * 32;
        } else if (id < 2048) {
            int local = id - 1024;
            W = W1; Wt = W1t; K = D_; N = F_;
            n0 = (local & 63) * 32; k0 = (local >> 6) * 32;
        } else {
            int local = id - 2048;
            W = W2; Wt = W2t; K = F_; N = D_;
            n0 = (local & 15) * 32; k0 = (local >> 4) * 32;
        }
        int tx = threadIdx.x & 31, ty = threadIdx.x >> 5;
        for (int j = 0; j < 32; j += 8)
            tle[ty + j][tx] = W[(size_t)(k0 + ty + j) * N + n0 + tx];
        __syncthreads();
        for (int j = 0; j < 32; j += 8)
            Wt[(size_t)(n0 + ty + j) * K + k0 + tx] = __float2bfloat16(tle[tx][ty + j]);
    } else {
        int wave = threadIdx.x >> 6, lane = threadIdx.x & 63;
        int grow = (id - 3072) * 4 + wave;
        const float* in;
        bf16* out;
        int row;
        if (grow < ROWS) { in = x; out = xn; row = grow; }
        else             { in = y; out = yn; row = grow - ROWS; }
        const float* p = in + (size_t)row * D_ + lane * 8;
        float4 v0 = *(const float4*)p;
        float4 v1 = *(const float4*)(p + 4);
        float s  = v0.x + v0.y + v0.z + v0.w + v1.x + v1.y + v1.z + v1.w;
        float ss = v0.x*v0.x + v0.y*v0.y + v0.z*v0.z + v0.w*v0.w
                 + v1.x*v1.x + v1.y*v1.y + v1.z*v1.z + v1.w*v1.w;
        for (int m = 1; m < 64; m <<= 1) {
            s  += __shfl_xor(s,  m, 64);
            ss += __shfl_xor(ss, m, 64);
        }
        float mu   = s * (1.f / D_);
        float var  = ss * (1.f / D_) - mu * mu;
        float rstd = rsqrtf(var + 1e-6f);
        int c = lane * 8;
        float4 g0 = *(const float4*)(ln1g + c), g1 = *(const float4*)(ln1g + c + 4);
        float4 b0 = *(const float4*)(ln1b + c), b1 = *(const float4*)(ln1b + c + 4);
        bf16* o = out + (size_t)row * D_ + c;
        o[0] = __float2bfloat16((v0.x - mu) * rstd * g0.x + b0.x);
        o[1] = __float2bfloat16((v0.y - mu) * rstd * g0.y + b0.y);
        o[2] = __float2bfloat16((v0.z - mu) * rstd * g0.z + b0.z);
        o[3] = __float2bfloat16((v0.w - mu) * rstd * g0.w + b0.w);
        o[4] = __float2bfloat16((v1.x - mu) * rstd * g1.x + b1.x);
        o[5] = __float2bfloat16((v1.y - mu) * rstd * g1.y + b1.y);
        o[6] = __float2bfloat16((v1.z - mu) * rstd * g1.z + b1.z);
        o[7] = __float2bfloat16((v1.w - mu) * rstd * g1.w + b1.w);
    }
}

// LayerNorm, bf16 input (for x1 -> xn2)
__global__ __launch_bounds__(256) void lnb_kernel(
    const bf16* __restrict__ in, const float* __restrict__ gam,
    const float* __restrict__ bet, bf16* __restrict__ out)
{
    int wave = threadIdx.x >> 6, lane = threadIdx.x & 63;
    int row  = blockIdx.x * 4 + wave;
    bf16x8 v = *(const bf16x8*)(in + (size_t)row * D_ + lane * 8);
    float f[8];
    float s = 0.f, ss = 0.f;
#pragma unroll
    for (int j = 0; j < 8; ++j) {
        f[j] = (float)v[j];
        s += f[j]; ss += f[j] * f[j];
    }
    for (int m = 1; m < 64; m <<= 1) {
        s  += __shfl_xor(s,  m, 64);
        ss += __shfl_xor(ss, m, 64);
    }
    float mu   = s * (1.f / D_);
    float var  = ss * (1.f / D_) - mu * mu;
    float rstd = rsqrtf(var + 1e-6f);
    int c = lane * 8;
    float4 g0 = *(const float4*)(gam + c), g1 = *(const float4*)(gam + c + 4);
    float4 b0 = *(const float4*)(bet + c), b1 = *(const float4*)(bet + c + 4);
    bf16* o = out + (size_t)row * D_ + c;
    o[0] = __float2bfloat16((f[0] - mu) * rstd * g0.x + b0.x);
    o[1] = __float2bfloat16((f[1] - mu) * rstd * g0.y + b0.y);
    o[2] = __float2bfloat16((f[2] - mu) * rstd * g0.z + b0.z);
    o[3] = __float2bfloat16((f[3] - mu) * rstd * g0.w + b0.w);
    o[4] = __float2bfloat16((f[4] - mu) * rstd * g1.x + b1.x);
    o[5] = __float2bfloat16((f[5] - mu) * rstd * g1.y + b1.y);
    o[6] = __float2bfloat16((f[6] - mu) * rstd * g1.z + b1.z);
    o[7] = __float2bfloat16((f[7] - mu) * rstd * g1.w + b1.w);
}

// ---------------------------------------------------------------------------
// 64x64-tile GEMM. 4 waves (2x2, each 32x32), BK=64, reg-staged
// double-buffered LDS, XOR-swizzled. VTRANS epilogue for V projection.
// GELU epilogue for MLP1.
// ---------------------------------------------------------------------------
template<bool RESID, bool RESIDBF, bool ROWMASK, bool OUTBF, bool VTRANS, bool GELU>
__device__ __forceinline__ void gemm64_body(
    const bf16* __restrict__ A, const bf16* __restrict__ Bt,
    const float* __restrict__ bias, const float* __restrict__ resid,
    const bf16* __restrict__ residb, const float* __restrict__ rowmask,
    bf16* __restrict__ outb, float* __restrict__ outf,
    int Nn, int K)
{
    __shared__ __align__(16) char As[2][64 * 128];
    __shared__ __align__(16) char Bs[2][64 * 128];
    int t = threadIdx.x, lane = t & 63, wave = t >> 6;
    int wm = wave >> 1, wn = wave & 1;
    int r16 = lane & 15, g = lane >> 4;
    int m0 = blockIdx.x * 64, n0 = blockIdx.y * 64;

    const int sr0 = t >> 3, sr1 = sr0 + 32, sc = t & 7;
    const int wof0 = sr0 * 128 + ((sc ^ (sr0 & 7)) << 4);
    const int wof1 = sr1 * 128 + ((sc ^ (sr1 & 7)) << 4);
    const int rsw0 = ((g     ^ (r16 & 7)) << 4);
    const int rsw1 = (((4 + g) ^ (r16 & 7)) << 4);

    uint4 a0, a1, b0, b1;
#define G64_LOAD(k0)                                                         \
    a0 = *(const uint4*)(A  + (size_t)(m0 + sr0) * K + (k0) + sc * 8);       \
    a1 = *(const uint4*)(A  + (size_t)(m0 + sr1) * K + (k0) + sc * 8);       \
    b0 = *(const uint4*)(Bt + (size_t)(n0 + sr0) * K + (k0) + sc * 8);       \
    b1 = *(const uint4*)(Bt + (size_t)(n0 + sr1) * K + (k0) + sc * 8);
#define G64_WRITE(buf)                                                       \
    *(uint4*)(As[buf] + wof0) = a0;  *(uint4*)(As[buf] + wof1) = a1;         \
    *(uint4*)(Bs[buf] + wof0) = b0;  *(uint4*)(Bs[buf] + wof1) = b1;

    f32x4 acc[2][2] = {};
    G64_LOAD(0)
    G64_WRITE(0)
    int cur = 0;
    const int nit = K >> 6;
    for (int it = 0; it < nit; ++it) {
        if (it + 1 < nit) { G64_LOAD((it + 1) << 6) }
        __syncthreads();
        bf16x8 af[2][2], bfr[2][2];
#pragma unroll
        for (int i = 0; i < 2; ++i) {
            af[i][0] = *(const bf16x8*)(As[cur] + (wm * 32 + i * 16 + r16) * 128 + rsw0);
            af[i][1] = *(const bf16x8*)(As[cur] + (wm * 32 + i * 16 + r16) * 128 + rsw1);
            bfr[i][0] = *(const bf16x8*)(Bs[cur] + (wn * 32 + i * 16 + r16) * 128 + rsw0);
            bfr[i][1] = *(const bf16x8*)(Bs[cur] + (wn * 32 + i * 16 + r16) * 128 + rsw1);
        }
        __builtin_amdgcn_s_setprio(1);
#pragma unroll
        for (int i = 0; i < 2; ++i)
#pragma unroll
            for (int j = 0; j < 2; ++j) {
                acc[i][j] = __builtin_amdgcn_mfma_f32_16x16x32_bf16(af[i][0], bfr[j][0], acc[i][j], 0, 0, 0);
                acc[i][j] = __builtin_amdgcn_mfma_f32_16x16x32_bf16(af[i][1], bfr[j][1], acc[i][j], 0, 0, 0);
            }
        __builtin_amdgcn_s_setprio(0);
        if (it + 1 < nit) { G64_WRITE(cur ^ 1) }
        cur ^= 1;
    }
#undef G64_LOAD
#undef G64_WRITE

#pragma unroll
    for (int i = 0; i < 2; ++i) {
        int rb = m0 + wm * 32 + i * 16 + g * 4;
#pragma unroll
        for (int j = 0; j < 2; ++j) {
            int cb = n0 + wn * 32 + j * 16 + r16;
            float bia = bias[cb];
            if (VTRANS) {
                bf16x4v w;
#pragma unroll
                for (int e = 0; e < 4; ++e) {
                    int rr = rb + e;
                    float val = acc[i][j][e] + bia;
                    if (ROWMASK) val *= rowmask[rr];
                    w[e] = (__bf16)val;
                }
                int bb = rb >> 11, m = rb & (M_ - 1);
                int bh = bb * H_ + (cb >> 6), d = cb & (DH_ - 1);
                *(bf16x4v*)(outb + ((size_t)bh * DH_ + d) * M_ + m) = w;
            } else {
#pragma unroll
                for (int e = 0; e < 4; ++e) {
                    int rr = rb + e;
                    float val = acc[i][j][e] + bia;
                    if (GELU) val = 0.5f * val * (1.f + erff(val * 0.70710678118654752f));
                    if (RESID) {
                        if (RESIDBF) val += (float)residb[(size_t)rr * Nn + cb];
                        else         val += resid[(size_t)rr * Nn + cb];
                    }
                    if (ROWMASK) val *= rowmask[rr];
                    if (OUTBF)   outb[(size_t)rr * Nn + cb] = __float2bfloat16(val);
                    else         outf[(size_t)rr * Nn + cb] = val;
                }
            }
        }
    }
}

// Wo projection: resid = x (f32), out = x1 bf16
__global__ __launch_bounds__(256) void gemm64_wo(
    const bf16* __restrict__ A, const bf16* __restrict__ Bt,
    const float* __restrict__ bias, const float* __restrict__ resid,
    bf16* __restrict__ outb, int Nn, int K)
{
    gemm64_body<true, false, false, true, false, false>(A, Bt, bias, resid, nullptr, nullptr,
                                                        outb, nullptr, Nn, K);
}

// MLP1: GELU epilogue, out = hff bf16
__global__ __launch_bounds__(256) void gemm64_mlp1(
    const bf16* __restrict__ A, const bf16* __restrict__ Bt,
    const float* __restrict__ bias, bf16* __restrict__ outb, int Nn, int K)
{
    gemm64_body<false, false, false, true, false, true>(A, Bt, bias, nullptr, nullptr, nullptr,
                                                        outb, nullptr, Nn, K);
}

// MLP2: resid = x1 (bf16), out = d_out f32
__global__ __launch_bounds__(256) void gemm64_mlp2(
    const bf16* __restrict__ A, const bf16* __restrict__ Bt,
    const float* __restrict__ bias, const bf16* __restrict__ residb,
    float* __restrict__ outf, int Nn, int K)
{
    gemm64_body<true, true, false, false, false, false>(A, Bt, bias, nullptr, residb, nullptr,
                                                        nullptr, outf, Nn, K);
}

// Batched Q/K/V projection: z selects Q, K, or V; V writes transposed.
__global__ __launch_bounds__(256) void gemm64_qkv(
    const bf16* __restrict__ xn, const bf16* __restrict__ yn,
    const bf16* __restrict__ Wqt, const bf16* __restrict__ Wkt, const bf16* __restrict__ Wvt,
    const float* __restrict__ bq, const float* __restrict__ bk, const float* __restrict__ bv,
    const float* __restrict__ mask_x, const float* __restrict__ mask_y,
    bf16* __restrict__ qb, bf16* __restrict__ kb, bf16* __restrict__ vtb)
{
    int z = blockIdx.z;
    if (z == 2) {
        gemm64_body<false, false, true, true, true, false>(yn, Wvt, bv, nullptr, nullptr, mask_y,
                                                           vtb, nullptr, D_, D_);
    } else {
        const bf16* A        = z == 0 ? xn : yn;
        const bf16* Bt       = z == 0 ? Wqt : Wkt;
        const float* bias    = z == 0 ? bq  : bk;
        const float* rowmask = z == 0 ? mask_x : mask_y;
        bf16* outb           = z == 0 ? qb  : kb;
        gemm64_body<false, false, true, true, false, false>(A, Bt, bias, nullptr, nullptr, rowmask,
                                                            outb, nullptr, D_, D_);
    }
}

// ---------------------------------------------------------------------------
// Flash attention (swapped S^T = K*Q), LDS-staged double-buffered K/V with
// XOR swizzle, reg-staged. 1D grid, XCD-chunked remap. 4 waves, 32 q-rows
// each. __expf softmax, T13 defer-max THR=8. bf16 numerator + (m,l) f32.
// ---------------------------------------------------------------------------
__global__ __launch_bounds__(256, 3) void attn_kernel(
    const bf16* __restrict__ q, const bf16* __restrict__ kk,
    const bf16* __restrict__ vt, bf16* __restrict__ num,
    float* __restrict__ ml)
{
    int bid = blockIdx.x;
    int wg  = (bid & 7) * (ATT_GRID / 8) + (bid >> 3);
    int n0  = (wg & 15) * 128;
    int bh  = (wg >> 4) & 15;
    int sp  = wg >> 8;
    int b = bh >> 3, h = bh & 7;
    int t = threadIdx.x, lane = t & 63, wave = t >> 6;
    int ql = lane & 15, gg = lane >> 4;

    __shared__ __align__(16) char KsB[2][64 * 128];
    __shared__ __align__(16) char VsB[2][64 * 128];
    __shared__ __align__(16) bf16 plds[4][16][72];

    bf16x8 qf0[2], qf1[2];
    {
        int qr0 = b * N_ + n0 + wave * 32 + ql;
        for (int ks = 0; ks < 2; ++ks) {
            bf16x8 qv = *(const bf16x8*)(q + (size_t)qr0 * D_ + h * DH_ + ks * 32 + gg * 8);
            for (int j = 0; j < 8; ++j) qv[j] = (__bf16)((float)qv[j] * 0.125f);
            qf0[ks] = qv;
            bf16x8 qw = *(const bf16x8*)(q + (size_t)(qr0 + 16) * D_ + h * DH_ + ks * 32 + gg * 8);
            for (int j = 0; j < 8; ++j) qw[j] = (__bf16)((float)qw[j] * 0.125f);
            qf1[ks] = qw;
        }
    }

    f32x4 cacc0[4] = {}, cacc1[4] = {};
    float m0r = -1e30f, l0r = 0.f, m1r = -1e30f, l1r = 0.f;

    const bf16* kbase = kk + (size_t)(b * M_ + sp * KV_PER) * D_ + h * DH_;
    const bf16* vtb   = vt + (size_t)bh * DH_ * M_ + sp * KV_PER;

    const int k0r = t >> 3,          kc0 = t & 7;
    const int k1r = (t >> 3) + 32;
    const int wofs0 = k0r * 128 + ((kc0 ^ (k0r & 7)) << 4);
    const int wofs1 = k1r * 128 + ((kc0 ^ (k1r & 7)) << 4);
    const int rsw0 = ((gg     ^ (ql & 7)) << 4);
    const int rsw1 = (((4 + gg) ^ (ql & 7)) << 4);

#define STAGE_LOAD(tt)                                                              \
    kw0 = *(const uint4*)(kbase + (size_t)((tt) * 64 + k0r) * D_ + kc0 * 8);        \
    kw1 = *(const uint4*)(kbase + (size_t)((tt) * 64 + k1r) * D_ + kc0 * 8);        \
    vw0 = *(const uint4*)(vtb + (size_t)k0r * M_ + (tt) * 64 + kc0 * 8);            \
    vw1 = *(const uint4*)(vtb + (size_t)k1r * M_ + (tt) * 64 + kc0 * 8);

#define STAGE_WRITE(buf)                                                            \
    *(uint4*)(KsB[buf] + wofs0) = kw0;                                              \
    *(uint4*)(KsB[buf] + wofs1) = kw1;                                              \
    *(uint4*)(VsB[buf] + wofs0) = vw0;                                              \
    *(uint4*)(VsB[buf] + wofs1) = vw1;

#define SOFTMAX_PV(S, MR, LR, CACC)                                                 \
    {                                                                               \
        float tmax = fmaxf(                                                         \
            fmaxf(fmaxf(fmaxf(S[0][0], S[0][1]), fmaxf(S[0][2], S[0][3])),          \
                  fmaxf(fmaxf(S[1][0], S[1][1]), fmaxf(S[1][2], S[1][3]))),         \
            fmaxf(fmaxf(fmaxf(S[2][0], S[2][1]), fmaxf(S[2][2], S[2][3])),          \
                  fmaxf(fmaxf(S[3][0], S[3][1]), fmaxf(S[3][2], S[3][3]))));        \
        tmax = fmaxf(tmax, __shfl_xor(tmax, 16, 64));                               \
        tmax = fmaxf(tmax, __shfl_xor(tmax, 32, 64));                               \
        if (__any(tmax - MR > 8.f)) {                                               \
            float mnew = fmaxf(MR, tmax);                                           \
            float scl  = __expf(MR - mnew);                                         \
            MR = mnew;                                                              \
            LR *= scl;                                                              \
            for (int df = 0; df < 4; ++df)                                          \
                for (int e = 0; e < 4; ++e) CACC[df][e] *= scl;                     \
        }                                                                           \
        float p[4][4]; float ps = 0.f;                                              \
        for (int nf = 0; nf < 4; ++nf)                                              \
            for (int e = 0; e < 4; ++e) { p[nf][e] = __expf(S[nf][e] - MR); ps += p[nf][e]; } \
        ps += __shfl_xor(ps, 16, 64);                                               \
        ps += __shfl_xor(ps, 32, 64);                                               \
        LR += ps;                                                                   \
        for (int nf = 0; nf < 4; ++nf) {                                            \
            bf16x4v w;                                                              \
            w[0] = (__bf16)p[nf][0]; w[1] = (__bf16)p[nf][1];                       \
            w[2] = (__bf16)p[nf][2]; w[3] = (__bf16)p[nf][3];                       \
            *(bf16x4v*)(&plds[wave][ql][nf * 16 + 4 * gg]) = w;                     \
        }                                                                           \
        __builtin_amdgcn_s_setprio(1);                                              \
        for (int ks = 0; ks < 2; ++ks) {                                            \
            bf16x8 pf = *(const bf16x8*)((const char*)&plds[wave][0][0]             \
                                         + ql * 144 + ks * 64 + gg * 16);           \
            for (int df = 0; df < 4; ++df)                                          \
                CACC[df] = __builtin_amdgcn_mfma_f32_16x16x32_bf16(                 \
                    vf[df * 2 + ks], pf, CACC[df], 0, 0, 0);                        \
        }                                                                           \
        __builtin_amdgcn_s_setprio(0);                                              \
    }

    uint4 kw0, kw1, vw0, vw1;
    STAGE_LOAD(0)
    STAGE_WRITE(0)
    int cur = 0;

    for (int tt = 0; tt < NT; ++tt) {
        if (tt + 1 < NT) { STAGE_LOAD(tt + 1) }
        __syncthreads();

        const char* Kb = KsB[cur];
        const char* Vb = VsB[cur];

        bf16x8 kf[8];
#pragma unroll
        for (int nf = 0; nf < 4; ++nf) {
            kf[nf * 2 + 0] = *(const bf16x8*)(Kb + (nf * 16 + ql) * 128 + rsw0);
            kf[nf * 2 + 1] = *(const bf16x8*)(Kb + (nf * 16 + ql) * 128 + rsw1);
        }

        f32x4 s0[4] = {}, s1[4] = {};
        __builtin_amdgcn_s_setprio(1);
#pragma unroll
        for (int nf = 0; nf < 4; ++nf) {
            s0[nf] = __builtin_amdgcn_mfma_f32_16x16x32_bf16(kf[nf * 2 + 0], qf0[0], s0[nf], 0, 0, 0);
            s0[nf] = __builtin_amdgcn_mfma_f32_16x16x32_bf16(kf[nf * 2 + 1], qf0[1], s0[nf], 0, 0, 0);
            s1[nf] = __builtin_amdgcn_mfma_f32_16x16x32_bf16(kf[nf * 2 + 0], qf1[0], s1[nf], 0, 0, 0);
            s1[nf] = __builtin_amdgcn_mfma_f32_16x16x32_bf16(kf[nf * 2 + 1], qf1[1], s1[nf], 0, 0, 0);
        }
        __builtin_amdgcn_s_setprio(0);

        bf16x8 vf[8];
#pragma unroll
        for (int df = 0; df < 4; ++df) {
            vf[df * 2 + 0] = *(const bf16x8*)(Vb + (df * 16 + ql) * 128 + rsw0);
            vf[df * 2 + 1] = *(const bf16x8*)(Vb + (df * 16 + ql) * 128 + rsw1);
        }

        SOFTMAX_PV(s0, m0r, l0r, cacc0)
        SOFTMAX_PV(s1, m1r, l1r, cacc1)

        if (tt + 1 < NT) { STAGE_WRITE(cur ^ 1) }
        cur ^= 1;
    }

    {
        int qr0 = b * N_ + n0 + wave * 32 + ql;
        bf16* nb0 = num + (size_t)sp * ROWS * D_ + (size_t)qr0 * D_ + h * DH_;
        bf16* nb1 = num + (size_t)sp * ROWS * D_ + (size_t)(qr0 + 16) * D_ + h * DH_;
#pragma unroll
        for (int df = 0; df < 4; ++df) {
            bf16x4v w0, w1;
#pragma unroll
            for (int e = 0; e < 4; ++e) {
                w0[e] = (__bf16)cacc0[df][e];
                w1[e] = (__bf16)cacc1[df][e];
            }
            *(bf16x4v*)(nb0 + df * 16 + 4 * gg) = w0;
            *(bf16x4v*)(nb1 + df * 16 + 4 * gg) = w1;
        }
        if (lane < 16) {
            size_t base = ((size_t)(sp * (B_ * H_) + bh) * N_ + (n0 + wave * 32 + ql)) * 2;
            ml[base] = m0r; ml[base + 1] = l0r;
            size_t base1 = ((size_t)(sp * (B_ * H_) + bh) * N_ + (n0 + wave * 32 + 16 + ql)) * 2;
            ml[base1] = m1r; ml[base1 + 1] = l1r;
        }
    }
#undef STAGE_LOAD
#undef STAGE_WRITE
#undef SOFTMAX_PV
}

// Combine the SPLIT partials (bf16 numerators) -> bf16 ctx. 8 elems/thread.
__global__ __launch_bounds__(256) void attn_combine(
    const bf16* __restrict__ num, const float* __restrict__ ml,
    bf16* __restrict__ ctx)
{
    int idx = blockIdx.x * 256 + threadIdx.x;
    int row = idx >> 6;              // 64 eight-col chunks per row
    int c8  = (idx & 63) << 3;
    int b = row >> 11, n = row & (N_ - 1);
    int h = c8 >> 6;
    int bh = (b << 3) + h;
    float mv[SPLIT], lv[SPLIT];
#pragma unroll
    for (int sp = 0; sp < SPLIT; ++sp) {
        const float* mp = ml + ((size_t)(sp * (B_ * H_) + bh) * N_ + n) * 2;
        mv[sp] = mp[0]; lv[sp] = mp[1];
    }
    float mx = mv[0];
#pragma unroll
    for (int sp = 1; sp < SPLIT; ++sp) mx = fmaxf(mx, mv[sp]);
    float den = 0.f;
    float wsc[SPLIT];
#pragma unroll
    for (int sp = 0; sp < SPLIT; ++sp) {
        wsc[sp] = __expf(mv[sp] - mx);
        den += wsc[sp] * lv[sp];
    }
    float inv = 1.f / den;
    float a[8] = {};
#pragma unroll
    for (int sp = 0; sp < SPLIT; ++sp) {
        bf16x8 v = *(const bf16x8*)(num + (size_t)sp * ROWS * D_ + (size_t)row * D_ + c8);
#pragma unroll
        for (int e = 0; e < 8; ++e) a[e] += wsc[sp] * (float)v[e];
    }
    bf16x8 o;
#pragma unroll
    for (int e = 0; e < 8; ++e) o[e] = (__bf16)(a[e] * inv);
    *(bf16x8*)(ctx + (size_t)row * D_ + c8) = o;
}

// ---------------------------------------------------------------------------
extern "C" void kernel_launch(void* const* d_in, const int* in_sizes, int n_in,
                              void* d_out, int out_size, void* d_ws, size_t ws_size,
                              hipStream_t stream)
{
    const float* x      = (const float*)d_in[0];
    const float* y      = (const float*)d_in[1];
    const float* mask_x = (const float*)d_in[2];
    const float* mask_y = (const float*)d_in[3];
    const float* Wq = (const float*)d_in[4];  const float* bq = (const float*)d_in[5];
    const float* Wk = (const float*)d_in[6];  const float* bk = (const float*)d_in[7];
    const float* Wv = (const float*)d_in[8];  const float* bv = (const float*)d_in[9];
    const float* Wo = (const float*)d_in[10]; const float* bo = (const float*)d_in[11];
    const float* W1 = (const float*)d_in[12]; const float* b1 = (const float*)d_in[13];
    const float* W2 = (const float*)d_in[14]; const float* b2 = (const float*)d_in[15];
    const float* ln1g = (const float*)d_in[16]; const float* ln1b = (const float*)d_in[17];
    const float* ln2g = (const float*)d_in[18]; const float* ln2b = (const float*)d_in[19];

    char* ws = (char*)d_ws;
    const size_t SZA = (size_t)ROWS * D_ * 2;     // 4 MiB bf16 activation
    bf16* xn   = (bf16*)ws;            ws += SZA;
    bf16* yn   = (bf16*)ws;            ws += SZA;
    bf16* qb   = (bf16*)ws;            ws += SZA;
    bf16* kb   = (bf16*)ws;            ws += SZA;
    bf16* vtb  = (bf16*)ws;            ws += SZA;
    bf16* ctxb = (bf16*)ws;            ws += SZA;
    bf16* xn2  = (bf16*)ws;            ws += SZA;
    bf16* x1b  = (bf16*)ws;            ws += SZA;
    bf16* hff  = (bf16*)ws;            ws += (size_t)ROWS * F_ * 2;
    bf16* Wqt = (bf16*)ws;             ws += (size_t)D_ * D_ * 2;
    bf16* Wkt = (bf16*)ws;             ws += (size_t)D_ * D_ * 2;
    bf16* Wvt = (bf16*)ws;             ws += (size_t)D_ * D_ * 2;
    bf16* Wot = (bf16*)ws;             ws += (size_t)D_ * D_ * 2;
    bf16* W1t = (bf16*)ws;             ws += (size_t)D_ * F_ * 2;
    bf16* W2t = (bf16*)ws;             ws += (size_t)F_ * D_ * 2;
    bf16* numb = (bf16*)ws;            ws += (size_t)SPLIT * ROWS * D_ * 2;
    float* mlb = (float*)ws;           ws += (size_t)SPLIT * B_ * H_ * N_ * 2 * 4;

    // One fused prep launch: all 6 weight transposes + LN(x) + LN(y)
    prep_kernel<<<5120, 256, 0, stream>>>(
        Wq, Wk, Wv, Wo, W1, W2, Wqt, Wkt, Wvt, Wot, W1t, W2t,
        x, y, ln1g, ln1b, xn, yn);

    // Q/K/V projections; V written directly in per-head transposed layout
    gemm64_qkv<<<dim3(ROWS / 64, D_ / 64, 3), 256, 0, stream>>>(
        xn, yn, Wqt, Wkt, Wvt, bq, bk, bv, mask_x, mask_y, qb, kb, vtb);

    attn_kernel<<<ATT_GRID, 256, 0, stream>>>(qb, kb, vtb, numb, mlb);
    attn_combine<<<(ROWS * D_ / 8) / 256, 256, 0, stream>>>(numb, mlb, ctxb);

    // out-proj + residual(x f32) -> x1 (bf16)
    gemm64_wo<<<dim3(ROWS / 64, D_ / 64), 256, 0, stream>>>(
        ctxb, Wot, bo, x, x1b, D_, D_);

    // ln2 on bf16 x1
    lnb_kernel<<<ROWS / 4, 256, 0, stream>>>(x1b, ln2g, ln2b, xn2);

    // MLP1 + GELU -> hff (bf16), gemm64 structure (2048 blocks)
    gemm64_mlp1<<<dim3(ROWS / 64, F_ / 64), 256, 0, stream>>>(
        xn2, W1t, b1, hff, F_, D_);

    // MLP2 + residual(x1 bf16) -> d_out (f32)
    gemm64_mlp2<<<dim3(ROWS / 64, D_ / 64), 256, 0, stream>>>(
        hff, W2t, b2, x1b, (float*)d_out, D_, F_);
}

// Round 15
// 110.910 us; speedup vs baseline: 1.3147x; 1.0073x over previous
//
#include <hip/hip_runtime.h>
#include <hip/hip_bf16.h>

// Problem constants
#define B_  2
#define N_  2048
#define M_  2048
#define D_  512
#define H_  8
#define F_  2048
#define DH_ 64
#define ROWS 4096   // B_*N_ == B_*M_

#define SPLIT 4
#define KV_PER (M_ / SPLIT)   // 512
#define NT (KV_PER / 64)      // 8 tiles of 64 keys
#define ATT_GRID (16 * 16 * SPLIT)   // n0(16) x bh(16) x sp = 1024

typedef __bf16 bf16x8 __attribute__((ext_vector_type(8)));
typedef __bf16 bf16x4v __attribute__((ext_vector_type(4)));
typedef float  f32x4  __attribute__((ext_vector_type(4)));
using bf16 = __hip_bfloat16;

// ---------------------------------------------------------------------------
// Fused prep: blocks 0..3071 = weight transposes (f32->bf16, W[K,N]->Wt[N,K]);
// blocks 3072..5119 = LayerNorm of x and y.
// ---------------------------------------------------------------------------
__global__ __launch_bounds__(256) void prep_kernel(
    const float* __restrict__ Wq, const float* __restrict__ Wk,
    const float* __restrict__ Wv, const float* __restrict__ Wo,
    const float* __restrict__ W1, const float* __restrict__ W2,
    bf16* __restrict__ Wqt, bf16* __restrict__ Wkt,
    bf16* __restrict__ Wvt, bf16* __restrict__ Wot,
    bf16* __restrict__ W1t, bf16* __restrict__ W2t,
    const float* __restrict__ x, const float* __restrict__ y,
    const float* __restrict__ ln1g, const float* __restrict__ ln1b,
    bf16* __restrict__ xn, bf16* __restrict__ yn)
{
    __shared__ float tle[32][33];
    int id = blockIdx.x;
    if (id < 3072) {
        const float* W; bf16* Wt; int K, N, n0, k0;
        if (id < 1024) {
            int z = id >> 8, xy = id & 255;
            W  = z == 0 ? Wq  : (z == 1 ? Wk  : (z == 2 ? Wv  : Wo));
            Wt = z == 0 ? Wqt : (z == 1 ? Wkt : (z == 2 ? Wvt : Wot));
            K = D_; N = D_;
            n0 = (xy & 15) * 32; k0 = (xy >> 4) * 32;
        } else if (id < 2048) {
            int local = id - 1024;
            W = W1; Wt = W1t; K = D_; N = F_;
            n0 = (local & 63) * 32; k0 = (local >> 6) * 32;
        } else {
            int local = id - 2048;
            W = W2; Wt = W2t; K = F_; N = D_;
            n0 = (local & 15) * 32; k0 = (local >> 4) * 32;
        }
        int tx = threadIdx.x & 31, ty = threadIdx.x >> 5;
        for (int j = 0; j < 32; j += 8)
            tle[ty + j][tx] = W[(size_t)(k0 + ty + j) * N + n0 + tx];
        __syncthreads();
        for (int j = 0; j < 32; j += 8)
            Wt[(size_t)(n0 + ty + j) * K + k0 + tx] = __float2bfloat16(tle[tx][ty + j]);
    } else {
        int wave = threadIdx.x >> 6, lane = threadIdx.x & 63;
        int grow = (id - 3072) * 4 + wave;
        const float* in;
        bf16* out;
        int row;
        if (grow < ROWS) { in = x; out = xn; row = grow; }
        else             { in = y; out = yn; row = grow - ROWS; }
        const float* p = in + (size_t)row * D_ + lane * 8;
        float4 v0 = *(const float4*)p;
        float4 v1 = *(const float4*)(p + 4);
        float s  = v0.x + v0.y + v0.z + v0.w + v1.x + v1.y + v1.z + v1.w;
        float ss = v0.x*v0.x + v0.y*v0.y + v0.z*v0.z + v0.w*v0.w
                 + v1.x*v1.x + v1.y*v1.y + v1.z*v1.z + v1.w*v1.w;
        for (int m = 1; m < 64; m <<= 1) {
            s  += __shfl_xor(s,  m, 64);
            ss += __shfl_xor(ss, m, 64);
        }
        float mu   = s * (1.f / D_);
        float var  = ss * (1.f / D_) - mu * mu;
        float rstd = rsqrtf(var + 1e-6f);
        int c = lane * 8;
        float4 g0 = *(const float4*)(ln1g + c), g1 = *(const float4*)(ln1g + c + 4);
        float4 b0 = *(const float4*)(ln1b + c), b1 = *(const float4*)(ln1b + c + 4);
        bf16* o = out + (size_t)row * D_ + c;
        o[0] = __float2bfloat16((v0.x - mu) * rstd * g0.x + b0.x);
        o[1] = __float2bfloat16((v0.y - mu) * rstd * g0.y + b0.y);
        o[2] = __float2bfloat16((v0.z - mu) * rstd * g0.z + b0.z);
        o[3] = __float2bfloat16((v0.w - mu) * rstd * g0.w + b0.w);
        o[4] = __float2bfloat16((v1.x - mu) * rstd * g1.x + b1.x);
        o[5] = __float2bfloat16((v1.y - mu) * rstd * g1.y + b1.y);
        o[6] = __float2bfloat16((v1.z - mu) * rstd * g1.z + b1.z);
        o[7] = __float2bfloat16((v1.w - mu) * rstd * g1.w + b1.w);
    }
}

// LayerNorm, bf16 input (for x1 -> xn2)
__global__ __launch_bounds__(256) void lnb_kernel(
    const bf16* __restrict__ in, const float* __restrict__ gam,
    const float* __restrict__ bet, bf16* __restrict__ out)
{
    int wave = threadIdx.x >> 6, lane = threadIdx.x & 63;
    int row  = blockIdx.x * 4 + wave;
    bf16x8 v = *(const bf16x8*)(in + (size_t)row * D_ + lane * 8);
    float f[8];
    float s = 0.f, ss = 0.f;
#pragma unroll
    for (int j = 0; j < 8; ++j) {
        f[j] = (float)v[j];
        s += f[j]; ss += f[j] * f[j];
    }
    for (int m = 1; m < 64; m <<= 1) {
        s  += __shfl_xor(s,  m, 64);
        ss += __shfl_xor(ss, m, 64);
    }
    float mu   = s * (1.f / D_);
    float var  = ss * (1.f / D_) - mu * mu;
    float rstd = rsqrtf(var + 1e-6f);
    int c = lane * 8;
    float4 g0 = *(const float4*)(gam + c), g1 = *(const float4*)(gam + c + 4);
    float4 b0 = *(const float4*)(bet + c), b1 = *(const float4*)(bet + c + 4);
    bf16* o = out + (size_t)row * D_ + c;
    o[0] = __float2bfloat16((f[0] - mu) * rstd * g0.x + b0.x);
    o[1] = __float2bfloat16((f[1] - mu) * rstd * g0.y + b0.y);
    o[2] = __float2bfloat16((f[2] - mu) * rstd * g0.z + b0.z);
    o[3] = __float2bfloat16((f[3] - mu) * rstd * g0.w + b0.w);
    o[4] = __float2bfloat16((f[4] - mu) * rstd * g1.x + b1.x);
    o[5] = __float2bfloat16((f[5] - mu) * rstd * g1.y + b1.y);
    o[6] = __float2bfloat16((f[6] - mu) * rstd * g1.z + b1.z);
    o[7] = __float2bfloat16((f[7] - mu) * rstd * g1.w + b1.w);
}

// ---------------------------------------------------------------------------
// 64x64-tile GEMM. 4 waves (2x2, each 32x32), BK=64, reg-staged
// double-buffered LDS, XOR-swizzled. VTRANS epilogue for V projection.
// GELU epilogue for MLP1.
// ---------------------------------------------------------------------------
template<bool RESID, bool RESIDBF, bool ROWMASK, bool OUTBF, bool VTRANS, bool GELU>
__device__ __forceinline__ void gemm64_body(
    const bf16* __restrict__ A, const bf16* __restrict__ Bt,
    const float* __restrict__ bias, const float* __restrict__ resid,
    const bf16* __restrict__ residb, const float* __restrict__ rowmask,
    bf16* __restrict__ outb, float* __restrict__ outf,
    int Nn, int K)
{
    __shared__ __align__(16) char As[2][64 * 128];
    __shared__ __align__(16) char Bs[2][64 * 128];
    int t = threadIdx.x, lane = t & 63, wave = t >> 6;
    int wm = wave >> 1, wn = wave & 1;
    int r16 = lane & 15, g = lane >> 4;
    int m0 = blockIdx.x * 64, n0 = blockIdx.y * 64;

    const int sr0 = t >> 3, sr1 = sr0 + 32, sc = t & 7;
    const int wof0 = sr0 * 128 + ((sc ^ (sr0 & 7)) << 4);
    const int wof1 = sr1 * 128 + ((sc ^ (sr1 & 7)) << 4);
    const int rsw0 = ((g     ^ (r16 & 7)) << 4);
    const int rsw1 = (((4 + g) ^ (r16 & 7)) << 4);

    uint4 a0, a1, b0, b1;
#define G64_LOAD(k0)                                                         \
    a0 = *(const uint4*)(A  + (size_t)(m0 + sr0) * K + (k0) + sc * 8);       \
    a1 = *(const uint4*)(A  + (size_t)(m0 + sr1) * K + (k0) + sc * 8);       \
    b0 = *(const uint4*)(Bt + (size_t)(n0 + sr0) * K + (k0) + sc * 8);       \
    b1 = *(const uint4*)(Bt + (size_t)(n0 + sr1) * K + (k0) + sc * 8);
#define G64_WRITE(buf)                                                       \
    *(uint4*)(As[buf] + wof0) = a0;  *(uint4*)(As[buf] + wof1) = a1;         \
    *(uint4*)(Bs[buf] + wof0) = b0;  *(uint4*)(Bs[buf] + wof1) = b1;

    f32x4 acc[2][2] = {};
    G64_LOAD(0)
    G64_WRITE(0)
    int cur = 0;
    const int nit = K >> 6;
    for (int it = 0; it < nit; ++it) {
        if (it + 1 < nit) { G64_LOAD((it + 1) << 6) }
        __syncthreads();
        bf16x8 af[2][2], bfr[2][2];
#pragma unroll
        for (int i = 0; i < 2; ++i) {
            af[i][0] = *(const bf16x8*)(As[cur] + (wm * 32 + i * 16 + r16) * 128 + rsw0);
            af[i][1] = *(const bf16x8*)(As[cur] + (wm * 32 + i * 16 + r16) * 128 + rsw1);
            bfr[i][0] = *(const bf16x8*)(Bs[cur] + (wn * 32 + i * 16 + r16) * 128 + rsw0);
            bfr[i][1] = *(const bf16x8*)(Bs[cur] + (wn * 32 + i * 16 + r16) * 128 + rsw1);
        }
        __builtin_amdgcn_s_setprio(1);
#pragma unroll
        for (int i = 0; i < 2; ++i)
#pragma unroll
            for (int j = 0; j < 2; ++j) {
                acc[i][j] = __builtin_amdgcn_mfma_f32_16x16x32_bf16(af[i][0], bfr[j][0], acc[i][j], 0, 0, 0);
                acc[i][j] = __builtin_amdgcn_mfma_f32_16x16x32_bf16(af[i][1], bfr[j][1], acc[i][j], 0, 0, 0);
            }
        __builtin_amdgcn_s_setprio(0);
        if (it + 1 < nit) { G64_WRITE(cur ^ 1) }
        cur ^= 1;
    }
#undef G64_LOAD
#undef G64_WRITE

#pragma unroll
    for (int i = 0; i < 2; ++i) {
        int rb = m0 + wm * 32 + i * 16 + g * 4;
#pragma unroll
        for (int j = 0; j < 2; ++j) {
            int cb = n0 + wn * 32 + j * 16 + r16;
            float bia = bias[cb];
            if (VTRANS) {
                bf16x4v w;
#pragma unroll
                for (int e = 0; e < 4; ++e) {
                    int rr = rb + e;
                    float val = acc[i][j][e] + bia;
                    if (ROWMASK) val *= rowmask[rr];
                    w[e] = (__bf16)val;
                }
                int bb = rb >> 11, m = rb & (M_ - 1);
                int bh = bb * H_ + (cb >> 6), d = cb & (DH_ - 1);
                *(bf16x4v*)(outb + ((size_t)bh * DH_ + d) * M_ + m) = w;
            } else {
#pragma unroll
                for (int e = 0; e < 4; ++e) {
                    int rr = rb + e;
                    float val = acc[i][j][e] + bia;
                    if (GELU) val = 0.5f * val * (1.f + erff(val * 0.70710678118654752f));
                    if (RESID) {
                        if (RESIDBF) val += (float)residb[(size_t)rr * Nn + cb];
                        else         val += resid[(size_t)rr * Nn + cb];
                    }
                    if (ROWMASK) val *= rowmask[rr];
                    if (OUTBF)   outb[(size_t)rr * Nn + cb] = __float2bfloat16(val);
                    else         outf[(size_t)rr * Nn + cb] = val;
                }
            }
        }
    }
}

// Wo projection: resid = x (f32), out = x1 bf16
__global__ __launch_bounds__(256) void gemm64_wo(
    const bf16* __restrict__ A, const bf16* __restrict__ Bt,
    const float* __restrict__ bias, const float* __restrict__ resid,
    bf16* __restrict__ outb, int Nn, int K)
{
    gemm64_body<true, false, false, true, false, false>(A, Bt, bias, resid, nullptr, nullptr,
                                                        outb, nullptr, Nn, K);
}

// MLP1: GELU epilogue, out = hff bf16
__global__ __launch_bounds__(256) void gemm64_mlp1(
    const bf16* __restrict__ A, const bf16* __restrict__ Bt,
    const float* __restrict__ bias, bf16* __restrict__ outb, int Nn, int K)
{
    gemm64_body<false, false, false, true, false, true>(A, Bt, bias, nullptr, nullptr, nullptr,
                                                        outb, nullptr, Nn, K);
}

// MLP2: resid = x1 (bf16), out = d_out f32
__global__ __launch_bounds__(256) void gemm64_mlp2(
    const bf16* __restrict__ A, const bf16* __restrict__ Bt,
    const float* __restrict__ bias, const bf16* __restrict__ residb,
    float* __restrict__ outf, int Nn, int K)
{
    gemm64_body<true, true, false, false, false, false>(A, Bt, bias, nullptr, residb, nullptr,
                                                        nullptr, outf, Nn, K);
}

// Batched Q/K/V projection: z selects Q, K, or V; V writes transposed.
__global__ __launch_bounds__(256) void gemm64_qkv(
    const bf16* __restrict__ xn, const bf16* __restrict__ yn,
    const bf16* __restrict__ Wqt, const bf16* __restrict__ Wkt, const bf16* __restrict__ Wvt,
    const float* __restrict__ bq, const float* __restrict__ bk, const float* __restrict__ bv,
    const float* __restrict__ mask_x, const float* __restrict__ mask_y,
    bf16* __restrict__ qb, bf16* __restrict__ kb, bf16* __restrict__ vtb)
{
    int z = blockIdx.z;
    if (z == 2) {
        gemm64_body<false, false, true, true, true, false>(yn, Wvt, bv, nullptr, nullptr, mask_y,
                                                           vtb, nullptr, D_, D_);
    } else {
        const bf16* A        = z == 0 ? xn : yn;
        const bf16* Bt       = z == 0 ? Wqt : Wkt;
        const float* bias    = z == 0 ? bq  : bk;
        const float* rowmask = z == 0 ? mask_x : mask_y;
        bf16* outb           = z == 0 ? qb  : kb;
        gemm64_body<false, false, true, true, false, false>(A, Bt, bias, nullptr, nullptr, rowmask,
                                                            outb, nullptr, D_, D_);
    }
}

// ---------------------------------------------------------------------------
// Flash attention (swapped S^T = K*Q), LDS-staged double-buffered K/V with
// XOR swizzle, reg-staged. 1D grid, XCD-chunked remap. 4 waves, 32 q-rows
// each. __expf softmax, T13 defer-max THR=8. Deferred l-reduce: per-lane
// partial l accumulated through the loop, single cross-lane reduce at end.
// bf16 numerator + (m,l) f32.
// ---------------------------------------------------------------------------
__global__ __launch_bounds__(256, 3) void attn_kernel(
    const bf16* __restrict__ q, const bf16* __restrict__ kk,
    const bf16* __restrict__ vt, bf16* __restrict__ num,
    float* __restrict__ ml)
{
    int bid = blockIdx.x;
    int wg  = (bid & 7) * (ATT_GRID / 8) + (bid >> 3);
    int n0  = (wg & 15) * 128;
    int bh  = (wg >> 4) & 15;
    int sp  = wg >> 8;
    int b = bh >> 3, h = bh & 7;
    int t = threadIdx.x, lane = t & 63, wave = t >> 6;
    int ql = lane & 15, gg = lane >> 4;

    __shared__ __align__(16) char KsB[2][64 * 128];
    __shared__ __align__(16) char VsB[2][64 * 128];
    __shared__ __align__(16) bf16 plds[4][16][72];

    bf16x8 qf0[2], qf1[2];
    {
        int qr0 = b * N_ + n0 + wave * 32 + ql;
        for (int ks = 0; ks < 2; ++ks) {
            bf16x8 qv = *(const bf16x8*)(q + (size_t)qr0 * D_ + h * DH_ + ks * 32 + gg * 8);
            for (int j = 0; j < 8; ++j) qv[j] = (__bf16)((float)qv[j] * 0.125f);
            qf0[ks] = qv;
            bf16x8 qw = *(const bf16x8*)(q + (size_t)(qr0 + 16) * D_ + h * DH_ + ks * 32 + gg * 8);
            for (int j = 0; j < 8; ++j) qw[j] = (__bf16)((float)qw[j] * 0.125f);
            qf1[ks] = qw;
        }
    }

    f32x4 cacc0[4] = {}, cacc1[4] = {};
    float m0r = -1e30f, l0r = 0.f, m1r = -1e30f, l1r = 0.f;  // l per-lane partial

    const bf16* kbase = kk + (size_t)(b * M_ + sp * KV_PER) * D_ + h * DH_;
    const bf16* vtb   = vt + (size_t)bh * DH_ * M_ + sp * KV_PER;

    const int k0r = t >> 3,          kc0 = t & 7;
    const int k1r = (t >> 3) + 32;
    const int wofs0 = k0r * 128 + ((kc0 ^ (k0r & 7)) << 4);
    const int wofs1 = k1r * 128 + ((kc0 ^ (k1r & 7)) << 4);
    const int rsw0 = ((gg     ^ (ql & 7)) << 4);
    const int rsw1 = (((4 + gg) ^ (ql & 7)) << 4);

#define STAGE_LOAD(tt)                                                              \
    kw0 = *(const uint4*)(kbase + (size_t)((tt) * 64 + k0r) * D_ + kc0 * 8);        \
    kw1 = *(const uint4*)(kbase + (size_t)((tt) * 64 + k1r) * D_ + kc0 * 8);        \
    vw0 = *(const uint4*)(vtb + (size_t)k0r * M_ + (tt) * 64 + kc0 * 8);            \
    vw1 = *(const uint4*)(vtb + (size_t)k1r * M_ + (tt) * 64 + kc0 * 8);

#define STAGE_WRITE(buf)                                                            \
    *(uint4*)(KsB[buf] + wofs0) = kw0;                                              \
    *(uint4*)(KsB[buf] + wofs1) = kw1;                                              \
    *(uint4*)(VsB[buf] + wofs0) = vw0;                                              \
    *(uint4*)(VsB[buf] + wofs1) = vw1;

// l kept per-lane (no cross-lane reduce inside the loop); scl is row-uniform
// so scaling the per-lane partial is exact.
#define SOFTMAX_PV(S, MR, LR, CACC)                                                 \
    {                                                                               \
        float tmax = fmaxf(                                                         \
            fmaxf(fmaxf(fmaxf(S[0][0], S[0][1]), fmaxf(S[0][2], S[0][3])),          \
                  fmaxf(fmaxf(S[1][0], S[1][1]), fmaxf(S[1][2], S[1][3]))),         \
            fmaxf(fmaxf(fmaxf(S[2][0], S[2][1]), fmaxf(S[2][2], S[2][3])),          \
                  fmaxf(fmaxf(S[3][0], S[3][1]), fmaxf(S[3][2], S[3][3]))));        \
        tmax = fmaxf(tmax, __shfl_xor(tmax, 16, 64));                               \
        tmax = fmaxf(tmax, __shfl_xor(tmax, 32, 64));                               \
        if (__any(tmax - MR > 8.f)) {                                               \
            float mnew = fmaxf(MR, tmax);                                           \
            float scl  = __expf(MR - mnew);                                         \
            MR = mnew;                                                              \
            LR *= scl;                                                              \
            for (int df = 0; df < 4; ++df)                                          \
                for (int e = 0; e < 4; ++e) CACC[df][e] *= scl;                     \
        }                                                                           \
        float p[4][4]; float ps = 0.f;                                              \
        for (int nf = 0; nf < 4; ++nf)                                              \
            for (int e = 0; e < 4; ++e) { p[nf][e] = __expf(S[nf][e] - MR); ps += p[nf][e]; } \
        LR += ps;                                                                   \
        for (int nf = 0; nf < 4; ++nf) {                                            \
            bf16x4v w;                                                              \
            w[0] = (__bf16)p[nf][0]; w[1] = (__bf16)p[nf][1];                       \
            w[2] = (__bf16)p[nf][2]; w[3] = (__bf16)p[nf][3];                       \
            *(bf16x4v*)(&plds[wave][ql][nf * 16 + 4 * gg]) = w;                     \
        }                                                                           \
        __builtin_amdgcn_s_setprio(1);                                              \
        for (int ks = 0; ks < 2; ++ks) {                                            \
            bf16x8 pf = *(const bf16x8*)((const char*)&plds[wave][0][0]             \
                                         + ql * 144 + ks * 64 + gg * 16);           \
            for (int df = 0; df < 4; ++df)                                          \
                CACC[df] = __builtin_amdgcn_mfma_f32_16x16x32_bf16(                 \
                    vf[df * 2 + ks], pf, CACC[df], 0, 0, 0);                        \
        }                                                                           \
        __builtin_amdgcn_s_setprio(0);                                              \
    }

    uint4 kw0, kw1, vw0, vw1;
    STAGE_LOAD(0)
    STAGE_WRITE(0)
    int cur = 0;

    for (int tt = 0; tt < NT; ++tt) {
        if (tt + 1 < NT) { STAGE_LOAD(tt + 1) }
        __syncthreads();

        const char* Kb = KsB[cur];
        const char* Vb = VsB[cur];

        bf16x8 kf[8];
#pragma unroll
        for (int nf = 0; nf < 4; ++nf) {
            kf[nf * 2 + 0] = *(const bf16x8*)(Kb + (nf * 16 + ql) * 128 + rsw0);
            kf[nf * 2 + 1] = *(const bf16x8*)(Kb + (nf * 16 + ql) * 128 + rsw1);
        }

        f32x4 s0[4] = {}, s1[4] = {};
        __builtin_amdgcn_s_setprio(1);
#pragma unroll
        for (int nf = 0; nf < 4; ++nf) {
            s0[nf] = __builtin_amdgcn_mfma_f32_16x16x32_bf16(kf[nf * 2 + 0], qf0[0], s0[nf], 0, 0, 0);
            s0[nf] = __builtin_amdgcn_mfma_f32_16x16x32_bf16(kf[nf * 2 + 1], qf0[1], s0[nf], 0, 0, 0);
            s1[nf] = __builtin_amdgcn_mfma_f32_16x16x32_bf16(kf[nf * 2 + 0], qf1[0], s1[nf], 0, 0, 0);
            s1[nf] = __builtin_amdgcn_mfma_f32_16x16x32_bf16(kf[nf * 2 + 1], qf1[1], s1[nf], 0, 0, 0);
        }
        __builtin_amdgcn_s_setprio(0);

        bf16x8 vf[8];
#pragma unroll
        for (int df = 0; df < 4; ++df) {
            vf[df * 2 + 0] = *(const bf16x8*)(Vb + (df * 16 + ql) * 128 + rsw0);
            vf[df * 2 + 1] = *(const bf16x8*)(Vb + (df * 16 + ql) * 128 + rsw1);
        }

        SOFTMAX_PV(s0, m0r, l0r, cacc0)
        SOFTMAX_PV(s1, m1r, l1r, cacc1)

        if (tt + 1 < NT) { STAGE_WRITE(cur ^ 1) }
        cur ^= 1;
    }

    // final cross-lane l reduce (once, not per tile)
    l0r += __shfl_xor(l0r, 16, 64);
    l0r += __shfl_xor(l0r, 32, 64);
    l1r += __shfl_xor(l1r, 16, 64);
    l1r += __shfl_xor(l1r, 32, 64);

    {
        int qr0 = b * N_ + n0 + wave * 32 + ql;
        bf16* nb0 = num + (size_t)sp * ROWS * D_ + (size_t)qr0 * D_ + h * DH_;
        bf16* nb1 = num + (size_t)sp * ROWS * D_ + (size_t)(qr0 + 16) * D_ + h * DH_;
#pragma unroll
        for (int df = 0; df < 4; ++df) {
            bf16x4v w0, w1;
#pragma unroll
            for (int e = 0; e < 4; ++e) {
                w0[e] = (__bf16)cacc0[df][e];
                w1[e] = (__bf16)cacc1[df][e];
            }
            *(bf16x4v*)(nb0 + df * 16 + 4 * gg) = w0;
            *(bf16x4v*)(nb1 + df * 16 + 4 * gg) = w1;
        }
        if (lane < 16) {
            size_t base = ((size_t)(sp * (B_ * H_) + bh) * N_ + (n0 + wave * 32 + ql)) * 2;
            ml[base] = m0r; ml[base + 1] = l0r;
            size_t base1 = ((size_t)(sp * (B_ * H_) + bh) * N_ + (n0 + wave * 32 + 16 + ql)) * 2;
            ml[base1] = m1r; ml[base1 + 1] = l1r;
        }
    }
#undef STAGE_LOAD
#undef STAGE_WRITE
#undef SOFTMAX_PV
}

// Combine the SPLIT partials (bf16 numerators) -> bf16 ctx. 8 elems/thread.
__global__ __launch_bounds__(256) void attn_combine(
    const bf16* __restrict__ num, const float* __restrict__ ml,
    bf16* __restrict__ ctx)
{
    int idx = blockIdx.x * 256 + threadIdx.x;
    int row = idx >> 6;              // 64 eight-col chunks per row
    int c8  = (idx & 63) << 3;
    int b = row >> 11, n = row & (N_ - 1);
    int h = c8 >> 6;
    int bh = (b << 3) + h;
    float mv[SPLIT], lv[SPLIT];
#pragma unroll
    for (int sp = 0; sp < SPLIT; ++sp) {
        const float* mp = ml + ((size_t)(sp * (B_ * H_) + bh) * N_ + n) * 2;
        mv[sp] = mp[0]; lv[sp] = mp[1];
    }
    float mx = mv[0];
#pragma unroll
    for (int sp = 1; sp < SPLIT; ++sp) mx = fmaxf(mx, mv[sp]);
    float den = 0.f;
    float wsc[SPLIT];
#pragma unroll
    for (int sp = 0; sp < SPLIT; ++sp) {
        wsc[sp] = __expf(mv[sp] - mx);
        den += wsc[sp] * lv[sp];
    }
    float inv = 1.f / den;
    float a[8] = {};
#pragma unroll
    for (int sp = 0; sp < SPLIT; ++sp) {
        bf16x8 v = *(const bf16x8*)(num + (size_t)sp * ROWS * D_ + (size_t)row * D_ + c8);
#pragma unroll
        for (int e = 0; e < 8; ++e) a[e] += wsc[sp] * (float)v[e];
    }
    bf16x8 o;
#pragma unroll
    for (int e = 0; e < 8; ++e) o[e] = (__bf16)(a[e] * inv);
    *(bf16x8*)(ctx + (size_t)row * D_ + c8) = o;
}

// ---------------------------------------------------------------------------
extern "C" void kernel_launch(void* const* d_in, const int* in_sizes, int n_in,
                              void* d_out, int out_size, void* d_ws, size_t ws_size,
                              hipStream_t stream)
{
    const float* x      = (const float*)d_in[0];
    const float* y      = (const float*)d_in[1];
    const float* mask_x = (const float*)d_in[2];
    const float* mask_y = (const float*)d_in[3];
    const float* Wq = (const float*)d_in[4];  const float* bq = (const float*)d_in[5];
    const float* Wk = (const float*)d_in[6];  const float* bk = (const float*)d_in[7];
    const float* Wv = (const float*)d_in[8];  const float* bv = (const float*)d_in[9];
    const float* Wo = (const float*)d_in[10]; const float* bo = (const float*)d_in[11];
    const float* W1 = (const float*)d_in[12]; const float* b1 = (const float*)d_in[13];
    const float* W2 = (const float*)d_in[14]; const float* b2 = (const float*)d_in[15];
    const float* ln1g = (const float*)d_in[16]; const float* ln1b = (const float*)d_in[17];
    const float* ln2g = (const float*)d_in[18]; const float* ln2b = (const float*)d_in[19];

    char* ws = (char*)d_ws;
    const size_t SZA = (size_t)ROWS * D_ * 2;     // 4 MiB bf16 activation
    bf16* xn   = (bf16*)ws;            ws += SZA;
    bf16* yn   = (bf16*)ws;            ws += SZA;
    bf16* qb   = (bf16*)ws;            ws += SZA;
    bf16* kb   = (bf16*)ws;            ws += SZA;
    bf16* vtb  = (bf16*)ws;            ws += SZA;
    bf16* ctxb = (bf16*)ws;            ws += SZA;
    bf16* xn2  = (bf16*)ws;            ws += SZA;
    bf16* x1b  = (bf16*)ws;            ws += SZA;
    bf16* hff  = (bf16*)ws;            ws += (size_t)ROWS * F_ * 2;
    bf16* Wqt = (bf16*)ws;             ws += (size_t)D_ * D_ * 2;
    bf16* Wkt = (bf16*)ws;             ws += (size_t)D_ * D_ * 2;
    bf16* Wvt = (bf16*)ws;             ws += (size_t)D_ * D_ * 2;
    bf16* Wot = (bf16*)ws;             ws += (size_t)D_ * D_ * 2;
    bf16* W1t = (bf16*)ws;             ws += (size_t)D_ * F_ * 2;
    bf16* W2t = (bf16*)ws;             ws += (size_t)F_ * D_ * 2;
    bf16* numb = (bf16*)ws;            ws += (size_t)SPLIT * ROWS * D_ * 2;
    float* mlb = (float*)ws;           ws += (size_t)SPLIT * B_ * H_ * N_ * 2 * 4;

    // One fused prep launch: all 6 weight transposes + LN(x) + LN(y)
    prep_kernel<<<5120, 256, 0, stream>>>(
        Wq, Wk, Wv, Wo, W1, W2, Wqt, Wkt, Wvt, Wot, W1t, W2t,
        x, y, ln1g, ln1b, xn, yn);

    // Q/K/V projections; V written directly in per-head transposed layout
    gemm64_qkv<<<dim3(ROWS / 64, D_ / 64, 3), 256, 0, stream>>>(
        xn, yn, Wqt, Wkt, Wvt, bq, bk, bv, mask_x, mask_y, qb, kb, vtb);

    attn_kernel<<<ATT_GRID, 256, 0, stream>>>(qb, kb, vtb, numb, mlb);
    attn_combine<<<(ROWS * D_ / 8) / 256, 256, 0, stream>>>(numb, mlb, ctxb);

    // out-proj + residual(x f32) -> x1 (bf16)
    gemm64_wo<<<dim3(ROWS / 64, D_ / 64), 256, 0, stream>>>(
        ctxb, Wot, bo, x, x1b, D_, D_);

    // ln2 on bf16 x1
    lnb_kernel<<<ROWS / 4, 256, 0, stream>>>(x1b, ln2g, ln2b, xn2);

    // MLP1 + GELU -> hff (bf16), gemm64 structure (2048 blocks)
    gemm64_mlp1<<<dim3(ROWS / 64, F_ / 64), 256, 0, stream>>>(
        xn2, W1t, b1, hff, F_, D_);

    // MLP2 + residual(x1 bf16) -> d_out (f32)
    gemm64_mlp2<<<dim3(ROWS / 64, D_ / 64), 256, 0, stream>>>(
        hff, W2t, b2, x1b, (float*)d_out, D_, F_);
}